// Round 8
// baseline (341.791 us; speedup 1.0000x reference)
//
#include <hip/hip_runtime.h>
#include <stdint.h>

// B=2, S=2048, D=1024, H=16, DK=64, DH=4096. I/O fp32; internals bf16 MFMA.
// R15: attention rebuilt as 4 waves x 64 q-rows (two q-column-blocks per
// wave sharing one K/V fragment read). Halves LDS read traffic per unit
// work vs R12 (16KB/wave/tile now feeds 64 rows); MFMA becomes the dominant
// pipe (32 MFMA/wave/tile). Grid (8,32)=256 = 1 block/CU, 1 wave/SIMD.
// GEMMs: R14 wait-at-consumption counted-vmcnt gemm_8p + XCD swizzle.

typedef unsigned short u16;
typedef __attribute__((ext_vector_type(8))) short v8s;   // 8 x bf16
typedef __attribute__((ext_vector_type(4))) float v4f;
typedef __attribute__((ext_vector_type(16))) float v16f;
typedef __attribute__((ext_vector_type(2))) unsigned int v2u;

#define AS1 __attribute__((address_space(1)))
#define AS3 __attribute__((address_space(3)))

__device__ __forceinline__ void gl_lds16(const u16* g, u16* l) {
  __builtin_amdgcn_global_load_lds((const AS1 void*)g, (AS3 void*)l, 16, 0, 0);
}

__device__ __forceinline__ float bf2f(u16 u) {
  union { uint32_t i; float f; } v; v.i = ((uint32_t)u) << 16; return v.f;
}
__device__ __forceinline__ u16 f2bf(float f) {
  union { float f; uint32_t i; } v; v.f = f;
  uint32_t x = v.i;
  return (u16)((x + 0x7FFFu + ((x >> 16) & 1u)) >> 16);  // RNE
}
__device__ __forceinline__ uint32_t fbits(float f) {
  union { float f; uint32_t u; } v; v.f = f; return v.u;
}

// ---------------------------------------------------------------------------
__global__ __launch_bounds__(256) void cvt_f2b(
    const float* __restrict__ src, u16* __restrict__ dst, int n4) {
  int i = (blockIdx.x * 256 + threadIdx.x);
  if (i < n4) {
    float4 v = *(const float4*)(src + (size_t)i * 4);
    ushort4 o;
    o.x = f2bf(v.x); o.y = f2bf(v.y); o.z = f2bf(v.z); o.w = f2bf(v.w);
    *(ushort4*)(dst + (size_t)i * 4) = o;
  }
}

// ---------------------------------------------------------------------------
__global__ __launch_bounds__(256) void transpose_f2b(
    const float* __restrict__ src, u16* __restrict__ dst,
    int R, int C, int ld_s, int ld_d) {
  __shared__ float tile[32][33];
  const int tx = threadIdx.x & 31, ty = threadIdx.x >> 5;
  const int c0 = blockIdx.x * 32, r0 = blockIdx.y * 32;
#pragma unroll
  for (int j = 0; j < 32; j += 8)
    tile[ty + j][tx] = src[(size_t)(r0 + ty + j) * ld_s + c0 + tx];
  __syncthreads();
#pragma unroll
  for (int j = 0; j < 32; j += 8)
    dst[(size_t)(c0 + ty + j) * ld_d + r0 + tx] = f2bf(tile[tx][ty + j]);
}

__global__ __launch_bounds__(256) void transpose_b2b(
    const u16* __restrict__ src, u16* __restrict__ dst,
    int R, int C, int ld_s, int ld_d) {
  __shared__ u16 tile[32][33];
  const int tx = threadIdx.x & 31, ty = threadIdx.x >> 5;
  const int c0 = blockIdx.x * 32, r0 = blockIdx.y * 32;
#pragma unroll
  for (int j = 0; j < 32; j += 8)
    tile[ty + j][tx] = src[(size_t)(r0 + ty + j) * ld_s + c0 + tx];
  __syncthreads();
#pragma unroll
  for (int j = 0; j < 32; j += 8)
    dst[(size_t)(c0 + ty + j) * ld_d + r0 + tx] = tile[tx][ty + j];
}

// ---------------------------------------------------------------------------
// gemm_8p: 256x256 tile, BK=64, 512 threads (8 waves: 2M x 4N), 128 KiB LDS.
// Wait-at-consumption schedule (2 barriers/K-tile), counted vmcnt never 0 in
// steady state. XCD-aware bijective block swizzle. (R14, proven)
// z==0 -> C0 (+bias, relu, fp32 or bf16); z=1..3 -> C1/C2/C3 bf16 partials.
// ---------------------------------------------------------------------------
__global__ __launch_bounds__(512, 1) void gemm_8p(
    const u16* __restrict__ A, const u16* __restrict__ Bt,
    const float* __restrict__ bias, void* __restrict__ C0,
    u16* __restrict__ C1, u16* __restrict__ C2, u16* __restrict__ C3,
    int M, int N, int ldk, int klen, int relu, int c0_f32) {
  __shared__ u16 As[2][16384];   // [buf][row*64 + elem], 256 rows x 64 k
  __shared__ u16 Bs[2][16384];
  const int tid = threadIdx.x;
  const int w = tid >> 6, l = tid & 63;
  const int l16 = l & 15, kgrp = (l >> 4) & 3;
  const int wm = w >> 2, wn = w & 3;

  // XCD-aware bijective swizzle over full linear id (all launches nwg%8==0)
  const int gx = gridDim.x, gyd = gridDim.y;
  const int nxy = gx * gyd;
  const int nwg = nxy * gridDim.z;
  int lin = blockIdx.x + gx * (blockIdx.y + gyd * blockIdx.z);
  if ((nwg & 7) == 0) lin = (lin & 7) * (nwg >> 3) + (lin >> 3);
  const int z = lin / nxy;
  const int rem = lin - z * nxy;
  const int by = rem / gx;
  const int bx = rem - by * gx;
  const int m0 = by * 256, n0 = bx * 256;
  const int NT = klen >> 6;

  const int rl = tid >> 3;
  const int sw = 8 * ((tid & 7) ^ (rl & 7));
  const u16* gA[4]; const u16* gB[4];
#pragma unroll
  for (int j = 0; j < 4; j++) {
    gA[j] = A + (size_t)(m0 + j * 64 + rl) * ldk + (size_t)z * klen + sw;
    gB[j] = Bt + (size_t)(n0 + j * 64 + rl) * ldk + (size_t)z * klen + sw;
  }
  const int sdst = w * 512;   // wave-uniform LDS base (+ j*4096)

  const int ch0 = 8 * ((kgrp) ^ (l16 & 7));
  const int ch1 = 8 * ((4 + kgrp) ^ (l16 & 7));
  const int abase = (wm * 128 + l16) * 64;
  const int bbase = (wn * 64 + l16) * 64;

  v4f acc[8][4];
#pragma unroll
  for (int i = 0; i < 8; i++)
#pragma unroll
    for (int j = 0; j < 4; j++)
#pragma unroll
      for (int r = 0; r < 4; r++) acc[i][j][r] = 0.f;

  v8s a[4][2], b[4][2];

#define FENCE() asm volatile("" ::: "memory")
#define VMC(n) asm volatile("s_waitcnt vmcnt(" #n ")" ::: "memory")
#define BARX() { __builtin_amdgcn_s_barrier(); \
                 __builtin_amdgcn_sched_barrier(0); FENCE(); }
#define STGA(q, j, kt) gl_lds16(gA[j] + (size_t)(kt) * 64, &As[q][(j) * 4096 + sdst])
#define STGB(q, j, kt) gl_lds16(gB[j] + (size_t)(kt) * 64, &Bs[q][(j) * 4096 + sdst])
#define LDA(p, mh) { \
  const u16* Ap = &As[p][abase + (mh) * 4096]; \
  _Pragma("unroll") for (int mi = 0; mi < 4; mi++) { \
    a[mi][0] = *(const v8s*)(Ap + mi * 1024 + ch0); \
    a[mi][1] = *(const v8s*)(Ap + mi * 1024 + ch1); } }
#define LDB(p, nh) { \
  const u16* Bp = &Bs[p][bbase + (nh) * 2048]; \
  _Pragma("unroll") for (int ni = 0; ni < 2; ni++) { \
    b[(nh) * 2 + ni][0] = *(const v8s*)(Bp + ni * 1024 + ch0); \
    b[(nh) * 2 + ni][1] = *(const v8s*)(Bp + ni * 1024 + ch1); } }
#define MFQ(mh, nh) { \
  __builtin_amdgcn_s_setprio(1); \
  _Pragma("unroll") for (int ks = 0; ks < 2; ks++) \
  _Pragma("unroll") for (int mi = 0; mi < 4; mi++) \
  _Pragma("unroll") for (int ni = 0; ni < 2; ni++) \
    acc[(mh) * 4 + mi][(nh) * 2 + ni] = __builtin_amdgcn_mfma_f32_16x16x32_bf16( \
        a[mi][ks], b[(nh) * 2 + ni][ks], acc[(mh) * 4 + mi][(nh) * 2 + ni], 0, 0, 0); \
  __builtin_amdgcn_s_setprio(0); }

  // prologue: stage tile 0 into buf0, need-first order: A02, B01, B23, A13.
  STGA(0, 0, 0); STGA(0, 2, 0);
  FENCE();
  STGB(0, 0, 0); STGB(0, 1, 0);
  FENCE();
  STGB(0, 2, 0); STGB(0, 3, 0);
  FENCE();
  STGA(0, 1, 0); STGA(0, 3, 0);

  int p = 0;
  for (int kt = 0; kt < NT - 1; ++kt, p ^= 1) {
    const int q = p ^ 1;
    const int kn = kt + 1;
    // Ph1: A02/B01/B23(kt) landed; A13(kt) still in flight
    VMC(2); BARX();
    LDA(p, 0);
    LDB(p, 0);
    FENCE();
    STGA(q, 0, kn); STGA(q, 2, kn);
    MFQ(0, 0);
    // Ph2: issue all B stages of kt+1 (B23 gets 3 phases of flight)
    LDB(p, 1);
    FENCE();
    STGB(q, 0, kn); STGB(q, 1, kn);
    STGB(q, 2, kn); STGB(q, 3, kn);
    MFQ(0, 1);
    // Ph3: retire A13(kt) (oldest 2 of 8 in flight)
    VMC(6); BARX();
    LDA(p, 1);
    FENCE();
    STGA(q, 1, kn); STGA(q, 3, kn);
    MFQ(1, 1);
    // Ph4: pure MFMA; next tile-boundary drain overlaps this cluster
    MFQ(1, 0);
  }
  // peeled last tile: drain everything; no staging.
  VMC(0); BARX();
  LDA(p, 0);
  LDB(p, 0);
  MFQ(0, 0);
  LDB(p, 1);
  MFQ(0, 1);
  LDA(p, 1);
  MFQ(1, 1);
  MFQ(1, 0);

#undef FENCE
#undef VMC
#undef BARX
#undef STGA
#undef STGB
#undef LDA
#undef LDB
#undef MFQ

#pragma unroll
  for (int mi = 0; mi < 8; mi++) {
    const int row = m0 + wm * 128 + mi * 16 + kgrp * 4;
#pragma unroll
    for (int ni = 0; ni < 4; ni++) {
      const int col = n0 + wn * 64 + ni * 16 + l16;
      float bv = (bias && z == 0) ? bias[col] : 0.f;
#pragma unroll
      for (int r = 0; r < 4; r++) {
        float v = acc[mi][ni][r] + bv;
        if (z == 0 && relu) v = fmaxf(v, 0.f);
        size_t idx = (size_t)(row + r) * N + col;
        if (z == 0) {
          if (c0_f32) ((float*)C0)[idx] = v;
          else ((u16*)C0)[idx] = f2bf(v);
        } else if (z == 1) {
          C1[idx] = f2bf(v);
        } else if (z == 2) {
          C2[idx] = f2bf(v);
        } else {
          C3[idx] = f2bf(v);
        }
      }
    }
  }
}

// ---------------------------------------------------------------------------
// G2: 128x64 tile, BK=64, double-buffered (Qproj + small path).
// ---------------------------------------------------------------------------
__global__ __launch_bounds__(256) void gemm_g2(
    const u16* __restrict__ A, const u16* __restrict__ Bt,
    const float* __restrict__ bias, void* __restrict__ C,
    int M, int N, int K, int relu, int accum, int out_f32) {
  __shared__ u16 As[2][8192];
  __shared__ u16 Bs[2][4096];
  const int tid = threadIdx.x;
  const int w = tid >> 6, l = tid & 63;
  const int l16 = l & 15, kgrp = l >> 4;
  const int m0 = blockIdx.y * 128, n0 = blockIdx.x * 64;
  const int wr = (w >> 1) * 64, wc = (w & 1) * 32;

  const int srow = w * 8 + (l >> 3);
  const u16* gA[4];
#pragma unroll
  for (int i = 0; i < 4; i++) {
    int r = i * 32 + srow;
    gA[i] = A + (size_t)(m0 + r) * K + 8 * ((l & 7) ^ (r & 7));
  }
  const u16* gB[2];
#pragma unroll
  for (int i = 0; i < 2; i++) {
    int r = i * 32 + srow;
    gB[i] = Bt + (size_t)(n0 + r) * K + 8 * ((l & 7) ^ (r & 7));
  }

  v4f acc[4][2];
#pragma unroll
  for (int i = 0; i < 4; i++)
#pragma unroll
    for (int j = 0; j < 2; j++)
#pragma unroll
      for (int r = 0; r < 4; r++) acc[i][j][r] = 0.f;

#pragma unroll
  for (int i = 0; i < 4; i++) gl_lds16(gA[i], &As[0][(i * 256 + w * 64) * 8]);
#pragma unroll
  for (int i = 0; i < 2; i++) gl_lds16(gB[i], &Bs[0][(i * 256 + w * 64) * 8]);

  int cur = 0;
  for (int k0 = 0; k0 < K; k0 += 64) {
    __syncthreads();
    if (k0 + 64 < K) {
      int nxt = cur ^ 1;
#pragma unroll
      for (int i = 0; i < 4; i++)
        gl_lds16(gA[i] + k0 + 64, &As[nxt][(i * 256 + w * 64) * 8]);
#pragma unroll
      for (int i = 0; i < 2; i++)
        gl_lds16(gB[i] + k0 + 64, &Bs[nxt][(i * 256 + w * 64) * 8]);
    }
    v8s a[4][2], b[2][2];
#pragma unroll
    for (int ks = 0; ks < 2; ks++) {
      int ch = 8 * ((ks * 4 + kgrp) ^ (l16 & 7));
#pragma unroll
      for (int mi = 0; mi < 4; mi++)
        a[mi][ks] = *(const v8s*)(&As[cur][(wr + mi * 16 + l16) * 64 + ch]);
#pragma unroll
      for (int ni = 0; ni < 2; ni++)
        b[ni][ks] = *(const v8s*)(&Bs[cur][(wc + ni * 16 + l16) * 64 + ch]);
    }
#pragma unroll
    for (int ks = 0; ks < 2; ks++)
#pragma unroll
      for (int mi = 0; mi < 4; mi++)
#pragma unroll
        for (int ni = 0; ni < 2; ni++)
          acc[mi][ni] = __builtin_amdgcn_mfma_f32_16x16x32_bf16(a[mi][ks], b[ni][ks], acc[mi][ni], 0, 0, 0);
    cur ^= 1;
  }

#pragma unroll
  for (int ni = 0; ni < 2; ni++) {
    int col = n0 + wc + ni * 16 + l16;
    float bv = bias ? bias[col] : 0.f;
#pragma unroll
    for (int mi = 0; mi < 4; mi++) {
      int row = m0 + wr + mi * 16 + kgrp * 4;
#pragma unroll
      for (int r = 0; r < 4; r++) {
        float v = acc[mi][ni][r] + bv;
        if (relu) v = fmaxf(v, 0.f);
        size_t idx = (size_t)(row + r) * N + col;
        if (out_f32) {
          float* Cf = (float*)C;
          if (accum) v += Cf[idx];
          Cf[idx] = v;
        } else {
          ((u16*)C)[idx] = f2bf(v);
        }
      }
    }
  }
}

// ---------------------------------------------------------------------------
// Attention: O = softmax(Q Q^T / sqrt(S)) Q per (b,h).
// R15: 256 threads, 4 waves x 64 q-rows (two q-col-blocks A/B per wave).
// One K/V fragment read feeds 4 MFMA (both q-blocks). Grid (8,32) = 256.
// LDS: KV dbuf 32KB. Wave w stages K rows [16w,16w+16) + V d-rows ditto
// (4 gl_lds16/wave). Layout/swizzle/permlane machinery identical to R12.
// ---------------------------------------------------------------------------
__global__ __launch_bounds__(256) void attn_kernel(
    const u16* __restrict__ Q, const u16* __restrict__ Qt,
    u16* __restrict__ O) {
  __shared__ u16 KV[2][8192];
  const int tid = threadIdx.x;
  const int w = tid >> 6, l = tid & 63;
  const int l31 = l & 31, hi = l >> 5;
  const int bh = blockIdx.y, b = bh >> 4, h = bh & 15;
  const int q0 = blockIdx.x * 256;
  const size_t rowQ = (size_t)(b * 2048 + q0 + w * 64);
  const float cexp = 1.4426950408889634f / 45.254833995939045f;

  // staging: wave w stages K rows [16w..16w+16) and V d-rows [16w..16w+16)
  const int r0 = w * 16 + (l >> 3);
  const int sch8 = 8 * ((l & 7) ^ (l >> 3));
  const u16* gK = Q + (size_t)(b * 2048 + r0) * 1024 + h * 64 + sch8;
  const u16* gK1 = gK + (size_t)8 * 1024;
  const u16* gV = Qt + (size_t)(h * 64 + r0) * 4096 + b * 2048 + sch8;
  const u16* gV1 = gV + (size_t)8 * 4096;
  const int ldstK = w * 1024;
  const int ldstV = 4096 + w * 1024;

  // Q fragments for both q-blocks: q = rowQ + {0,32} + l31, pre-scaled.
  v8s qa[4], qc[4];
#pragma unroll
  for (int t = 0; t < 4; t++) {
    v8s va = *(const v8s*)(Q + (rowQ + l31) * 1024 + h * 64 + t * 16 + hi * 8);
    v8s vc = *(const v8s*)(Q + (rowQ + 32 + l31) * 1024 + h * 64 + t * 16 + hi * 8);
#pragma unroll
    for (int j = 0; j < 8; j++) {
      va[j] = (short)f2bf(bf2f((u16)va[j]) * cexp);
      vc[j] = (short)f2bf(bf2f((u16)vc[j]) * cexp);
    }
    qa[t] = va; qc[t] = vc;
  }

  v16f oA0, oA1, oB0, oB1;
#pragma unroll
  for (int r = 0; r < 16; r++) { oA0[r] = 0.f; oA1[r] = 0.f; oB0[r] = 0.f; oB1[r] = 0.f; }
  float lsA = 0.f, lsB = 0.f;

  gl_lds16(gK, &KV[0][ldstK]);
  gl_lds16(gK1, &KV[0][ldstK + 512]);
  gl_lds16(gV, &KV[0][ldstV]);
  gl_lds16(gV1, &KV[0][ldstV + 512]);

  int cur = 0;
  for (int kb = 0; kb < 2048; kb += 64) {
    __syncthreads();
    if (kb + 64 < 2048) {
      int nxt = cur ^ 1;
      gl_lds16(gK + (size_t)(kb + 64) * 1024, &KV[nxt][ldstK]);
      gl_lds16(gK1 + (size_t)(kb + 64) * 1024, &KV[nxt][ldstK + 512]);
      gl_lds16(gV + (kb + 64), &KV[nxt][ldstV]);
      gl_lds16(gV1 + (kb + 64), &KV[nxt][ldstV + 512]);
    }
    const u16* Ks = &KV[cur][0];
    const u16* Vt = &KV[cur][4096];

    // QK^T: s[kblock][qblock]
    v16f s00, s10, s01, s11;
#pragma unroll
    for (int r = 0; r < 16; r++) { s00[r] = 0.f; s10[r] = 0.f; s01[r] = 0.f; s11[r] = 0.f; }
    __builtin_amdgcn_s_setprio(1);
#pragma unroll
    for (int t = 0; t < 4; t++) {
      const int c = 8 * ((2 * t + hi) ^ (l & 7));
      v8s ka0 = *(const v8s*)(Ks + l31 * 64 + c);
      v8s ka1 = *(const v8s*)(Ks + (32 + l31) * 64 + c);
      s00 = __builtin_amdgcn_mfma_f32_32x32x16_bf16(ka0, qa[t], s00, 0, 0, 0);
      s10 = __builtin_amdgcn_mfma_f32_32x32x16_bf16(ka1, qa[t], s10, 0, 0, 0);
      s01 = __builtin_amdgcn_mfma_f32_32x32x16_bf16(ka0, qc[t], s01, 0, 0, 0);
      s11 = __builtin_amdgcn_mfma_f32_32x32x16_bf16(ka1, qc[t], s11, 0, 0, 0);
    }
    __builtin_amdgcn_s_setprio(0);

    float pA0[16], pA1[16], pB0[16], pB1[16];
#pragma unroll
    for (int r = 0; r < 16; r++) {
      pA0[r] = __builtin_amdgcn_exp2f(s00[r]);
      pA1[r] = __builtin_amdgcn_exp2f(s10[r]);
      pB0[r] = __builtin_amdgcn_exp2f(s01[r]);
      pB1[r] = __builtin_amdgcn_exp2f(s11[r]);
      lsA += pA0[r] + pA1[r];
      lsB += pB0[r] + pB1[r];
    }

    // PV: 4 k-chunks of 16; P operands via perm-pack + permlane32_swap,
    // V fragments shared across both q-blocks.
#define PACKP(P, out) { \
      const int off = 8 * ((tt) & 1); \
      uint32_t dw00 = __builtin_amdgcn_perm(fbits(P[off + 1]), fbits(P[off + 0]), 0x07060302u); \
      uint32_t dw01 = __builtin_amdgcn_perm(fbits(P[off + 3]), fbits(P[off + 2]), 0x07060302u); \
      uint32_t dw10 = __builtin_amdgcn_perm(fbits(P[off + 5]), fbits(P[off + 4]), 0x07060302u); \
      uint32_t dw11 = __builtin_amdgcn_perm(fbits(P[off + 7]), fbits(P[off + 6]), 0x07060302u); \
      v2u sA_ = __builtin_amdgcn_permlane32_swap(dw00, dw10, false, false); \
      v2u sB_ = __builtin_amdgcn_permlane32_swap(dw01, dw11, false, false); \
      out.u[0] = sA_[0]; out.u[1] = sB_[0]; out.u[2] = sA_[1]; out.u[3] = sB_[1]; }
#define PVSTEP(t, PA, PB) { \
      const int tt = (t); \
      union { uint32_t u[4]; v8s v; } paA, paB; \
      PACKP(PA, paA); \
      PACKP(PB, paB); \
      const int c = 8 * ((2 * tt + hi) ^ (l & 7)); \
      v8s vb0 = *(const v8s*)(Vt + l31 * 64 + c); \
      v8s vb1 = *(const v8s*)(Vt + (32 + l31) * 64 + c); \
      __builtin_amdgcn_s_setprio(1); \
      oA0 = __builtin_amdgcn_mfma_f32_32x32x16_bf16(paA.v, vb0, oA0, 0, 0, 0); \
      oA1 = __builtin_amdgcn_mfma_f32_32x32x16_bf16(paA.v, vb1, oA1, 0, 0, 0); \
      oB0 = __builtin_amdgcn_mfma_f32_32x32x16_bf16(paB.v, vb0, oB0, 0, 0, 0); \
      oB1 = __builtin_amdgcn_mfma_f32_32x32x16_bf16(paB.v, vb1, oB1, 0, 0, 0); \
      __builtin_amdgcn_s_setprio(0); }
    PVSTEP(0, pA0, pB0)
    PVSTEP(1, pA0, pB0)
    PVSTEP(2, pA1, pB1)
    PVSTEP(3, pA1, pB1)
#undef PVSTEP
#undef PACKP
    cur ^= 1;
  }

  lsA += __shfl_xor(lsA, 32, 64);   // den[q] at lanes with l31 == q
  lsB += __shfl_xor(lsB, 32, 64);

#pragma unroll
  for (int r = 0; r < 16; r++) {
    const int qo = (r & 3) + 8 * (r >> 2) + hi * 4;
    float rdA = 1.f / __shfl(lsA, qo, 64);
    float rdB = 1.f / __shfl(lsB, qo, 64);
    O[(rowQ + qo) * 1024 + h * 64 + l31] = f2bf(oA0[r] * rdA);
    O[(rowQ + qo) * 1024 + h * 64 + 32 + l31] = f2bf(oA1[r] * rdA);
    O[(rowQ + 32 + qo) * 1024 + h * 64 + l31] = f2bf(oB0[r] * rdB);
    O[(rowQ + 32 + qo) * 1024 + h * 64 + 32 + l31] = f2bf(oB1[r] * rdB);
  }
}

// ---------------------------------------------------------------------------
// out = LayerNorm(Y [+ Y2 + Y3 + Y4] + Xr) * g + b; row length 1024; dtype
// flags (1 = fp32, 0 = bf16). Y2/Y3/Y4 nullable (Y3/Y4 always bf16).
// In-place safe.
// ---------------------------------------------------------------------------
__global__ __launch_bounds__(256) void ln_residual(
    const void* __restrict__ Y, const void* __restrict__ Y2,
    const void* __restrict__ Y3, const void* __restrict__ Y4,
    const void* __restrict__ Xr,
    const float* __restrict__ g, const float* __restrict__ bb,
    void* __restrict__ out, int yf, int y2f, int xf, int of) {
  const int row = blockIdx.x, tid = threadIdx.x;
  const size_t base = (size_t)row * 1024;
  float v[4], s = 0.f, sq = 0.f;
#pragma unroll
  for (int i = 0; i < 4; i++) {
    int c = tid + i * 256;
    float ya = yf ? ((const float*)Y)[base + c] : bf2f(((const u16*)Y)[base + c]);
    float xa = xf ? ((const float*)Xr)[base + c] : bf2f(((const u16*)Xr)[base + c]);
    float x = ya + xa;
    if (Y2) {
      float y2a = y2f ? ((const float*)Y2)[base + c] : bf2f(((const u16*)Y2)[base + c]);
      x += y2a;
    }
    if (Y3) x += bf2f(((const u16*)Y3)[base + c]);
    if (Y4) x += bf2f(((const u16*)Y4)[base + c]);
    v[i] = x; s += x; sq += x * x;
  }
#pragma unroll
  for (int off = 32; off >= 1; off >>= 1) {
    s += __shfl_down(s, off, 64);
    sq += __shfl_down(sq, off, 64);
  }
  __shared__ float rs[4], rq[4];
  const int w = tid >> 6, l = tid & 63;
  if (l == 0) { rs[w] = s; rq[w] = sq; }
  __syncthreads();
  s = rs[0] + rs[1] + rs[2] + rs[3];
  sq = rq[0] + rq[1] + rq[2] + rq[3];
  const float mu = s * (1.f / 1024.f);
  const float var = sq * (1.f / 1024.f) - mu * mu;
  const float rstd = rsqrtf(var + 1e-5f);
#pragma unroll
  for (int i = 0; i < 4; i++) {
    int c = tid + i * 256;
    float r = (v[i] - mu) * rstd * g[c] + bb[c];
    if (of) ((float*)out)[base + c] = r;
    else ((u16*)out)[base + c] = f2bf(r);
  }
}

// ---------------------------------------------------------------------------
extern "C" void kernel_launch(void* const* d_in, const int* in_sizes, int n_in,
                              void* d_out, int out_size, void* d_ws, size_t ws_size,
                              hipStream_t stream) {
  const float* x   = (const float*)d_in[0];
  const float* Wq  = (const float*)d_in[1];
  const float* bq  = (const float*)d_in[2];
  const float* Wo  = (const float*)d_in[3];
  const float* bo  = (const float*)d_in[4];
  const float* g1  = (const float*)d_in[5];
  const float* be1 = (const float*)d_in[6];
  const float* W1  = (const float*)d_in[7];
  const float* b1  = (const float*)d_in[8];
  const float* W2  = (const float*)d_in[9];
  const float* b2  = (const float*)d_in[10];
  const float* g2  = (const float*)d_in[11];
  const float* be2 = (const float*)d_in[12];
  float* out = (float*)d_out;
  u16* ws  = (u16*)d_ws;

  const size_t M1 = 1048576;
  dim3 blk(256);
  dim3 blk8(512);
  const bool big = ws_size >= (size_t)37 * M1 * 2;  // 74 MiB

  if (big) {
    u16* xb   = ws + 0;          // [0..4M)  -> attn -> P2_ffn2
    u16* Qb   = ws + 4 * M1;     // [4..8M)  -> x1
    u16* Qt   = ws + 8 * M1;     // [8..12M) -> Yb (Wo P0) -> P1_ffn2
    u16* WqT  = ws + 12 * M1;    // [12..13M) -> WoT
    u16* W1T  = ws + 13 * M1;    // [13..17M) P1_wo -> W1T -> P3_ffn2
    u16* W2T  = ws + 17 * M1;    // [17..21M) P2_wo -> W2T
    u16* Hh   = ws + 21 * M1;    // [21..37M) P3_wo (head) -> Hh
    u16* attn = xb;  u16* Yb = Qt;  u16* x1 = Qb;  u16* WoT = WqT;
    // Wo split-4 partials: dead regions until later writers run (all after LN1)
    u16* P1wo = W1T;             // overwritten by transpose(W1) after LN1
    u16* P2wo = W2T;             // overwritten by transpose(W2) after FFN1
    u16* P3wo = Hh;              // overwritten by FFN1 after LN1
    // FFN2 split-4 partials: dead after their last reads
    u16* P1f2 = Qt;              // Yb dead after LN1
    u16* P2f2 = xb;              // attn dead after Wo-proj
    u16* P3f2 = W1T;             // W1T dead after FFN1

    cvt_f2b<<<dim3(4096), blk, 0, stream>>>(x, xb, 1048576);
    transpose_f2b<<<dim3(32, 32), blk, 0, stream>>>(Wq, WqT, 1024, 1024, 1024, 1024);
    gemm_g2<<<dim3(16, 32), blk, 0, stream>>>(xb, WqT, bq, Qb, 4096, 1024, 1024, 0, 0, 0);

    transpose_b2b<<<dim3(32, 128), blk, 0, stream>>>(Qb, Qt, 4096, 1024, 1024, 4096);
    attn_kernel<<<dim3(8, 32), blk, 0, stream>>>(Qb, Qt, attn);

    // Wo projection: split-K=4 phase-pipelined 256x256, P0 -> Yb (bf16, +bias)
    transpose_f2b<<<dim3(32, 32), blk, 0, stream>>>(Wo, WoT, 1024, 1024, 1024, 1024);
    gemm_8p<<<dim3(4, 16, 4), blk8, 0, stream>>>(attn, WoT, bo, Yb, P1wo, P2wo, P3wo,
                                                 4096, 1024, 1024, 256, 0, 0);
    ln_residual<<<dim3(4096), blk, 0, stream>>>(Yb, P1wo, P2wo, P3wo, x, g1, be1, x1,
                                                0, 0, 1, 0);

    // FFN1: full-K phase-pipelined 256x256 (grid 256 = 1 block/CU)
    transpose_f2b<<<dim3(128, 32), blk, 0, stream>>>(W1, W1T, 1024, 4096, 4096, 1024);
    gemm_8p<<<dim3(16, 16, 1), blk8, 0, stream>>>(x1, W1T, b1, Hh,
                                                  nullptr, nullptr, nullptr,
                                                  4096, 4096, 1024, 1024, 1, 0);

    // FFN2: split-K=4 phase-pipelined 256x256, P0 -> out (fp32, +bias)
    transpose_f2b<<<dim3(32, 128), blk, 0, stream>>>(W2, W2T, 4096, 1024, 1024, 4096);
    gemm_8p<<<dim3(4, 16, 4), blk8, 0, stream>>>(Hh, W2T, b2, out, P1f2, P2f2, P3f2,
                                                 4096, 1024, 4096, 1024, 0, 1);

    ln_residual<<<dim3(4096), blk, 0, stream>>>(out, P1f2, P2f2, P3f2, x1, g2, be2, out,
                                                1, 0, 0, 1);
  } else {
    u16* xb   = ws + 0;
    u16* Qb   = ws + 4 * M1;
    u16* Qt   = ws + 8 * M1;
    u16* attn = xb;  u16* Yb = Qt;  u16* x1 = Qb;  u16* Hc = xb;
    u16* Wt1  = ws + 12 * M1;
    u16* Wt2  = ws + 13 * M1;

    cvt_f2b<<<dim3(4096), blk, 0, stream>>>(x, xb, 1048576);
    transpose_f2b<<<dim3(32, 32), blk, 0, stream>>>(Wq, Wt1, 1024, 1024, 1024, 1024);
    gemm_g2<<<dim3(16, 32), blk, 0, stream>>>(xb, Wt1, bq, Qb, 4096, 1024, 1024, 0, 0, 0);

    transpose_b2b<<<dim3(32, 128), blk, 0, stream>>>(Qb, Qt, 4096, 1024, 1024, 4096);
    attn_kernel<<<dim3(8, 32), blk, 0, stream>>>(Qb, Qt, attn);

    transpose_f2b<<<dim3(32, 32), blk, 0, stream>>>(Wo, Wt2, 1024, 1024, 1024, 1024);
    gemm_g2<<<dim3(16, 32), blk, 0, stream>>>(attn, Wt2, bo, Yb, 4096, 1024, 1024, 0, 0, 0);
    ln_residual<<<dim3(4096), blk, 0, stream>>>(Yb, nullptr, nullptr, nullptr, x, g1, be1,
                                                x1, 0, 0, 1, 0);

    for (int c = 0; c < 4; c++) {
      transpose_f2b<<<dim3(32, 32), blk, 0, stream>>>(W1 + (size_t)c * 1024, Wt1,
                                                      1024, 1024, 4096, 1024);
      gemm_g2<<<dim3(16, 32), blk, 0, stream>>>(x1, Wt1, b1 + (size_t)c * 1024, Hc,
                                                4096, 1024, 1024, 1, 0, 0);
      transpose_f2b<<<dim3(32, 32), blk, 0, stream>>>(W2 + (size_t)c * M1, Wt2,
                                                      1024, 1024, 1024, 1024);
      gemm_g2<<<dim3(16, 32), blk, 0, stream>>>(Hc, Wt2, (c == 0) ? b2 : (const float*)nullptr,
                                                out, 4096, 1024, 1024, 0, (c > 0) ? 1 : 0, 1);
    }
    ln_residual<<<dim3(4096), blk, 0, stream>>>(out, nullptr, nullptr, nullptr, x1, g2, be2,
                                                out, 1, 0, 0, 1);
  }
}

// Round 9
// 341.698 us; speedup vs baseline: 1.0003x; 1.0003x over previous
//
#include <hip/hip_runtime.h>
#include <stdint.h>

// B=2, S=2048, D=1024, H=16, DK=64, DH=4096. I/O fp32; internals bf16 MFMA.
// R16: attention = split-KV. 8 waves x 64 q-rows (512-row blocks, 2 waves/
// SIMD) x 2 KV-halves (blockIdx.z). Each block writes unnormalized fp32
// O-partials + per-row sum-exp to ws; attn_combine merges + normalizes.
// Halves per-CU LDS traffic vs R12 while keeping 2 waves/SIMD (R15's R=64
// at 1 wave/SIMD regressed). Small-ws path keeps the proven R12 attention.
// GEMMs: R14 wait-at-consumption counted-vmcnt gemm_8p + XCD swizzle.

typedef unsigned short u16;
typedef __attribute__((ext_vector_type(8))) short v8s;   // 8 x bf16
typedef __attribute__((ext_vector_type(4))) float v4f;
typedef __attribute__((ext_vector_type(16))) float v16f;
typedef __attribute__((ext_vector_type(2))) unsigned int v2u;

#define AS1 __attribute__((address_space(1)))
#define AS3 __attribute__((address_space(3)))

__device__ __forceinline__ void gl_lds16(const u16* g, u16* l) {
  __builtin_amdgcn_global_load_lds((const AS1 void*)g, (AS3 void*)l, 16, 0, 0);
}

__device__ __forceinline__ float bf2f(u16 u) {
  union { uint32_t i; float f; } v; v.i = ((uint32_t)u) << 16; return v.f;
}
__device__ __forceinline__ u16 f2bf(float f) {
  union { float f; uint32_t i; } v; v.f = f;
  uint32_t x = v.i;
  return (u16)((x + 0x7FFFu + ((x >> 16) & 1u)) >> 16);  // RNE
}
__device__ __forceinline__ uint32_t fbits(float f) {
  union { float f; uint32_t u; } v; v.f = f; return v.u;
}

// ---------------------------------------------------------------------------
__global__ __launch_bounds__(256) void cvt_f2b(
    const float* __restrict__ src, u16* __restrict__ dst, int n4) {
  int i = (blockIdx.x * 256 + threadIdx.x);
  if (i < n4) {
    float4 v = *(const float4*)(src + (size_t)i * 4);
    ushort4 o;
    o.x = f2bf(v.x); o.y = f2bf(v.y); o.z = f2bf(v.z); o.w = f2bf(v.w);
    *(ushort4*)(dst + (size_t)i * 4) = o;
  }
}

// ---------------------------------------------------------------------------
__global__ __launch_bounds__(256) void transpose_f2b(
    const float* __restrict__ src, u16* __restrict__ dst,
    int R, int C, int ld_s, int ld_d) {
  __shared__ float tile[32][33];
  const int tx = threadIdx.x & 31, ty = threadIdx.x >> 5;
  const int c0 = blockIdx.x * 32, r0 = blockIdx.y * 32;
#pragma unroll
  for (int j = 0; j < 32; j += 8)
    tile[ty + j][tx] = src[(size_t)(r0 + ty + j) * ld_s + c0 + tx];
  __syncthreads();
#pragma unroll
  for (int j = 0; j < 32; j += 8)
    dst[(size_t)(c0 + ty + j) * ld_d + r0 + tx] = f2bf(tile[tx][ty + j]);
}

__global__ __launch_bounds__(256) void transpose_b2b(
    const u16* __restrict__ src, u16* __restrict__ dst,
    int R, int C, int ld_s, int ld_d) {
  __shared__ u16 tile[32][33];
  const int tx = threadIdx.x & 31, ty = threadIdx.x >> 5;
  const int c0 = blockIdx.x * 32, r0 = blockIdx.y * 32;
#pragma unroll
  for (int j = 0; j < 32; j += 8)
    tile[ty + j][tx] = src[(size_t)(r0 + ty + j) * ld_s + c0 + tx];
  __syncthreads();
#pragma unroll
  for (int j = 0; j < 32; j += 8)
    dst[(size_t)(c0 + ty + j) * ld_d + r0 + tx] = tile[tx][ty + j];
}

// ---------------------------------------------------------------------------
// gemm_8p: 256x256 tile, BK=64, 512 threads (8 waves: 2M x 4N), 128 KiB LDS.
// Wait-at-consumption schedule (2 barriers/K-tile), counted vmcnt never 0 in
// steady state. XCD-aware bijective block swizzle. (R14, proven)
// z==0 -> C0 (+bias, relu, fp32 or bf16); z=1..3 -> C1/C2/C3 bf16 partials.
// ---------------------------------------------------------------------------
__global__ __launch_bounds__(512, 1) void gemm_8p(
    const u16* __restrict__ A, const u16* __restrict__ Bt,
    const float* __restrict__ bias, void* __restrict__ C0,
    u16* __restrict__ C1, u16* __restrict__ C2, u16* __restrict__ C3,
    int M, int N, int ldk, int klen, int relu, int c0_f32) {
  __shared__ u16 As[2][16384];   // [buf][row*64 + elem], 256 rows x 64 k
  __shared__ u16 Bs[2][16384];
  const int tid = threadIdx.x;
  const int w = tid >> 6, l = tid & 63;
  const int l16 = l & 15, kgrp = (l >> 4) & 3;
  const int wm = w >> 2, wn = w & 3;

  // XCD-aware bijective swizzle over full linear id (all launches nwg%8==0)
  const int gx = gridDim.x, gyd = gridDim.y;
  const int nxy = gx * gyd;
  const int nwg = nxy * gridDim.z;
  int lin = blockIdx.x + gx * (blockIdx.y + gyd * blockIdx.z);
  if ((nwg & 7) == 0) lin = (lin & 7) * (nwg >> 3) + (lin >> 3);
  const int z = lin / nxy;
  const int rem = lin - z * nxy;
  const int by = rem / gx;
  const int bx = rem - by * gx;
  const int m0 = by * 256, n0 = bx * 256;
  const int NT = klen >> 6;

  const int rl = tid >> 3;
  const int sw = 8 * ((tid & 7) ^ (rl & 7));
  const u16* gA[4]; const u16* gB[4];
#pragma unroll
  for (int j = 0; j < 4; j++) {
    gA[j] = A + (size_t)(m0 + j * 64 + rl) * ldk + (size_t)z * klen + sw;
    gB[j] = Bt + (size_t)(n0 + j * 64 + rl) * ldk + (size_t)z * klen + sw;
  }
  const int sdst = w * 512;   // wave-uniform LDS base (+ j*4096)

  const int ch0 = 8 * ((kgrp) ^ (l16 & 7));
  const int ch1 = 8 * ((4 + kgrp) ^ (l16 & 7));
  const int abase = (wm * 128 + l16) * 64;
  const int bbase = (wn * 64 + l16) * 64;

  v4f acc[8][4];
#pragma unroll
  for (int i = 0; i < 8; i++)
#pragma unroll
    for (int j = 0; j < 4; j++)
#pragma unroll
      for (int r = 0; r < 4; r++) acc[i][j][r] = 0.f;

  v8s a[4][2], b[4][2];

#define FENCE() asm volatile("" ::: "memory")
#define VMC(n) asm volatile("s_waitcnt vmcnt(" #n ")" ::: "memory")
#define BARX() { __builtin_amdgcn_s_barrier(); \
                 __builtin_amdgcn_sched_barrier(0); FENCE(); }
#define STGA(q, j, kt) gl_lds16(gA[j] + (size_t)(kt) * 64, &As[q][(j) * 4096 + sdst])
#define STGB(q, j, kt) gl_lds16(gB[j] + (size_t)(kt) * 64, &Bs[q][(j) * 4096 + sdst])
#define LDA(p, mh) { \
  const u16* Ap = &As[p][abase + (mh) * 4096]; \
  _Pragma("unroll") for (int mi = 0; mi < 4; mi++) { \
    a[mi][0] = *(const v8s*)(Ap + mi * 1024 + ch0); \
    a[mi][1] = *(const v8s*)(Ap + mi * 1024 + ch1); } }
#define LDB(p, nh) { \
  const u16* Bp = &Bs[p][bbase + (nh) * 2048]; \
  _Pragma("unroll") for (int ni = 0; ni < 2; ni++) { \
    b[(nh) * 2 + ni][0] = *(const v8s*)(Bp + ni * 1024 + ch0); \
    b[(nh) * 2 + ni][1] = *(const v8s*)(Bp + ni * 1024 + ch1); } }
#define MFQ(mh, nh) { \
  __builtin_amdgcn_s_setprio(1); \
  _Pragma("unroll") for (int ks = 0; ks < 2; ks++) \
  _Pragma("unroll") for (int mi = 0; mi < 4; mi++) \
  _Pragma("unroll") for (int ni = 0; ni < 2; ni++) \
    acc[(mh) * 4 + mi][(nh) * 2 + ni] = __builtin_amdgcn_mfma_f32_16x16x32_bf16( \
        a[mi][ks], b[(nh) * 2 + ni][ks], acc[(mh) * 4 + mi][(nh) * 2 + ni], 0, 0, 0); \
  __builtin_amdgcn_s_setprio(0); }

  // prologue: stage tile 0 into buf0, need-first order: A02, B01, B23, A13.
  STGA(0, 0, 0); STGA(0, 2, 0);
  FENCE();
  STGB(0, 0, 0); STGB(0, 1, 0);
  FENCE();
  STGB(0, 2, 0); STGB(0, 3, 0);
  FENCE();
  STGA(0, 1, 0); STGA(0, 3, 0);

  int p = 0;
  for (int kt = 0; kt < NT - 1; ++kt, p ^= 1) {
    const int q = p ^ 1;
    const int kn = kt + 1;
    // Ph1: A02/B01/B23(kt) landed; A13(kt) still in flight
    VMC(2); BARX();
    LDA(p, 0);
    LDB(p, 0);
    FENCE();
    STGA(q, 0, kn); STGA(q, 2, kn);
    MFQ(0, 0);
    // Ph2: issue all B stages of kt+1 (B23 gets 3 phases of flight)
    LDB(p, 1);
    FENCE();
    STGB(q, 0, kn); STGB(q, 1, kn);
    STGB(q, 2, kn); STGB(q, 3, kn);
    MFQ(0, 1);
    // Ph3: retire A13(kt) (oldest 2 of 8 in flight)
    VMC(6); BARX();
    LDA(p, 1);
    FENCE();
    STGA(q, 1, kn); STGA(q, 3, kn);
    MFQ(1, 1);
    // Ph4: pure MFMA; next tile-boundary drain overlaps this cluster
    MFQ(1, 0);
  }
  // peeled last tile: drain everything; no staging.
  VMC(0); BARX();
  LDA(p, 0);
  LDB(p, 0);
  MFQ(0, 0);
  LDB(p, 1);
  MFQ(0, 1);
  LDA(p, 1);
  MFQ(1, 1);
  MFQ(1, 0);

#undef FENCE
#undef VMC
#undef BARX
#undef STGA
#undef STGB
#undef LDA
#undef LDB
#undef MFQ

#pragma unroll
  for (int mi = 0; mi < 8; mi++) {
    const int row = m0 + wm * 128 + mi * 16 + kgrp * 4;
#pragma unroll
    for (int ni = 0; ni < 4; ni++) {
      const int col = n0 + wn * 64 + ni * 16 + l16;
      float bv = (bias && z == 0) ? bias[col] : 0.f;
#pragma unroll
      for (int r = 0; r < 4; r++) {
        float v = acc[mi][ni][r] + bv;
        if (z == 0 && relu) v = fmaxf(v, 0.f);
        size_t idx = (size_t)(row + r) * N + col;
        if (z == 0) {
          if (c0_f32) ((float*)C0)[idx] = v;
          else ((u16*)C0)[idx] = f2bf(v);
        } else if (z == 1) {
          C1[idx] = f2bf(v);
        } else if (z == 2) {
          C2[idx] = f2bf(v);
        } else {
          C3[idx] = f2bf(v);
        }
      }
    }
  }
}

// ---------------------------------------------------------------------------
// G2: 128x64 tile, BK=64, double-buffered (Qproj + small path).
// ---------------------------------------------------------------------------
__global__ __launch_bounds__(256) void gemm_g2(
    const u16* __restrict__ A, const u16* __restrict__ Bt,
    const float* __restrict__ bias, void* __restrict__ C,
    int M, int N, int K, int relu, int accum, int out_f32) {
  __shared__ u16 As[2][8192];
  __shared__ u16 Bs[2][4096];
  const int tid = threadIdx.x;
  const int w = tid >> 6, l = tid & 63;
  const int l16 = l & 15, kgrp = l >> 4;
  const int m0 = blockIdx.y * 128, n0 = blockIdx.x * 64;
  const int wr = (w >> 1) * 64, wc = (w & 1) * 32;

  const int srow = w * 8 + (l >> 3);
  const u16* gA[4];
#pragma unroll
  for (int i = 0; i < 4; i++) {
    int r = i * 32 + srow;
    gA[i] = A + (size_t)(m0 + r) * K + 8 * ((l & 7) ^ (r & 7));
  }
  const u16* gB[2];
#pragma unroll
  for (int i = 0; i < 2; i++) {
    int r = i * 32 + srow;
    gB[i] = Bt + (size_t)(n0 + r) * K + 8 * ((l & 7) ^ (r & 7));
  }

  v4f acc[4][2];
#pragma unroll
  for (int i = 0; i < 4; i++)
#pragma unroll
    for (int j = 0; j < 2; j++)
#pragma unroll
      for (int r = 0; r < 4; r++) acc[i][j][r] = 0.f;

#pragma unroll
  for (int i = 0; i < 4; i++) gl_lds16(gA[i], &As[0][(i * 256 + w * 64) * 8]);
#pragma unroll
  for (int i = 0; i < 2; i++) gl_lds16(gB[i], &Bs[0][(i * 256 + w * 64) * 8]);

  int cur = 0;
  for (int k0 = 0; k0 < K; k0 += 64) {
    __syncthreads();
    if (k0 + 64 < K) {
      int nxt = cur ^ 1;
#pragma unroll
      for (int i = 0; i < 4; i++)
        gl_lds16(gA[i] + k0 + 64, &As[nxt][(i * 256 + w * 64) * 8]);
#pragma unroll
      for (int i = 0; i < 2; i++)
        gl_lds16(gB[i] + k0 + 64, &Bs[nxt][(i * 256 + w * 64) * 8]);
    }
    v8s a[4][2], b[2][2];
#pragma unroll
    for (int ks = 0; ks < 2; ks++) {
      int ch = 8 * ((ks * 4 + kgrp) ^ (l16 & 7));
#pragma unroll
      for (int mi = 0; mi < 4; mi++)
        a[mi][ks] = *(const v8s*)(&As[cur][(wr + mi * 16 + l16) * 64 + ch]);
#pragma unroll
      for (int ni = 0; ni < 2; ni++)
        b[ni][ks] = *(const v8s*)(&Bs[cur][(wc + ni * 16 + l16) * 64 + ch]);
    }
#pragma unroll
    for (int ks = 0; ks < 2; ks++)
#pragma unroll
      for (int mi = 0; mi < 4; mi++)
#pragma unroll
        for (int ni = 0; ni < 2; ni++)
          acc[mi][ni] = __builtin_amdgcn_mfma_f32_16x16x32_bf16(a[mi][ks], b[ni][ks], acc[mi][ni], 0, 0, 0);
    cur ^= 1;
  }

#pragma unroll
  for (int ni = 0; ni < 2; ni++) {
    int col = n0 + wc + ni * 16 + l16;
    float bv = bias ? bias[col] : 0.f;
#pragma unroll
    for (int mi = 0; mi < 4; mi++) {
      int row = m0 + wr + mi * 16 + kgrp * 4;
#pragma unroll
      for (int r = 0; r < 4; r++) {
        float v = acc[mi][ni][r] + bv;
        if (relu) v = fmaxf(v, 0.f);
        size_t idx = (size_t)(row + r) * N + col;
        if (out_f32) {
          float* Cf = (float*)C;
          if (accum) v += Cf[idx];
          Cf[idx] = v;
        } else {
          ((u16*)C)[idx] = f2bf(v);
        }
      }
    }
  }
}

// ---------------------------------------------------------------------------
// attn_split: split-KV attention. 512 threads, 8 waves x 64 q-rows (two
// q-col-blocks per wave, 32x32x16 MFMA, in-register P). Grid (4,32,2):
// x = 512-row q-block, y = (b,h), z = KV-half (1024 cols each).
// Writes unnormalized fp32 O-partials (Op + z*4M floats) and per-(row,h)
// sum-exp (lsp + z*64K floats). attn_combine merges + normalizes.
// Staging identical to R12 (w<4: K, w>=4: V; XOR swizzle).
// ---------------------------------------------------------------------------
__global__ __launch_bounds__(512) void attn_split(
    const u16* __restrict__ Q, const u16* __restrict__ Qt,
    float* __restrict__ Op, float* __restrict__ lsp) {
  __shared__ u16 KV[2][8192];
  const int tid = threadIdx.x;
  const int w = tid >> 6, l = tid & 63;
  const int l31 = l & 31, hi = l >> 5;
  const int bh = blockIdx.y, b = bh >> 4, h = bh & 15;
  const int q0 = blockIdx.x * 512;
  const int z = blockIdx.z;
  const int kv0 = z * 1024;
  const size_t rowQ = (size_t)(b * 2048 + q0 + w * 64);
  const float cexp = 1.4426950408889634f / 45.254833995939045f;

  // staging: wave w<4 stages K rows [16w..16w+16); w>=4 stages V d-rows.
  const int isV = w >> 2, wl = w & 3;
  const int r0 = wl * 16 + (l >> 3);
  const int sch8 = 8 * ((l & 7) ^ (l >> 3));
  const u16* gS0;
  size_t kstep;
  if (!isV) {
    gS0 = Q + (size_t)(b * 2048 + kv0 + r0) * 1024 + h * 64 + sch8;
    kstep = 1024;
  } else {
    gS0 = Qt + (size_t)(h * 64 + r0) * 4096 + b * 2048 + kv0 + sch8;
    kstep = 1;
  }
  const u16* gS1 = gS0 + (size_t)8 * (isV ? 4096 : 1024);
  const int ldst = isV * 4096 + wl * 1024;

  // Q fragments for both q-blocks: q = rowQ + {0,32} + l31, pre-scaled.
  v8s qa[4], qc[4];
#pragma unroll
  for (int t = 0; t < 4; t++) {
    v8s va = *(const v8s*)(Q + (rowQ + l31) * 1024 + h * 64 + t * 16 + hi * 8);
    v8s vc = *(const v8s*)(Q + (rowQ + 32 + l31) * 1024 + h * 64 + t * 16 + hi * 8);
#pragma unroll
    for (int j = 0; j < 8; j++) {
      va[j] = (short)f2bf(bf2f((u16)va[j]) * cexp);
      vc[j] = (short)f2bf(bf2f((u16)vc[j]) * cexp);
    }
    qa[t] = va; qc[t] = vc;
  }

  v16f oA0, oA1, oB0, oB1;
#pragma unroll
  for (int r = 0; r < 16; r++) { oA0[r] = 0.f; oA1[r] = 0.f; oB0[r] = 0.f; oB1[r] = 0.f; }
  float lsA = 0.f, lsB = 0.f;

  gl_lds16(gS0, &KV[0][ldst]);
  gl_lds16(gS1, &KV[0][ldst + 512]);

  int cur = 0;
  for (int kb = 0; kb < 1024; kb += 64) {
    __syncthreads();
    if (kb + 64 < 1024) {
      int nxt = cur ^ 1;
      gl_lds16(gS0 + (size_t)(kb + 64) * kstep, &KV[nxt][ldst]);
      gl_lds16(gS1 + (size_t)(kb + 64) * kstep, &KV[nxt][ldst + 512]);
    }
    const u16* Ks = &KV[cur][0];
    const u16* Vt = &KV[cur][4096];

    // QK^T: s[kblock][qblock]
    v16f s00, s10, s01, s11;
#pragma unroll
    for (int r = 0; r < 16; r++) { s00[r] = 0.f; s10[r] = 0.f; s01[r] = 0.f; s11[r] = 0.f; }
    __builtin_amdgcn_s_setprio(1);
#pragma unroll
    for (int t = 0; t < 4; t++) {
      const int c = 8 * ((2 * t + hi) ^ (l & 7));
      v8s ka0 = *(const v8s*)(Ks + l31 * 64 + c);
      v8s ka1 = *(const v8s*)(Ks + (32 + l31) * 64 + c);
      s00 = __builtin_amdgcn_mfma_f32_32x32x16_bf16(ka0, qa[t], s00, 0, 0, 0);
      s10 = __builtin_amdgcn_mfma_f32_32x32x16_bf16(ka1, qa[t], s10, 0, 0, 0);
      s01 = __builtin_amdgcn_mfma_f32_32x32x16_bf16(ka0, qc[t], s01, 0, 0, 0);
      s11 = __builtin_amdgcn_mfma_f32_32x32x16_bf16(ka1, qc[t], s11, 0, 0, 0);
    }
    __builtin_amdgcn_s_setprio(0);

    float pA0[16], pA1[16], pB0[16], pB1[16];
#pragma unroll
    for (int r = 0; r < 16; r++) {
      pA0[r] = __builtin_amdgcn_exp2f(s00[r]);
      pA1[r] = __builtin_amdgcn_exp2f(s10[r]);
      pB0[r] = __builtin_amdgcn_exp2f(s01[r]);
      pB1[r] = __builtin_amdgcn_exp2f(s11[r]);
      lsA += pA0[r] + pA1[r];
      lsB += pB0[r] + pB1[r];
    }

    // PV: 4 k-chunks of 16; P operands via perm-pack + permlane32_swap,
    // V fragments shared across both q-blocks.
#define PACKP(P, out) { \
      const int off = 8 * ((tt) & 1); \
      uint32_t dw00 = __builtin_amdgcn_perm(fbits(P[off + 1]), fbits(P[off + 0]), 0x07060302u); \
      uint32_t dw01 = __builtin_amdgcn_perm(fbits(P[off + 3]), fbits(P[off + 2]), 0x07060302u); \
      uint32_t dw10 = __builtin_amdgcn_perm(fbits(P[off + 5]), fbits(P[off + 4]), 0x07060302u); \
      uint32_t dw11 = __builtin_amdgcn_perm(fbits(P[off + 7]), fbits(P[off + 6]), 0x07060302u); \
      v2u sA_ = __builtin_amdgcn_permlane32_swap(dw00, dw10, false, false); \
      v2u sB_ = __builtin_amdgcn_permlane32_swap(dw01, dw11, false, false); \
      out.u[0] = sA_[0]; out.u[1] = sB_[0]; out.u[2] = sA_[1]; out.u[3] = sB_[1]; }
#define PVSTEP(t, PA, PB) { \
      const int tt = (t); \
      union { uint32_t u[4]; v8s v; } paA, paB; \
      PACKP(PA, paA); \
      PACKP(PB, paB); \
      const int c = 8 * ((2 * tt + hi) ^ (l & 7)); \
      v8s vb0 = *(const v8s*)(Vt + l31 * 64 + c); \
      v8s vb1 = *(const v8s*)(Vt + (32 + l31) * 64 + c); \
      __builtin_amdgcn_s_setprio(1); \
      oA0 = __builtin_amdgcn_mfma_f32_32x32x16_bf16(paA.v, vb0, oA0, 0, 0, 0); \
      oA1 = __builtin_amdgcn_mfma_f32_32x32x16_bf16(paA.v, vb1, oA1, 0, 0, 0); \
      oB0 = __builtin_amdgcn_mfma_f32_32x32x16_bf16(paB.v, vb0, oB0, 0, 0, 0); \
      oB1 = __builtin_amdgcn_mfma_f32_32x32x16_bf16(paB.v, vb1, oB1, 0, 0, 0); \
      __builtin_amdgcn_s_setprio(0); }
    PVSTEP(0, pA0, pB0)
    PVSTEP(1, pA0, pB0)
    PVSTEP(2, pA1, pB1)
    PVSTEP(3, pA1, pB1)
#undef PVSTEP
#undef PACKP
    cur ^= 1;
  }

  lsA += __shfl_xor(lsA, 32, 64);   // full den for q=l31 at every lane
  lsB += __shfl_xor(lsB, 32, 64);

  float* OPz = Op + (size_t)z * 4194304;   // 4096*1024 floats per half
#pragma unroll
  for (int r = 0; r < 16; r++) {
    const int qo = (r & 3) + 8 * (r >> 2) + hi * 4;
    OPz[(rowQ + qo) * 1024 + h * 64 + l31] = oA0[r];
    OPz[(rowQ + qo) * 1024 + h * 64 + 32 + l31] = oA1[r];
    OPz[(rowQ + 32 + qo) * 1024 + h * 64 + l31] = oB0[r];
    OPz[(rowQ + 32 + qo) * 1024 + h * 64 + 32 + l31] = oB1[r];
  }
  if (hi == 0) {
    lsp[(size_t)z * 65536 + (rowQ + l31) * 16 + h] = lsA;
    lsp[(size_t)z * 65536 + (rowQ + 32 + l31) * 16 + h] = lsB;
  }
}

// ---------------------------------------------------------------------------
// attn_combine: O = (Op0 + Op1) / (ls0 + ls1), bf16 out. One block per row.
// ---------------------------------------------------------------------------
__global__ __launch_bounds__(256) void attn_combine(
    const float* __restrict__ Op, const float* __restrict__ lsp,
    u16* __restrict__ O) {
  const int row = blockIdx.x, tid = threadIdx.x;
  const size_t base = (size_t)row * 1024;
#pragma unroll
  for (int i = 0; i < 4; i++) {
    int c = tid + i * 256;
    int h = c >> 6;
    float den = lsp[(size_t)row * 16 + h] + lsp[65536 + (size_t)row * 16 + h];
    float o = Op[base + c] + Op[4194304 + base + c];
    O[base + c] = f2bf(o / den);
  }
}

// ---------------------------------------------------------------------------
// attn_kernel (R12, proven): small-ws path. 512 threads, 8 waves x 32 q-rows,
// 32x32x16 MFMA, in-register P. Grid (8, 32).
// ---------------------------------------------------------------------------
__global__ __launch_bounds__(512) void attn_kernel(
    const u16* __restrict__ Q, const u16* __restrict__ Qt,
    u16* __restrict__ O) {
  __shared__ u16 KV[2][8192];
  const int tid = threadIdx.x;
  const int w = tid >> 6, l = tid & 63;
  const int l31 = l & 31, hi = l >> 5;
  const int bh = blockIdx.y, b = bh >> 4, h = bh & 15;
  const int q0 = blockIdx.x * 256;
  const size_t rowQ = (size_t)(b * 2048 + q0 + w * 32);
  const float cexp = 1.4426950408889634f / 45.254833995939045f;

  const int isV = w >> 2, wl = w & 3;
  const int r0 = wl * 16 + (l >> 3);
  const int sch8 = 8 * ((l & 7) ^ (l >> 3));
  const u16* gS0;
  size_t kstep;
  if (!isV) {
    gS0 = Q + (size_t)(b * 2048 + r0) * 1024 + h * 64 + sch8;
    kstep = 1024;
  } else {
    gS0 = Qt + (size_t)(h * 64 + r0) * 4096 + b * 2048 + sch8;
    kstep = 1;
  }
  const u16* gS1 = gS0 + (size_t)8 * (isV ? 4096 : 1024);
  const int ldst = isV * 4096 + wl * 1024;

  v8s qb[4];
#pragma unroll
  for (int t = 0; t < 4; t++) {
    v8s v = *(const v8s*)(Q + (rowQ + l31) * 1024 + h * 64 + t * 16 + hi * 8);
#pragma unroll
    for (int j = 0; j < 8; j++) v[j] = (short)f2bf(bf2f((u16)v[j]) * cexp);
    qb[t] = v;
  }

  v16f o0, o1;
#pragma unroll
  for (int r = 0; r < 16; r++) { o0[r] = 0.f; o1[r] = 0.f; }
  float ls = 0.f;

  gl_lds16(gS0, &KV[0][ldst]);
  gl_lds16(gS1, &KV[0][ldst + 512]);

  int cur = 0;
  for (int kb = 0; kb < 2048; kb += 64) {
    __syncthreads();
    if (kb + 64 < 2048) {
      int nxt = cur ^ 1;
      gl_lds16(gS0 + (size_t)(kb + 64) * kstep, &KV[nxt][ldst]);
      gl_lds16(gS1 + (size_t)(kb + 64) * kstep, &KV[nxt][ldst + 512]);
    }
    const u16* Ks = &KV[cur][0];
    const u16* Vt = &KV[cur][4096];

    v16f s0, s1;
#pragma unroll
    for (int r = 0; r < 16; r++) { s0[r] = 0.f; s1[r] = 0.f; }
#pragma unroll
    for (int t = 0; t < 4; t++) {
      const int c = 8 * ((2 * t + hi) ^ (l & 7));
      v8s ka0 = *(const v8s*)(Ks + l31 * 64 + c);
      v8s ka1 = *(const v8s*)(Ks + (32 + l31) * 64 + c);
      s0 = __builtin_amdgcn_mfma_f32_32x32x16_bf16(ka0, qb[t], s0, 0, 0, 0);
      s1 = __builtin_amdgcn_mfma_f32_32x32x16_bf16(ka1, qb[t], s1, 0, 0, 0);
    }

    float p0[16], p1[16];
#pragma unroll
    for (int r = 0; r < 16; r++) {
      p0[r] = __builtin_amdgcn_exp2f(s0[r]);
      p1[r] = __builtin_amdgcn_exp2f(s1[r]);
      ls += p0[r] + p1[r];
    }

#define PVSTEP(t, P) { \
      const int off = 8 * ((t) & 1); \
      uint32_t dw00 = __builtin_amdgcn_perm(fbits(P[off + 1]), fbits(P[off + 0]), 0x07060302u); \
      uint32_t dw01 = __builtin_amdgcn_perm(fbits(P[off + 3]), fbits(P[off + 2]), 0x07060302u); \
      uint32_t dw10 = __builtin_amdgcn_perm(fbits(P[off + 5]), fbits(P[off + 4]), 0x07060302u); \
      uint32_t dw11 = __builtin_amdgcn_perm(fbits(P[off + 7]), fbits(P[off + 6]), 0x07060302u); \
      v2u sA = __builtin_amdgcn_permlane32_swap(dw00, dw10, false, false); \
      v2u sB = __builtin_amdgcn_permlane32_swap(dw01, dw11, false, false); \
      union { uint32_t u[4]; v8s v; } pa; \
      pa.u[0] = sA[0]; pa.u[1] = sB[0]; pa.u[2] = sA[1]; pa.u[3] = sB[1]; \
      const int c = 8 * ((2 * (t) + hi) ^ (l & 7)); \
      v8s vb0 = *(const v8s*)(Vt + l31 * 64 + c); \
      v8s vb1 = *(const v8s*)(Vt + (32 + l31) * 64 + c); \
      o0 = __builtin_amdgcn_mfma_f32_32x32x16_bf16(pa.v, vb0, o0, 0, 0, 0); \
      o1 = __builtin_amdgcn_mfma_f32_32x32x16_bf16(pa.v, vb1, o1, 0, 0, 0); }
    PVSTEP(0, p0)
    PVSTEP(1, p0)
    PVSTEP(2, p1)
    PVSTEP(3, p1)
#undef PVSTEP
    cur ^= 1;
  }

  ls += __shfl_xor(ls, 32, 64);

  const int hiq = hi * 4;
#pragma unroll
  for (int r = 0; r < 16; r++) {
    const int qo = (r & 3) + 8 * (r >> 2) + hiq;
    float den = __shfl(ls, qo, 64);
    float rden = 1.f / den;
    O[(rowQ + qo) * 1024 + h * 64 + l31] = f2bf(o0[r] * rden);
    O[(rowQ + qo) * 1024 + h * 64 + 32 + l31] = f2bf(o1[r] * rden);
  }
}

// ---------------------------------------------------------------------------
// out = LayerNorm(Y [+ Y2 + Y3 + Y4] + Xr) * g + b; row length 1024; dtype
// flags (1 = fp32, 0 = bf16). Y2/Y3/Y4 nullable (Y3/Y4 always bf16).
// In-place safe.
// ---------------------------------------------------------------------------
__global__ __launch_bounds__(256) void ln_residual(
    const void* __restrict__ Y, const void* __restrict__ Y2,
    const void* __restrict__ Y3, const void* __restrict__ Y4,
    const void* __restrict__ Xr,
    const float* __restrict__ g, const float* __restrict__ bb,
    void* __restrict__ out, int yf, int y2f, int xf, int of) {
  const int row = blockIdx.x, tid = threadIdx.x;
  const size_t base = (size_t)row * 1024;
  float v[4], s = 0.f, sq = 0.f;
#pragma unroll
  for (int i = 0; i < 4; i++) {
    int c = tid + i * 256;
    float ya = yf ? ((const float*)Y)[base + c] : bf2f(((const u16*)Y)[base + c]);
    float xa = xf ? ((const float*)Xr)[base + c] : bf2f(((const u16*)Xr)[base + c]);
    float x = ya + xa;
    if (Y2) {
      float y2a = y2f ? ((const float*)Y2)[base + c] : bf2f(((const u16*)Y2)[base + c]);
      x += y2a;
    }
    if (Y3) x += bf2f(((const u16*)Y3)[base + c]);
    if (Y4) x += bf2f(((const u16*)Y4)[base + c]);
    v[i] = x; s += x; sq += x * x;
  }
#pragma unroll
  for (int off = 32; off >= 1; off >>= 1) {
    s += __shfl_down(s, off, 64);
    sq += __shfl_down(sq, off, 64);
  }
  __shared__ float rs[4], rq[4];
  const int w = tid >> 6, l = tid & 63;
  if (l == 0) { rs[w] = s; rq[w] = sq; }
  __syncthreads();
  s = rs[0] + rs[1] + rs[2] + rs[3];
  sq = rq[0] + rq[1] + rq[2] + rq[3];
  const float mu = s * (1.f / 1024.f);
  const float var = sq * (1.f / 1024.f) - mu * mu;
  const float rstd = rsqrtf(var + 1e-5f);
#pragma unroll
  for (int i = 0; i < 4; i++) {
    int c = tid + i * 256;
    float r = (v[i] - mu) * rstd * g[c] + bb[c];
    if (of) ((float*)out)[base + c] = r;
    else ((u16*)out)[base + c] = f2bf(r);
  }
}

// ---------------------------------------------------------------------------
extern "C" void kernel_launch(void* const* d_in, const int* in_sizes, int n_in,
                              void* d_out, int out_size, void* d_ws, size_t ws_size,
                              hipStream_t stream) {
  const float* x   = (const float*)d_in[0];
  const float* Wq  = (const float*)d_in[1];
  const float* bq  = (const float*)d_in[2];
  const float* Wo  = (const float*)d_in[3];
  const float* bo  = (const float*)d_in[4];
  const float* g1  = (const float*)d_in[5];
  const float* be1 = (const float*)d_in[6];
  const float* W1  = (const float*)d_in[7];
  const float* b1  = (const float*)d_in[8];
  const float* W2  = (const float*)d_in[9];
  const float* b2  = (const float*)d_in[10];
  const float* g2  = (const float*)d_in[11];
  const float* be2 = (const float*)d_in[12];
  float* out = (float*)d_out;
  u16* ws  = (u16*)d_ws;

  const size_t M1 = 1048576;
  dim3 blk(256);
  dim3 blk8(512);
  const bool big = ws_size >= (size_t)37 * M1 * 2;  // 74 MiB

  if (big) {
    u16* xb   = ws + 0;          // [0..4M)  -> attn -> P2_ffn2
    u16* Qb   = ws + 4 * M1;     // [4..8M)  -> x1
    u16* Qt   = ws + 8 * M1;     // [8..12M) -> Yb (Wo P0) -> P1_ffn2
    u16* WqT  = ws + 12 * M1;    // [12..13M) -> WoT
    u16* W1T  = ws + 13 * M1;    // [13..17M) Op0(lo) -> W1T -> P3_ffn2
    u16* W2T  = ws + 17 * M1;    // [17..21M) Op0(hi) -> W2T
    u16* Hh   = ws + 21 * M1;    // [21..37M) Op1+lsp -> Hh
    u16* attn = xb;  u16* Yb = Qt;  u16* x1 = Qb;  u16* WoT = WqT;
    // attn split-KV partials: [13..29M) fp32 O-partials (2 x 16MB), lsp at
    // [29..29.25M). All dead-after-combine; overwritten by W1T/W2T/Hh later.
    float* Opart = (float*)(ws + 13 * M1);
    float* lspart = (float*)(ws + 29 * M1);
    // Wo split-4 partials: dead regions until later writers run (all after LN1)
    u16* P1wo = W1T;             // overwritten by transpose(W1) after LN1
    u16* P2wo = W2T;             // overwritten by transpose(W2) after FFN1
    u16* P3wo = Hh;              // overwritten by FFN1 after LN1
    // FFN2 split-4 partials: dead after their last reads
    u16* P1f2 = Qt;              // Yb dead after LN1
    u16* P2f2 = xb;              // attn dead after Wo-proj
    u16* P3f2 = W1T;             // W1T dead after FFN1

    cvt_f2b<<<dim3(4096), blk, 0, stream>>>(x, xb, 1048576);
    transpose_f2b<<<dim3(32, 32), blk, 0, stream>>>(Wq, WqT, 1024, 1024, 1024, 1024);
    gemm_g2<<<dim3(16, 32), blk, 0, stream>>>(xb, WqT, bq, Qb, 4096, 1024, 1024, 0, 0, 0);

    transpose_b2b<<<dim3(32, 128), blk, 0, stream>>>(Qb, Qt, 4096, 1024, 1024, 4096);
    attn_split<<<dim3(4, 32, 2), blk8, 0, stream>>>(Qb, Qt, Opart, lspart);
    attn_combine<<<dim3(4096), blk, 0, stream>>>(Opart, lspart, attn);

    // Wo projection: split-K=4 phase-pipelined 256x256, P0 -> Yb (bf16, +bias)
    transpose_f2b<<<dim3(32, 32), blk, 0, stream>>>(Wo, WoT, 1024, 1024, 1024, 1024);
    gemm_8p<<<dim3(4, 16, 4), blk8, 0, stream>>>(attn, WoT, bo, Yb, P1wo, P2wo, P3wo,
                                                 4096, 1024, 1024, 256, 0, 0);
    ln_residual<<<dim3(4096), blk, 0, stream>>>(Yb, P1wo, P2wo, P3wo, x, g1, be1, x1,
                                                0, 0, 1, 0);

    // FFN1: full-K phase-pipelined 256x256 (grid 256 = 1 block/CU)
    transpose_f2b<<<dim3(128, 32), blk, 0, stream>>>(W1, W1T, 1024, 4096, 4096, 1024);
    gemm_8p<<<dim3(16, 16, 1), blk8, 0, stream>>>(x1, W1T, b1, Hh,
                                                  nullptr, nullptr, nullptr,
                                                  4096, 4096, 1024, 1024, 1, 0);

    // FFN2: split-K=4 phase-pipelined 256x256, P0 -> out (fp32, +bias)
    transpose_f2b<<<dim3(32, 128), blk, 0, stream>>>(W2, W2T, 4096, 1024, 1024, 4096);
    gemm_8p<<<dim3(4, 16, 4), blk8, 0, stream>>>(Hh, W2T, b2, out, P1f2, P2f2, P3f2,
                                                 4096, 1024, 4096, 1024, 0, 1);

    ln_residual<<<dim3(4096), blk, 0, stream>>>(out, P1f2, P2f2, P3f2, x1, g2, be2, out,
                                                1, 0, 0, 1);
  } else {
    u16* xb   = ws + 0;
    u16* Qb   = ws + 4 * M1;
    u16* Qt   = ws + 8 * M1;
    u16* attn = xb;  u16* Yb = Qt;  u16* x1 = Qb;  u16* Hc = xb;
    u16* Wt1  = ws + 12 * M1;
    u16* Wt2  = ws + 13 * M1;

    cvt_f2b<<<dim3(4096), blk, 0, stream>>>(x, xb, 1048576);
    transpose_f2b<<<dim3(32, 32), blk, 0, stream>>>(Wq, Wt1, 1024, 1024, 1024, 1024);
    gemm_g2<<<dim3(16, 32), blk, 0, stream>>>(xb, Wt1, bq, Qb, 4096, 1024, 1024, 0, 0, 0);

    transpose_b2b<<<dim3(32, 128), blk, 0, stream>>>(Qb, Qt, 4096, 1024, 1024, 4096);
    attn_kernel<<<dim3(8, 32), blk8, 0, stream>>>(Qb, Qt, attn);

    transpose_f2b<<<dim3(32, 32), blk, 0, stream>>>(Wo, Wt2, 1024, 1024, 1024, 1024);
    gemm_g2<<<dim3(16, 32), blk, 0, stream>>>(attn, Wt2, bo, Yb, 4096, 1024, 1024, 0, 0, 0);
    ln_residual<<<dim3(4096), blk, 0, stream>>>(Yb, nullptr, nullptr, nullptr, x, g1, be1,
                                                x1, 0, 0, 1, 0);

    for (int c = 0; c < 4; c++) {
      transpose_f2b<<<dim3(32, 32), blk, 0, stream>>>(W1 + (size_t)c * 1024, Wt1,
                                                      1024, 1024, 4096, 1024);
      gemm_g2<<<dim3(16, 32), blk, 0, stream>>>(x1, Wt1, b1 + (size_t)c * 1024, Hc,
                                                4096, 1024, 1024, 1, 0, 0);
      transpose_f2b<<<dim3(32, 32), blk, 0, stream>>>(W2 + (size_t)c * M1, Wt2,
                                                      1024, 1024, 1024, 1024);
      gemm_g2<<<dim3(16, 32), blk, 0, stream>>>(Hc, Wt2, (c == 0) ? b2 : (const float*)nullptr,
                                                out, 4096, 1024, 1024, 0, (c > 0) ? 1 : 0, 1);
    }
    ln_residual<<<dim3(4096), blk, 0, stream>>>(out, nullptr, nullptr, nullptr, x1, g2, be2,
                                                out, 1, 0, 0, 1);
  }
}

// Round 10
// 321.859 us; speedup vs baseline: 1.0619x; 1.0616x over previous
//
#include <hip/hip_runtime.h>
#include <stdint.h>

// B=2, S=2048, D=1024, H=16, DK=64, DH=4096. I/O fp32; internals bf16 MFMA.
// R17: revert attention to R12 (proven 48.9; R16's split-KV regressed via
// partial-traffic). Add: (1) prep_all fused kernel (input cvt + all 4 weight
// transposes, 14 -> 9 launches; ws re-layout, liveness re-verified);
// (2) XCD-aware bijective block swizzle on attention (K/V L2 locality,
// FETCH 68.7 -> ~30 MB predicted). GEMMs frozen at R14 (wait-at-consumption
// counted vmcnt + XCD swizzle).

typedef unsigned short u16;
typedef __attribute__((ext_vector_type(8))) short v8s;   // 8 x bf16
typedef __attribute__((ext_vector_type(4))) float v4f;
typedef __attribute__((ext_vector_type(16))) float v16f;
typedef __attribute__((ext_vector_type(2))) unsigned int v2u;

#define AS1 __attribute__((address_space(1)))
#define AS3 __attribute__((address_space(3)))

__device__ __forceinline__ void gl_lds16(const u16* g, u16* l) {
  __builtin_amdgcn_global_load_lds((const AS1 void*)g, (AS3 void*)l, 16, 0, 0);
}

__device__ __forceinline__ float bf2f(u16 u) {
  union { uint32_t i; float f; } v; v.i = ((uint32_t)u) << 16; return v.f;
}
__device__ __forceinline__ u16 f2bf(float f) {
  union { float f; uint32_t i; } v; v.f = f;
  uint32_t x = v.i;
  return (u16)((x + 0x7FFFu + ((x >> 16) & 1u)) >> 16);  // RNE
}
__device__ __forceinline__ uint32_t fbits(float f) {
  union { float f; uint32_t u; } v; v.f = f; return v.u;
}

// ---------------------------------------------------------------------------
__global__ __launch_bounds__(256) void cvt_f2b(
    const float* __restrict__ src, u16* __restrict__ dst, int n4) {
  int i = (blockIdx.x * 256 + threadIdx.x);
  if (i < n4) {
    float4 v = *(const float4*)(src + (size_t)i * 4);
    ushort4 o;
    o.x = f2bf(v.x); o.y = f2bf(v.y); o.z = f2bf(v.z); o.w = f2bf(v.w);
    *(ushort4*)(dst + (size_t)i * 4) = o;
  }
}

// ---------------------------------------------------------------------------
// prep_all: fused input-stage kernel (big path). Blocks:
//   [0,1024)      Wq  (1024x1024) -> WqT
//   [1024,2048)   Wo  (1024x1024) -> WoT
//   [2048,6144)   W1  (1024x4096) -> W1T  (grid 128x32 flattened)
//   [6144,10240)  W2  (4096x1024) -> W2T  (grid 32x128 flattened)
//   [10240,14336) x fp32 -> xb bf16 (elementwise, 1M float4)
// ---------------------------------------------------------------------------
__global__ __launch_bounds__(256) void prep_all(
    const float* __restrict__ x, const float* __restrict__ Wq,
    const float* __restrict__ Wo, const float* __restrict__ W1,
    const float* __restrict__ W2, u16* __restrict__ xb,
    u16* __restrict__ WqT, u16* __restrict__ WoT,
    u16* __restrict__ W1T, u16* __restrict__ W2T) {
  const int r = blockIdx.x;
  const int tid = threadIdx.x;
  if (r >= 10240) {
    int i = (r - 10240) * 256 + tid;
    float4 v = *(const float4*)(x + (size_t)i * 4);
    ushort4 o;
    o.x = f2bf(v.x); o.y = f2bf(v.y); o.z = f2bf(v.z); o.w = f2bf(v.w);
    *(ushort4*)(xb + (size_t)i * 4) = o;
    return;
  }
  __shared__ float tile[32][33];
  const float* src; u16* dst; int ld_s, ld_d, bx, by;
  if (r < 1024)      { src = Wq; dst = WqT; ld_s = 1024; ld_d = 1024; bx = r & 31; by = r >> 5; }
  else if (r < 2048) { int r2 = r - 1024; src = Wo; dst = WoT; ld_s = 1024; ld_d = 1024; bx = r2 & 31; by = r2 >> 5; }
  else if (r < 6144) { int r2 = r - 2048; src = W1; dst = W1T; ld_s = 4096; ld_d = 1024; bx = r2 & 127; by = r2 >> 7; }
  else               { int r2 = r - 6144; src = W2; dst = W2T; ld_s = 1024; ld_d = 4096; bx = r2 & 31; by = r2 >> 5; }
  const int tx = tid & 31, ty = tid >> 5;
  const int c0 = bx * 32, r0 = by * 32;
#pragma unroll
  for (int j = 0; j < 32; j += 8)
    tile[ty + j][tx] = src[(size_t)(r0 + ty + j) * ld_s + c0 + tx];
  __syncthreads();
#pragma unroll
  for (int j = 0; j < 32; j += 8)
    dst[(size_t)(c0 + ty + j) * ld_d + r0 + tx] = f2bf(tile[tx][ty + j]);
}

// ---------------------------------------------------------------------------
__global__ __launch_bounds__(256) void transpose_f2b(
    const float* __restrict__ src, u16* __restrict__ dst,
    int R, int C, int ld_s, int ld_d) {
  __shared__ float tile[32][33];
  const int tx = threadIdx.x & 31, ty = threadIdx.x >> 5;
  const int c0 = blockIdx.x * 32, r0 = blockIdx.y * 32;
#pragma unroll
  for (int j = 0; j < 32; j += 8)
    tile[ty + j][tx] = src[(size_t)(r0 + ty + j) * ld_s + c0 + tx];
  __syncthreads();
#pragma unroll
  for (int j = 0; j < 32; j += 8)
    dst[(size_t)(c0 + ty + j) * ld_d + r0 + tx] = f2bf(tile[tx][ty + j]);
}

__global__ __launch_bounds__(256) void transpose_b2b(
    const u16* __restrict__ src, u16* __restrict__ dst,
    int R, int C, int ld_s, int ld_d) {
  __shared__ u16 tile[32][33];
  const int tx = threadIdx.x & 31, ty = threadIdx.x >> 5;
  const int c0 = blockIdx.x * 32, r0 = blockIdx.y * 32;
#pragma unroll
  for (int j = 0; j < 32; j += 8)
    tile[ty + j][tx] = src[(size_t)(r0 + ty + j) * ld_s + c0 + tx];
  __syncthreads();
#pragma unroll
  for (int j = 0; j < 32; j += 8)
    dst[(size_t)(c0 + ty + j) * ld_d + r0 + tx] = tile[tx][ty + j];
}

// ---------------------------------------------------------------------------
// gemm_8p: 256x256 tile, BK=64, 512 threads (8 waves: 2M x 4N), 128 KiB LDS.
// Wait-at-consumption schedule (2 barriers/K-tile), counted vmcnt never 0 in
// steady state. XCD-aware bijective block swizzle. (R14, proven)
// z==0 -> C0 (+bias, relu, fp32 or bf16); z=1..3 -> C1/C2/C3 bf16 partials.
// ---------------------------------------------------------------------------
__global__ __launch_bounds__(512, 1) void gemm_8p(
    const u16* __restrict__ A, const u16* __restrict__ Bt,
    const float* __restrict__ bias, void* __restrict__ C0,
    u16* __restrict__ C1, u16* __restrict__ C2, u16* __restrict__ C3,
    int M, int N, int ldk, int klen, int relu, int c0_f32) {
  __shared__ u16 As[2][16384];   // [buf][row*64 + elem], 256 rows x 64 k
  __shared__ u16 Bs[2][16384];
  const int tid = threadIdx.x;
  const int w = tid >> 6, l = tid & 63;
  const int l16 = l & 15, kgrp = (l >> 4) & 3;
  const int wm = w >> 2, wn = w & 3;

  // XCD-aware bijective swizzle over full linear id (all launches nwg%8==0)
  const int gx = gridDim.x, gyd = gridDim.y;
  const int nxy = gx * gyd;
  const int nwg = nxy * gridDim.z;
  int lin = blockIdx.x + gx * (blockIdx.y + gyd * blockIdx.z);
  if ((nwg & 7) == 0) lin = (lin & 7) * (nwg >> 3) + (lin >> 3);
  const int z = lin / nxy;
  const int rem = lin - z * nxy;
  const int by = rem / gx;
  const int bx = rem - by * gx;
  const int m0 = by * 256, n0 = bx * 256;
  const int NT = klen >> 6;

  const int rl = tid >> 3;
  const int sw = 8 * ((tid & 7) ^ (rl & 7));
  const u16* gA[4]; const u16* gB[4];
#pragma unroll
  for (int j = 0; j < 4; j++) {
    gA[j] = A + (size_t)(m0 + j * 64 + rl) * ldk + (size_t)z * klen + sw;
    gB[j] = Bt + (size_t)(n0 + j * 64 + rl) * ldk + (size_t)z * klen + sw;
  }
  const int sdst = w * 512;   // wave-uniform LDS base (+ j*4096)

  const int ch0 = 8 * ((kgrp) ^ (l16 & 7));
  const int ch1 = 8 * ((4 + kgrp) ^ (l16 & 7));
  const int abase = (wm * 128 + l16) * 64;
  const int bbase = (wn * 64 + l16) * 64;

  v4f acc[8][4];
#pragma unroll
  for (int i = 0; i < 8; i++)
#pragma unroll
    for (int j = 0; j < 4; j++)
#pragma unroll
      for (int r = 0; r < 4; r++) acc[i][j][r] = 0.f;

  v8s a[4][2], b[4][2];

#define FENCE() asm volatile("" ::: "memory")
#define VMC(n) asm volatile("s_waitcnt vmcnt(" #n ")" ::: "memory")
#define BARX() { __builtin_amdgcn_s_barrier(); \
                 __builtin_amdgcn_sched_barrier(0); FENCE(); }
#define STGA(q, j, kt) gl_lds16(gA[j] + (size_t)(kt) * 64, &As[q][(j) * 4096 + sdst])
#define STGB(q, j, kt) gl_lds16(gB[j] + (size_t)(kt) * 64, &Bs[q][(j) * 4096 + sdst])
#define LDA(p, mh) { \
  const u16* Ap = &As[p][abase + (mh) * 4096]; \
  _Pragma("unroll") for (int mi = 0; mi < 4; mi++) { \
    a[mi][0] = *(const v8s*)(Ap + mi * 1024 + ch0); \
    a[mi][1] = *(const v8s*)(Ap + mi * 1024 + ch1); } }
#define LDB(p, nh) { \
  const u16* Bp = &Bs[p][bbase + (nh) * 2048]; \
  _Pragma("unroll") for (int ni = 0; ni < 2; ni++) { \
    b[(nh) * 2 + ni][0] = *(const v8s*)(Bp + ni * 1024 + ch0); \
    b[(nh) * 2 + ni][1] = *(const v8s*)(Bp + ni * 1024 + ch1); } }
#define MFQ(mh, nh) { \
  __builtin_amdgcn_s_setprio(1); \
  _Pragma("unroll") for (int ks = 0; ks < 2; ks++) \
  _Pragma("unroll") for (int mi = 0; mi < 4; mi++) \
  _Pragma("unroll") for (int ni = 0; ni < 2; ni++) \
    acc[(mh) * 4 + mi][(nh) * 2 + ni] = __builtin_amdgcn_mfma_f32_16x16x32_bf16( \
        a[mi][ks], b[(nh) * 2 + ni][ks], acc[(mh) * 4 + mi][(nh) * 2 + ni], 0, 0, 0); \
  __builtin_amdgcn_s_setprio(0); }

  // prologue: stage tile 0 into buf0, need-first order: A02, B01, B23, A13.
  STGA(0, 0, 0); STGA(0, 2, 0);
  FENCE();
  STGB(0, 0, 0); STGB(0, 1, 0);
  FENCE();
  STGB(0, 2, 0); STGB(0, 3, 0);
  FENCE();
  STGA(0, 1, 0); STGA(0, 3, 0);

  int p = 0;
  for (int kt = 0; kt < NT - 1; ++kt, p ^= 1) {
    const int q = p ^ 1;
    const int kn = kt + 1;
    // Ph1: A02/B01/B23(kt) landed; A13(kt) still in flight
    VMC(2); BARX();
    LDA(p, 0);
    LDB(p, 0);
    FENCE();
    STGA(q, 0, kn); STGA(q, 2, kn);
    MFQ(0, 0);
    // Ph2: issue all B stages of kt+1 (B23 gets 3 phases of flight)
    LDB(p, 1);
    FENCE();
    STGB(q, 0, kn); STGB(q, 1, kn);
    STGB(q, 2, kn); STGB(q, 3, kn);
    MFQ(0, 1);
    // Ph3: retire A13(kt) (oldest 2 of 8 in flight)
    VMC(6); BARX();
    LDA(p, 1);
    FENCE();
    STGA(q, 1, kn); STGA(q, 3, kn);
    MFQ(1, 1);
    // Ph4: pure MFMA; next tile-boundary drain overlaps this cluster
    MFQ(1, 0);
  }
  // peeled last tile: drain everything; no staging.
  VMC(0); BARX();
  LDA(p, 0);
  LDB(p, 0);
  MFQ(0, 0);
  LDB(p, 1);
  MFQ(0, 1);
  LDA(p, 1);
  MFQ(1, 1);
  MFQ(1, 0);

#undef FENCE
#undef VMC
#undef BARX
#undef STGA
#undef STGB
#undef LDA
#undef LDB
#undef MFQ

#pragma unroll
  for (int mi = 0; mi < 8; mi++) {
    const int row = m0 + wm * 128 + mi * 16 + kgrp * 4;
#pragma unroll
    for (int ni = 0; ni < 4; ni++) {
      const int col = n0 + wn * 64 + ni * 16 + l16;
      float bv = (bias && z == 0) ? bias[col] : 0.f;
#pragma unroll
      for (int r = 0; r < 4; r++) {
        float v = acc[mi][ni][r] + bv;
        if (z == 0 && relu) v = fmaxf(v, 0.f);
        size_t idx = (size_t)(row + r) * N + col;
        if (z == 0) {
          if (c0_f32) ((float*)C0)[idx] = v;
          else ((u16*)C0)[idx] = f2bf(v);
        } else if (z == 1) {
          C1[idx] = f2bf(v);
        } else if (z == 2) {
          C2[idx] = f2bf(v);
        } else {
          C3[idx] = f2bf(v);
        }
      }
    }
  }
}

// ---------------------------------------------------------------------------
// G2: 128x64 tile, BK=64, double-buffered (Qproj + small path).
// ---------------------------------------------------------------------------
__global__ __launch_bounds__(256) void gemm_g2(
    const u16* __restrict__ A, const u16* __restrict__ Bt,
    const float* __restrict__ bias, void* __restrict__ C,
    int M, int N, int K, int relu, int accum, int out_f32) {
  __shared__ u16 As[2][8192];
  __shared__ u16 Bs[2][4096];
  const int tid = threadIdx.x;
  const int w = tid >> 6, l = tid & 63;
  const int l16 = l & 15, kgrp = l >> 4;
  const int m0 = blockIdx.y * 128, n0 = blockIdx.x * 64;
  const int wr = (w >> 1) * 64, wc = (w & 1) * 32;

  const int srow = w * 8 + (l >> 3);
  const u16* gA[4];
#pragma unroll
  for (int i = 0; i < 4; i++) {
    int r = i * 32 + srow;
    gA[i] = A + (size_t)(m0 + r) * K + 8 * ((l & 7) ^ (r & 7));
  }
  const u16* gB[2];
#pragma unroll
  for (int i = 0; i < 2; i++) {
    int r = i * 32 + srow;
    gB[i] = Bt + (size_t)(n0 + r) * K + 8 * ((l & 7) ^ (r & 7));
  }

  v4f acc[4][2];
#pragma unroll
  for (int i = 0; i < 4; i++)
#pragma unroll
    for (int j = 0; j < 2; j++)
#pragma unroll
      for (int r = 0; r < 4; r++) acc[i][j][r] = 0.f;

#pragma unroll
  for (int i = 0; i < 4; i++) gl_lds16(gA[i], &As[0][(i * 256 + w * 64) * 8]);
#pragma unroll
  for (int i = 0; i < 2; i++) gl_lds16(gB[i], &Bs[0][(i * 256 + w * 64) * 8]);

  int cur = 0;
  for (int k0 = 0; k0 < K; k0 += 64) {
    __syncthreads();
    if (k0 + 64 < K) {
      int nxt = cur ^ 1;
#pragma unroll
      for (int i = 0; i < 4; i++)
        gl_lds16(gA[i] + k0 + 64, &As[nxt][(i * 256 + w * 64) * 8]);
#pragma unroll
      for (int i = 0; i < 2; i++)
        gl_lds16(gB[i] + k0 + 64, &Bs[nxt][(i * 256 + w * 64) * 8]);
    }
    v8s a[4][2], b[2][2];
#pragma unroll
    for (int ks = 0; ks < 2; ks++) {
      int ch = 8 * ((ks * 4 + kgrp) ^ (l16 & 7));
#pragma unroll
      for (int mi = 0; mi < 4; mi++)
        a[mi][ks] = *(const v8s*)(&As[cur][(wr + mi * 16 + l16) * 64 + ch]);
#pragma unroll
      for (int ni = 0; ni < 2; ni++)
        b[ni][ks] = *(const v8s*)(&Bs[cur][(wc + ni * 16 + l16) * 64 + ch]);
    }
#pragma unroll
    for (int ks = 0; ks < 2; ks++)
#pragma unroll
      for (int mi = 0; mi < 4; mi++)
#pragma unroll
        for (int ni = 0; ni < 2; ni++)
          acc[mi][ni] = __builtin_amdgcn_mfma_f32_16x16x32_bf16(a[mi][ks], b[ni][ks], acc[mi][ni], 0, 0, 0);
    cur ^= 1;
  }

#pragma unroll
  for (int ni = 0; ni < 2; ni++) {
    int col = n0 + wc + ni * 16 + l16;
    float bv = bias ? bias[col] : 0.f;
#pragma unroll
    for (int mi = 0; mi < 4; mi++) {
      int row = m0 + wr + mi * 16 + kgrp * 4;
#pragma unroll
      for (int r = 0; r < 4; r++) {
        float v = acc[mi][ni][r] + bv;
        if (relu) v = fmaxf(v, 0.f);
        size_t idx = (size_t)(row + r) * N + col;
        if (out_f32) {
          float* Cf = (float*)C;
          if (accum) v += Cf[idx];
          Cf[idx] = v;
        } else {
          ((u16*)C)[idx] = f2bf(v);
        }
      }
    }
  }
}

// ---------------------------------------------------------------------------
// Attention (R12 structure + XCD swizzle): O = softmax(Q Q^T / sqrt(S)) Q.
// 512 threads, 8 waves x 32 q-rows (256-row blocks), 32x32x16 MFMA,
// P fully in-register (perm-pack + permlane32_swap). Grid (8, 32) = 256.
// Bijective chunk swizzle keeps 4 consecutive (b,h) per XCD (K/V 2MB < L2).
// ---------------------------------------------------------------------------
__global__ __launch_bounds__(512) void attn_kernel(
    const u16* __restrict__ Q, const u16* __restrict__ Qt,
    u16* __restrict__ O) {
  __shared__ u16 KV[2][8192];
  const int tid = threadIdx.x;
  const int w = tid >> 6, l = tid & 63;
  const int l31 = l & 31, hi = l >> 5;

  // XCD-aware bijective swizzle (nwg % 8 == 0)
  const int gx = gridDim.x;
  const int nwg = gx * gridDim.y;
  int lin = blockIdx.x + gx * blockIdx.y;
  if ((nwg & 7) == 0) lin = (lin & 7) * (nwg >> 3) + (lin >> 3);
  const int bxi = lin % gx;
  const int bh = lin / gx;
  const int b = bh >> 4, h = bh & 15;
  const int q0 = bxi * 256;
  const size_t rowQ = (size_t)(b * 2048 + q0 + w * 32);
  const float cexp = 1.4426950408889634f / 45.254833995939045f;

  const int isV = w >> 2, wl = w & 3;
  const int r0 = wl * 16 + (l >> 3);
  const int sch8 = 8 * ((l & 7) ^ (l >> 3));
  const u16* gS0;
  size_t kstep;
  if (!isV) {
    gS0 = Q + (size_t)(b * 2048 + r0) * 1024 + h * 64 + sch8;
    kstep = 1024;
  } else {
    gS0 = Qt + (size_t)(h * 64 + r0) * 4096 + b * 2048 + sch8;
    kstep = 1;
  }
  const u16* gS1 = gS0 + (size_t)8 * (isV ? 4096 : 1024);
  const int ldst = isV * 4096 + wl * 1024;

  v8s qb[4];
#pragma unroll
  for (int t = 0; t < 4; t++) {
    v8s v = *(const v8s*)(Q + (rowQ + l31) * 1024 + h * 64 + t * 16 + hi * 8);
#pragma unroll
    for (int j = 0; j < 8; j++) v[j] = (short)f2bf(bf2f((u16)v[j]) * cexp);
    qb[t] = v;
  }

  v16f o0, o1;
#pragma unroll
  for (int r = 0; r < 16; r++) { o0[r] = 0.f; o1[r] = 0.f; }
  float ls = 0.f;

  gl_lds16(gS0, &KV[0][ldst]);
  gl_lds16(gS1, &KV[0][ldst + 512]);

  int cur = 0;
  for (int kb = 0; kb < 2048; kb += 64) {
    __syncthreads();
    if (kb + 64 < 2048) {
      int nxt = cur ^ 1;
      gl_lds16(gS0 + (size_t)(kb + 64) * kstep, &KV[nxt][ldst]);
      gl_lds16(gS1 + (size_t)(kb + 64) * kstep, &KV[nxt][ldst + 512]);
    }
    const u16* Ks = &KV[cur][0];
    const u16* Vt = &KV[cur][4096];

    v16f s0, s1;
#pragma unroll
    for (int r = 0; r < 16; r++) { s0[r] = 0.f; s1[r] = 0.f; }
#pragma unroll
    for (int t = 0; t < 4; t++) {
      const int c = 8 * ((2 * t + hi) ^ (l & 7));
      v8s ka0 = *(const v8s*)(Ks + l31 * 64 + c);
      v8s ka1 = *(const v8s*)(Ks + (32 + l31) * 64 + c);
      s0 = __builtin_amdgcn_mfma_f32_32x32x16_bf16(ka0, qb[t], s0, 0, 0, 0);
      s1 = __builtin_amdgcn_mfma_f32_32x32x16_bf16(ka1, qb[t], s1, 0, 0, 0);
    }

    float p0[16], p1[16];
#pragma unroll
    for (int r = 0; r < 16; r++) {
      p0[r] = __builtin_amdgcn_exp2f(s0[r]);
      p1[r] = __builtin_amdgcn_exp2f(s1[r]);
      ls += p0[r] + p1[r];
    }

#define PVSTEP(t, P) { \
      const int off = 8 * ((t) & 1); \
      uint32_t dw00 = __builtin_amdgcn_perm(fbits(P[off + 1]), fbits(P[off + 0]), 0x07060302u); \
      uint32_t dw01 = __builtin_amdgcn_perm(fbits(P[off + 3]), fbits(P[off + 2]), 0x07060302u); \
      uint32_t dw10 = __builtin_amdgcn_perm(fbits(P[off + 5]), fbits(P[off + 4]), 0x07060302u); \
      uint32_t dw11 = __builtin_amdgcn_perm(fbits(P[off + 7]), fbits(P[off + 6]), 0x07060302u); \
      v2u sA = __builtin_amdgcn_permlane32_swap(dw00, dw10, false, false); \
      v2u sB = __builtin_amdgcn_permlane32_swap(dw01, dw11, false, false); \
      union { uint32_t u[4]; v8s v; } pa; \
      pa.u[0] = sA[0]; pa.u[1] = sB[0]; pa.u[2] = sA[1]; pa.u[3] = sB[1]; \
      const int c = 8 * ((2 * (t) + hi) ^ (l & 7)); \
      v8s vb0 = *(const v8s*)(Vt + l31 * 64 + c); \
      v8s vb1 = *(const v8s*)(Vt + (32 + l31) * 64 + c); \
      o0 = __builtin_amdgcn_mfma_f32_32x32x16_bf16(pa.v, vb0, o0, 0, 0, 0); \
      o1 = __builtin_amdgcn_mfma_f32_32x32x16_bf16(pa.v, vb1, o1, 0, 0, 0); }
    PVSTEP(0, p0)
    PVSTEP(1, p0)
    PVSTEP(2, p1)
    PVSTEP(3, p1)
#undef PVSTEP
    cur ^= 1;
  }

  ls += __shfl_xor(ls, 32, 64);   // den[q] at lanes with l31 == q

  const int hiq = hi * 4;
#pragma unroll
  for (int r = 0; r < 16; r++) {
    const int qo = (r & 3) + 8 * (r >> 2) + hiq;
    float den = __shfl(ls, qo, 64);
    float rden = 1.f / den;
    O[(rowQ + qo) * 1024 + h * 64 + l31] = f2bf(o0[r] * rden);
    O[(rowQ + qo) * 1024 + h * 64 + 32 + l31] = f2bf(o1[r] * rden);
  }
}

// ---------------------------------------------------------------------------
// out = LayerNorm(Y [+ Y2 + Y3 + Y4] + Xr) * g + b; row length 1024; dtype
// flags (1 = fp32, 0 = bf16). Y2/Y3/Y4 nullable (Y3/Y4 always bf16).
// In-place safe.
// ---------------------------------------------------------------------------
__global__ __launch_bounds__(256) void ln_residual(
    const void* __restrict__ Y, const void* __restrict__ Y2,
    const void* __restrict__ Y3, const void* __restrict__ Y4,
    const void* __restrict__ Xr,
    const float* __restrict__ g, const float* __restrict__ bb,
    void* __restrict__ out, int yf, int y2f, int xf, int of) {
  const int row = blockIdx.x, tid = threadIdx.x;
  const size_t base = (size_t)row * 1024;
  float v[4], s = 0.f, sq = 0.f;
#pragma unroll
  for (int i = 0; i < 4; i++) {
    int c = tid + i * 256;
    float ya = yf ? ((const float*)Y)[base + c] : bf2f(((const u16*)Y)[base + c]);
    float xa = xf ? ((const float*)Xr)[base + c] : bf2f(((const u16*)Xr)[base + c]);
    float x = ya + xa;
    if (Y2) {
      float y2a = y2f ? ((const float*)Y2)[base + c] : bf2f(((const u16*)Y2)[base + c]);
      x += y2a;
    }
    if (Y3) x += bf2f(((const u16*)Y3)[base + c]);
    if (Y4) x += bf2f(((const u16*)Y4)[base + c]);
    v[i] = x; s += x; sq += x * x;
  }
#pragma unroll
  for (int off = 32; off >= 1; off >>= 1) {
    s += __shfl_down(s, off, 64);
    sq += __shfl_down(sq, off, 64);
  }
  __shared__ float rs[4], rq[4];
  const int w = tid >> 6, l = tid & 63;
  if (l == 0) { rs[w] = s; rq[w] = sq; }
  __syncthreads();
  s = rs[0] + rs[1] + rs[2] + rs[3];
  sq = rq[0] + rq[1] + rq[2] + rq[3];
  const float mu = s * (1.f / 1024.f);
  const float var = sq * (1.f / 1024.f) - mu * mu;
  const float rstd = rsqrtf(var + 1e-5f);
#pragma unroll
  for (int i = 0; i < 4; i++) {
    int c = tid + i * 256;
    float r = (v[i] - mu) * rstd * g[c] + bb[c];
    if (of) ((float*)out)[base + c] = r;
    else ((u16*)out)[base + c] = f2bf(r);
  }
}

// ---------------------------------------------------------------------------
extern "C" void kernel_launch(void* const* d_in, const int* in_sizes, int n_in,
                              void* d_out, int out_size, void* d_ws, size_t ws_size,
                              hipStream_t stream) {
  const float* x   = (const float*)d_in[0];
  const float* Wq  = (const float*)d_in[1];
  const float* bq  = (const float*)d_in[2];
  const float* Wo  = (const float*)d_in[3];
  const float* bo  = (const float*)d_in[4];
  const float* g1  = (const float*)d_in[5];
  const float* be1 = (const float*)d_in[6];
  const float* W1  = (const float*)d_in[7];
  const float* b1  = (const float*)d_in[8];
  const float* W2  = (const float*)d_in[9];
  const float* b2  = (const float*)d_in[10];
  const float* g2  = (const float*)d_in[11];
  const float* be2 = (const float*)d_in[12];
  float* out = (float*)d_out;
  u16* ws  = (u16*)d_ws;

  const size_t M1 = 1048576;
  dim3 blk(256);
  dim3 blk8(512);
  const bool big = ws_size >= (size_t)37 * M1 * 2;  // 74 MiB

  if (big) {
    // Layout (u16 offsets):
    //  [0..4M)   xb  -> attn out -> P2_ffn2
    //  [4..8M)   Qb  -> x1
    //  [8..12M)  Qt  -> Yb (Wo P0) -> P1_ffn2
    //  [12..13M) WqT
    //  [13..17M) W1T -> P3_ffn2 (after FFN1)
    //  [17..21M) W2T
    //  [21..37M) Hh; transient before FFN1: Wo partials P1/P2/P3 @21/25/29M,
    //            WoT @33M (all dead before FFN1 overwrites Hh)
    u16* xb   = ws + 0;
    u16* Qb   = ws + 4 * M1;
    u16* Qt   = ws + 8 * M1;
    u16* WqT  = ws + 12 * M1;
    u16* W1T  = ws + 13 * M1;
    u16* W2T  = ws + 17 * M1;
    u16* Hh   = ws + 21 * M1;
    u16* P1wo = ws + 21 * M1;
    u16* P2wo = ws + 25 * M1;
    u16* P3wo = ws + 29 * M1;
    u16* WoT  = ws + 33 * M1;
    u16* attn = xb;  u16* Yb = Qt;  u16* x1 = Qb;
    u16* P1f2 = Qt;              // Yb dead after LN1
    u16* P2f2 = xb;              // attn dead after Wo-proj
    u16* P3f2 = W1T;             // W1T dead after FFN1

    // 1: fused input convert + all four weight transposes
    prep_all<<<dim3(14336), blk, 0, stream>>>(x, Wq, Wo, W1, W2,
                                              xb, WqT, WoT, W1T, W2T);
    // 2: Q projection
    gemm_g2<<<dim3(16, 32), blk, 0, stream>>>(xb, WqT, bq, Qb, 4096, 1024, 1024, 0, 0, 0);
    // 3: Q transpose (for attn V-side access)
    transpose_b2b<<<dim3(32, 128), blk, 0, stream>>>(Qb, Qt, 4096, 1024, 1024, 4096);
    // 4: attention
    attn_kernel<<<dim3(8, 32), blk8, 0, stream>>>(Qb, Qt, attn);
    // 5: Wo projection: split-K=4, P0 -> Yb (bf16, +bias)
    gemm_8p<<<dim3(4, 16, 4), blk8, 0, stream>>>(attn, WoT, bo, Yb, P1wo, P2wo, P3wo,
                                                 4096, 1024, 1024, 256, 0, 0);
    // 6: LN1 (folds Wo split-K partials + residual)
    ln_residual<<<dim3(4096), blk, 0, stream>>>(Yb, P1wo, P2wo, P3wo, x, g1, be1, x1,
                                                0, 0, 1, 0);
    // 7: FFN1 (full-K, 256 blocks)
    gemm_8p<<<dim3(16, 16, 1), blk8, 0, stream>>>(x1, W1T, b1, Hh,
                                                  nullptr, nullptr, nullptr,
                                                  4096, 4096, 1024, 1024, 1, 0);
    // 8: FFN2: split-K=4, P0 -> out (fp32, +bias)
    gemm_8p<<<dim3(4, 16, 4), blk8, 0, stream>>>(Hh, W2T, b2, out, P1f2, P2f2, P3f2,
                                                 4096, 1024, 4096, 1024, 0, 1);
    // 9: LN2 (folds FFN2 split-K partials + residual)
    ln_residual<<<dim3(4096), blk, 0, stream>>>(out, P1f2, P2f2, P3f2, x1, g2, be2, out,
                                                1, 0, 0, 1);
  } else {
    u16* xb   = ws + 0;
    u16* Qb   = ws + 4 * M1;
    u16* Qt   = ws + 8 * M1;
    u16* attn = xb;  u16* Yb = Qt;  u16* x1 = Qb;  u16* Hc = xb;
    u16* Wt1  = ws + 12 * M1;
    u16* Wt2  = ws + 13 * M1;

    cvt_f2b<<<dim3(4096), blk, 0, stream>>>(x, xb, 1048576);
    transpose_f2b<<<dim3(32, 32), blk, 0, stream>>>(Wq, Wt1, 1024, 1024, 1024, 1024);
    gemm_g2<<<dim3(16, 32), blk, 0, stream>>>(xb, Wt1, bq, Qb, 4096, 1024, 1024, 0, 0, 0);

    transpose_b2b<<<dim3(32, 128), blk, 0, stream>>>(Qb, Qt, 4096, 1024, 1024, 4096);
    attn_kernel<<<dim3(8, 32), blk8, 0, stream>>>(Qb, Qt, attn);

    transpose_f2b<<<dim3(32, 32), blk, 0, stream>>>(Wo, Wt2, 1024, 1024, 1024, 1024);
    gemm_g2<<<dim3(16, 32), blk, 0, stream>>>(attn, Wt2, bo, Yb, 4096, 1024, 1024, 0, 0, 0);
    ln_residual<<<dim3(4096), blk, 0, stream>>>(Yb, nullptr, nullptr, nullptr, x, g1, be1,
                                                x1, 0, 0, 1, 0);

    for (int c = 0; c < 4; c++) {
      transpose_f2b<<<dim3(32, 32), blk, 0, stream>>>(W1 + (size_t)c * 1024, Wt1,
                                                      1024, 1024, 4096, 1024);
      gemm_g2<<<dim3(16, 32), blk, 0, stream>>>(x1, Wt1, b1 + (size_t)c * 1024, Hc,
                                                4096, 1024, 1024, 1, 0, 0);
      transpose_f2b<<<dim3(32, 32), blk, 0, stream>>>(W2 + (size_t)c * M1, Wt2,
                                                      1024, 1024, 1024, 1024);
      gemm_g2<<<dim3(16, 32), blk, 0, stream>>>(Hc, Wt2, (c == 0) ? b2 : (const float*)nullptr,
                                                out, 4096, 1024, 1024, 0, (c > 0) ? 1 : 0, 1);
    }
    ln_residual<<<dim3(4096), blk, 0, stream>>>(out, nullptr, nullptr, nullptr, x1, g2, be2,
                                                out, 1, 0, 0, 1);
  }
}

// Round 11
// 320.915 us; speedup vs baseline: 1.0651x; 1.0029x over previous
//
#include <hip/hip_runtime.h>
#include <stdint.h>

// B=2, S=2048, D=1024, H=16, DK=64, DH=4096. I/O fp32; internals bf16 MFMA.
// R18: (1) gemm_8p = R14 wait-at-consumption ledger + m201-style per-phase
// barrier-pair lockstep (bar -> lgkmcnt(0) -> setprio MFMA -> bar; VMC(6)
// end-Ph2, VMC(2) end-Ph4, never 0). R13's lockstep regression traced to its
// flawed ledger (B23 1-phase flight), not the barriers -- this isolates it.
// (2) ln_residual vectorized (float4/ushort4 per lane, was scalar bf16).
// Attention: R12+XCD swizzle (proven R17). prep_all fusion kept.

typedef unsigned short u16;
typedef __attribute__((ext_vector_type(8))) short v8s;   // 8 x bf16
typedef __attribute__((ext_vector_type(4))) float v4f;
typedef __attribute__((ext_vector_type(16))) float v16f;
typedef __attribute__((ext_vector_type(2))) unsigned int v2u;

#define AS1 __attribute__((address_space(1)))
#define AS3 __attribute__((address_space(3)))

__device__ __forceinline__ void gl_lds16(const u16* g, u16* l) {
  __builtin_amdgcn_global_load_lds((const AS1 void*)g, (AS3 void*)l, 16, 0, 0);
}

__device__ __forceinline__ float bf2f(u16 u) {
  union { uint32_t i; float f; } v; v.i = ((uint32_t)u) << 16; return v.f;
}
__device__ __forceinline__ u16 f2bf(float f) {
  union { float f; uint32_t i; } v; v.f = f;
  uint32_t x = v.i;
  return (u16)((x + 0x7FFFu + ((x >> 16) & 1u)) >> 16);  // RNE
}
__device__ __forceinline__ uint32_t fbits(float f) {
  union { float f; uint32_t u; } v; v.f = f; return v.u;
}

// ---------------------------------------------------------------------------
__global__ __launch_bounds__(256) void cvt_f2b(
    const float* __restrict__ src, u16* __restrict__ dst, int n4) {
  int i = (blockIdx.x * 256 + threadIdx.x);
  if (i < n4) {
    float4 v = *(const float4*)(src + (size_t)i * 4);
    ushort4 o;
    o.x = f2bf(v.x); o.y = f2bf(v.y); o.z = f2bf(v.z); o.w = f2bf(v.w);
    *(ushort4*)(dst + (size_t)i * 4) = o;
  }
}

// ---------------------------------------------------------------------------
// prep_all: fused input-stage kernel (big path). Blocks:
//   [0,1024)      Wq  (1024x1024) -> WqT
//   [1024,2048)   Wo  (1024x1024) -> WoT
//   [2048,6144)   W1  (1024x4096) -> W1T
//   [6144,10240)  W2  (4096x1024) -> W2T
//   [10240,14336) x fp32 -> xb bf16
// ---------------------------------------------------------------------------
__global__ __launch_bounds__(256) void prep_all(
    const float* __restrict__ x, const float* __restrict__ Wq,
    const float* __restrict__ Wo, const float* __restrict__ W1,
    const float* __restrict__ W2, u16* __restrict__ xb,
    u16* __restrict__ WqT, u16* __restrict__ WoT,
    u16* __restrict__ W1T, u16* __restrict__ W2T) {
  const int r = blockIdx.x;
  const int tid = threadIdx.x;
  if (r >= 10240) {
    int i = (r - 10240) * 256 + tid;
    float4 v = *(const float4*)(x + (size_t)i * 4);
    ushort4 o;
    o.x = f2bf(v.x); o.y = f2bf(v.y); o.z = f2bf(v.z); o.w = f2bf(v.w);
    *(ushort4*)(xb + (size_t)i * 4) = o;
    return;
  }
  __shared__ float tile[32][33];
  const float* src; u16* dst; int ld_s, ld_d, bx, by;
  if (r < 1024)      { src = Wq; dst = WqT; ld_s = 1024; ld_d = 1024; bx = r & 31; by = r >> 5; }
  else if (r < 2048) { int r2 = r - 1024; src = Wo; dst = WoT; ld_s = 1024; ld_d = 1024; bx = r2 & 31; by = r2 >> 5; }
  else if (r < 6144) { int r2 = r - 2048; src = W1; dst = W1T; ld_s = 4096; ld_d = 1024; bx = r2 & 127; by = r2 >> 7; }
  else               { int r2 = r - 6144; src = W2; dst = W2T; ld_s = 1024; ld_d = 4096; bx = r2 & 31; by = r2 >> 5; }
  const int tx = tid & 31, ty = tid >> 5;
  const int c0 = bx * 32, r0 = by * 32;
#pragma unroll
  for (int j = 0; j < 32; j += 8)
    tile[ty + j][tx] = src[(size_t)(r0 + ty + j) * ld_s + c0 + tx];
  __syncthreads();
#pragma unroll
  for (int j = 0; j < 32; j += 8)
    dst[(size_t)(c0 + ty + j) * ld_d + r0 + tx] = f2bf(tile[tx][ty + j]);
}

// ---------------------------------------------------------------------------
__global__ __launch_bounds__(256) void transpose_f2b(
    const float* __restrict__ src, u16* __restrict__ dst,
    int R, int C, int ld_s, int ld_d) {
  __shared__ float tile[32][33];
  const int tx = threadIdx.x & 31, ty = threadIdx.x >> 5;
  const int c0 = blockIdx.x * 32, r0 = blockIdx.y * 32;
#pragma unroll
  for (int j = 0; j < 32; j += 8)
    tile[ty + j][tx] = src[(size_t)(r0 + ty + j) * ld_s + c0 + tx];
  __syncthreads();
#pragma unroll
  for (int j = 0; j < 32; j += 8)
    dst[(size_t)(c0 + ty + j) * ld_d + r0 + tx] = f2bf(tile[tx][ty + j]);
}

__global__ __launch_bounds__(256) void transpose_b2b(
    const u16* __restrict__ src, u16* __restrict__ dst,
    int R, int C, int ld_s, int ld_d) {
  __shared__ u16 tile[32][33];
  const int tx = threadIdx.x & 31, ty = threadIdx.x >> 5;
  const int c0 = blockIdx.x * 32, r0 = blockIdx.y * 32;
#pragma unroll
  for (int j = 0; j < 32; j += 8)
    tile[ty + j][tx] = src[(size_t)(r0 + ty + j) * ld_s + c0 + tx];
  __syncthreads();
#pragma unroll
  for (int j = 0; j < 32; j += 8)
    dst[(size_t)(c0 + ty + j) * ld_d + r0 + tx] = tile[tx][ty + j];
}

// ---------------------------------------------------------------------------
// gemm_8p: 256x256 tile, BK=64, 512 threads (8 waves: 2M x 4N), 128 KiB LDS.
// Per-phase lockstep + wait-at-consumption counted vmcnt:
//   Ph1: LDA0/LDB0 ; stage A02(t+1)           ; bar,lgkm0, MFQ(0,0), bar
//   Ph2: LDB1      ; stage B01+B23(t+1); VMC(6); bar,lgkm0, MFQ(0,1), bar
//   Ph3: LDA1      ; stage A13(t+1)            ; bar,lgkm0, MFQ(1,1), bar
//   Ph4:                              VMC(2)   ; bar,       MFQ(1,0), bar
// Ledger: VMC(6)@Ph2-end retires A13(t) (3-phase flight) before Ph3 reads;
// VMC(2)@Ph4-end retires A02/B01/B23(t+1) (2-3+ phases) before Ph1(t+1).
// Never 0 in steady state. XCD-aware bijective block swizzle (proven).
// z==0 -> C0 (+bias, relu, fp32 or bf16); z=1..3 -> C1/C2/C3 bf16 partials.
// ---------------------------------------------------------------------------
__global__ __launch_bounds__(512, 1) void gemm_8p(
    const u16* __restrict__ A, const u16* __restrict__ Bt,
    const float* __restrict__ bias, void* __restrict__ C0,
    u16* __restrict__ C1, u16* __restrict__ C2, u16* __restrict__ C3,
    int M, int N, int ldk, int klen, int relu, int c0_f32) {
  __shared__ u16 As[2][16384];   // [buf][row*64 + elem], 256 rows x 64 k
  __shared__ u16 Bs[2][16384];
  const int tid = threadIdx.x;
  const int w = tid >> 6, l = tid & 63;
  const int l16 = l & 15, kgrp = (l >> 4) & 3;
  const int wm = w >> 2, wn = w & 3;

  // XCD-aware bijective swizzle over full linear id (all launches nwg%8==0)
  const int gx = gridDim.x, gyd = gridDim.y;
  const int nxy = gx * gyd;
  const int nwg = nxy * gridDim.z;
  int lin = blockIdx.x + gx * (blockIdx.y + gyd * blockIdx.z);
  if ((nwg & 7) == 0) lin = (lin & 7) * (nwg >> 3) + (lin >> 3);
  const int z = lin / nxy;
  const int rem = lin - z * nxy;
  const int by = rem / gx;
  const int bx = rem - by * gx;
  const int m0 = by * 256, n0 = bx * 256;
  const int NT = klen >> 6;

  const int rl = tid >> 3;
  const int sw = 8 * ((tid & 7) ^ (rl & 7));
  const u16* gA[4]; const u16* gB[4];
#pragma unroll
  for (int j = 0; j < 4; j++) {
    gA[j] = A + (size_t)(m0 + j * 64 + rl) * ldk + (size_t)z * klen + sw;
    gB[j] = Bt + (size_t)(n0 + j * 64 + rl) * ldk + (size_t)z * klen + sw;
  }
  const int sdst = w * 512;   // wave-uniform LDS base (+ j*4096)

  const int ch0 = 8 * ((kgrp) ^ (l16 & 7));
  const int ch1 = 8 * ((4 + kgrp) ^ (l16 & 7));
  const int abase = (wm * 128 + l16) * 64;
  const int bbase = (wn * 64 + l16) * 64;

  v4f acc[8][4];
#pragma unroll
  for (int i = 0; i < 8; i++)
#pragma unroll
    for (int j = 0; j < 4; j++)
#pragma unroll
      for (int r = 0; r < 4; r++) acc[i][j][r] = 0.f;

  v8s a[4][2], b[4][2];

#define FENCE() asm volatile("" ::: "memory")
#define VMC(n) asm volatile("s_waitcnt vmcnt(" #n ")" ::: "memory")
#define LGKM0() { asm volatile("s_waitcnt lgkmcnt(0)" ::: "memory"); \
                  __builtin_amdgcn_sched_barrier(0); }
#define BARX() { __builtin_amdgcn_s_barrier(); \
                 __builtin_amdgcn_sched_barrier(0); FENCE(); }
#define STGA(q, j, kt) gl_lds16(gA[j] + (size_t)(kt) * 64, &As[q][(j) * 4096 + sdst])
#define STGB(q, j, kt) gl_lds16(gB[j] + (size_t)(kt) * 64, &Bs[q][(j) * 4096 + sdst])
#define LDA(p, mh) { \
  const u16* Ap = &As[p][abase + (mh) * 4096]; \
  _Pragma("unroll") for (int mi = 0; mi < 4; mi++) { \
    a[mi][0] = *(const v8s*)(Ap + mi * 1024 + ch0); \
    a[mi][1] = *(const v8s*)(Ap + mi * 1024 + ch1); } }
#define LDB(p, nh) { \
  const u16* Bp = &Bs[p][bbase + (nh) * 2048]; \
  _Pragma("unroll") for (int ni = 0; ni < 2; ni++) { \
    b[(nh) * 2 + ni][0] = *(const v8s*)(Bp + ni * 1024 + ch0); \
    b[(nh) * 2 + ni][1] = *(const v8s*)(Bp + ni * 1024 + ch1); } }
#define MFQ(mh, nh) { \
  __builtin_amdgcn_s_setprio(1); \
  _Pragma("unroll") for (int ks = 0; ks < 2; ks++) \
  _Pragma("unroll") for (int mi = 0; mi < 4; mi++) \
  _Pragma("unroll") for (int ni = 0; ni < 2; ni++) \
    acc[(mh) * 4 + mi][(nh) * 2 + ni] = __builtin_amdgcn_mfma_f32_16x16x32_bf16( \
        a[mi][ks], b[(nh) * 2 + ni][ks], acc[(mh) * 4 + mi][(nh) * 2 + ni], 0, 0, 0); \
  __builtin_amdgcn_s_setprio(0); }

  // prologue: stage tile 0 into buf0 (A02, B01, B23, A13); retire first 6.
  STGA(0, 0, 0); STGA(0, 2, 0);
  FENCE();
  STGB(0, 0, 0); STGB(0, 1, 0);
  FENCE();
  STGB(0, 2, 0); STGB(0, 3, 0);
  FENCE();
  STGA(0, 1, 0); STGA(0, 3, 0);
  VMC(2); BARX();

  int p = 0;
  for (int kt = 0; kt < NT - 1; ++kt, p ^= 1) {
    const int q = p ^ 1;
    const int kn = kt + 1;
    // Ph1: A02/B01/B23(kt) landed; A13(kt) still in flight
    LDA(p, 0);
    LDB(p, 0);
    FENCE();
    STGA(q, 0, kn); STGA(q, 2, kn);
    BARX(); LGKM0();
    MFQ(0, 0);
    BARX();
    // Ph2: issue all B stages of kt+1; retire A13(kt) before Ph3 reads it
    LDB(p, 1);
    FENCE();
    STGB(q, 0, kn); STGB(q, 1, kn);
    STGB(q, 2, kn); STGB(q, 3, kn);
    VMC(6);
    BARX(); LGKM0();
    MFQ(0, 1);
    BARX();
    // Ph3: read A-half1; stage A13(kt+1)
    LDA(p, 1);
    FENCE();
    STGA(q, 1, kn); STGA(q, 3, kn);
    BARX(); LGKM0();
    MFQ(1, 1);
    BARX();
    // Ph4: pure MFMA; retire A02/B01/B23(kt+1) before next Ph1
    VMC(2);
    BARX();
    MFQ(1, 0);
    BARX();
  }
  // peeled last tile: drain everything; no staging, loose schedule.
  VMC(0); BARX();
  LDA(p, 0);
  LDB(p, 0);
  MFQ(0, 0);
  LDB(p, 1);
  MFQ(0, 1);
  LDA(p, 1);
  MFQ(1, 1);
  MFQ(1, 0);

#undef FENCE
#undef VMC
#undef LGKM0
#undef BARX
#undef STGA
#undef STGB
#undef LDA
#undef LDB
#undef MFQ

#pragma unroll
  for (int mi = 0; mi < 8; mi++) {
    const int row = m0 + wm * 128 + mi * 16 + kgrp * 4;
#pragma unroll
    for (int ni = 0; ni < 4; ni++) {
      const int col = n0 + wn * 64 + ni * 16 + l16;
      float bv = (bias && z == 0) ? bias[col] : 0.f;
#pragma unroll
      for (int r = 0; r < 4; r++) {
        float v = acc[mi][ni][r] + bv;
        if (z == 0 && relu) v = fmaxf(v, 0.f);
        size_t idx = (size_t)(row + r) * N + col;
        if (z == 0) {
          if (c0_f32) ((float*)C0)[idx] = v;
          else ((u16*)C0)[idx] = f2bf(v);
        } else if (z == 1) {
          C1[idx] = f2bf(v);
        } else if (z == 2) {
          C2[idx] = f2bf(v);
        } else {
          C3[idx] = f2bf(v);
        }
      }
    }
  }
}

// ---------------------------------------------------------------------------
// G2: 128x64 tile, BK=64, double-buffered (Qproj + small path).
// ---------------------------------------------------------------------------
__global__ __launch_bounds__(256) void gemm_g2(
    const u16* __restrict__ A, const u16* __restrict__ Bt,
    const float* __restrict__ bias, void* __restrict__ C,
    int M, int N, int K, int relu, int accum, int out_f32) {
  __shared__ u16 As[2][8192];
  __shared__ u16 Bs[2][4096];
  const int tid = threadIdx.x;
  const int w = tid >> 6, l = tid & 63;
  const int l16 = l & 15, kgrp = l >> 4;
  const int m0 = blockIdx.y * 128, n0 = blockIdx.x * 64;
  const int wr = (w >> 1) * 64, wc = (w & 1) * 32;

  const int srow = w * 8 + (l >> 3);
  const u16* gA[4];
#pragma unroll
  for (int i = 0; i < 4; i++) {
    int r = i * 32 + srow;
    gA[i] = A + (size_t)(m0 + r) * K + 8 * ((l & 7) ^ (r & 7));
  }
  const u16* gB[2];
#pragma unroll
  for (int i = 0; i < 2; i++) {
    int r = i * 32 + srow;
    gB[i] = Bt + (size_t)(n0 + r) * K + 8 * ((l & 7) ^ (r & 7));
  }

  v4f acc[4][2];
#pragma unroll
  for (int i = 0; i < 4; i++)
#pragma unroll
    for (int j = 0; j < 2; j++)
#pragma unroll
      for (int r = 0; r < 4; r++) acc[i][j][r] = 0.f;

#pragma unroll
  for (int i = 0; i < 4; i++) gl_lds16(gA[i], &As[0][(i * 256 + w * 64) * 8]);
#pragma unroll
  for (int i = 0; i < 2; i++) gl_lds16(gB[i], &Bs[0][(i * 256 + w * 64) * 8]);

  int cur = 0;
  for (int k0 = 0; k0 < K; k0 += 64) {
    __syncthreads();
    if (k0 + 64 < K) {
      int nxt = cur ^ 1;
#pragma unroll
      for (int i = 0; i < 4; i++)
        gl_lds16(gA[i] + k0 + 64, &As[nxt][(i * 256 + w * 64) * 8]);
#pragma unroll
      for (int i = 0; i < 2; i++)
        gl_lds16(gB[i] + k0 + 64, &Bs[nxt][(i * 256 + w * 64) * 8]);
    }
    v8s a[4][2], b[2][2];
#pragma unroll
    for (int ks = 0; ks < 2; ks++) {
      int ch = 8 * ((ks * 4 + kgrp) ^ (l16 & 7));
#pragma unroll
      for (int mi = 0; mi < 4; mi++)
        a[mi][ks] = *(const v8s*)(&As[cur][(wr + mi * 16 + l16) * 64 + ch]);
#pragma unroll
      for (int ni = 0; ni < 2; ni++)
        b[ni][ks] = *(const v8s*)(&Bs[cur][(wc + ni * 16 + l16) * 64 + ch]);
    }
#pragma unroll
    for (int ks = 0; ks < 2; ks++)
#pragma unroll
      for (int mi = 0; mi < 4; mi++)
#pragma unroll
        for (int ni = 0; ni < 2; ni++)
          acc[mi][ni] = __builtin_amdgcn_mfma_f32_16x16x32_bf16(a[mi][ks], b[ni][ks], acc[mi][ni], 0, 0, 0);
    cur ^= 1;
  }

#pragma unroll
  for (int ni = 0; ni < 2; ni++) {
    int col = n0 + wc + ni * 16 + l16;
    float bv = bias ? bias[col] : 0.f;
#pragma unroll
    for (int mi = 0; mi < 4; mi++) {
      int row = m0 + wr + mi * 16 + kgrp * 4;
#pragma unroll
      for (int r = 0; r < 4; r++) {
        float v = acc[mi][ni][r] + bv;
        if (relu) v = fmaxf(v, 0.f);
        size_t idx = (size_t)(row + r) * N + col;
        if (out_f32) {
          float* Cf = (float*)C;
          if (accum) v += Cf[idx];
          Cf[idx] = v;
        } else {
          ((u16*)C)[idx] = f2bf(v);
        }
      }
    }
  }
}

// ---------------------------------------------------------------------------
// Attention (R12 structure + XCD swizzle): O = softmax(Q Q^T / sqrt(S)) Q.
// 512 threads, 8 waves x 32 q-rows (256-row blocks), 32x32x16 MFMA,
// P fully in-register (perm-pack + permlane32_swap). Grid (8, 32) = 256.
// ---------------------------------------------------------------------------
__global__ __launch_bounds__(512) void attn_kernel(
    const u16* __restrict__ Q, const u16* __restrict__ Qt,
    u16* __restrict__ O) {
  __shared__ u16 KV[2][8192];
  const int tid = threadIdx.x;
  const int w = tid >> 6, l = tid & 63;
  const int l31 = l & 31, hi = l >> 5;

  // XCD-aware bijective swizzle (nwg % 8 == 0)
  const int gx = gridDim.x;
  const int nwg = gx * gridDim.y;
  int lin = blockIdx.x + gx * blockIdx.y;
  if ((nwg & 7) == 0) lin = (lin & 7) * (nwg >> 3) + (lin >> 3);
  const int bxi = lin % gx;
  const int bh = lin / gx;
  const int b = bh >> 4, h = bh & 15;
  const int q0 = bxi * 256;
  const size_t rowQ = (size_t)(b * 2048 + q0 + w * 32);
  const float cexp = 1.4426950408889634f / 45.254833995939045f;

  const int isV = w >> 2, wl = w & 3;
  const int r0 = wl * 16 + (l >> 3);
  const int sch8 = 8 * ((l & 7) ^ (l >> 3));
  const u16* gS0;
  size_t kstep;
  if (!isV) {
    gS0 = Q + (size_t)(b * 2048 + r0) * 1024 + h * 64 + sch8;
    kstep = 1024;
  } else {
    gS0 = Qt + (size_t)(h * 64 + r0) * 4096 + b * 2048 + sch8;
    kstep = 1;
  }
  const u16* gS1 = gS0 + (size_t)8 * (isV ? 4096 : 1024);
  const int ldst = isV * 4096 + wl * 1024;

  v8s qb[4];
#pragma unroll
  for (int t = 0; t < 4; t++) {
    v8s v = *(const v8s*)(Q + (rowQ + l31) * 1024 + h * 64 + t * 16 + hi * 8);
#pragma unroll
    for (int j = 0; j < 8; j++) v[j] = (short)f2bf(bf2f((u16)v[j]) * cexp);
    qb[t] = v;
  }

  v16f o0, o1;
#pragma unroll
  for (int r = 0; r < 16; r++) { o0[r] = 0.f; o1[r] = 0.f; }
  float ls = 0.f;

  gl_lds16(gS0, &KV[0][ldst]);
  gl_lds16(gS1, &KV[0][ldst + 512]);

  int cur = 0;
  for (int kb = 0; kb < 2048; kb += 64) {
    __syncthreads();
    if (kb + 64 < 2048) {
      int nxt = cur ^ 1;
      gl_lds16(gS0 + (size_t)(kb + 64) * kstep, &KV[nxt][ldst]);
      gl_lds16(gS1 + (size_t)(kb + 64) * kstep, &KV[nxt][ldst + 512]);
    }
    const u16* Ks = &KV[cur][0];
    const u16* Vt = &KV[cur][4096];

    v16f s0, s1;
#pragma unroll
    for (int r = 0; r < 16; r++) { s0[r] = 0.f; s1[r] = 0.f; }
#pragma unroll
    for (int t = 0; t < 4; t++) {
      const int c = 8 * ((2 * t + hi) ^ (l & 7));
      v8s ka0 = *(const v8s*)(Ks + l31 * 64 + c);
      v8s ka1 = *(const v8s*)(Ks + (32 + l31) * 64 + c);
      s0 = __builtin_amdgcn_mfma_f32_32x32x16_bf16(ka0, qb[t], s0, 0, 0, 0);
      s1 = __builtin_amdgcn_mfma_f32_32x32x16_bf16(ka1, qb[t], s1, 0, 0, 0);
    }

    float p0[16], p1[16];
#pragma unroll
    for (int r = 0; r < 16; r++) {
      p0[r] = __builtin_amdgcn_exp2f(s0[r]);
      p1[r] = __builtin_amdgcn_exp2f(s1[r]);
      ls += p0[r] + p1[r];
    }

#define PVSTEP(t, P) { \
      const int off = 8 * ((t) & 1); \
      uint32_t dw00 = __builtin_amdgcn_perm(fbits(P[off + 1]), fbits(P[off + 0]), 0x07060302u); \
      uint32_t dw01 = __builtin_amdgcn_perm(fbits(P[off + 3]), fbits(P[off + 2]), 0x07060302u); \
      uint32_t dw10 = __builtin_amdgcn_perm(fbits(P[off + 5]), fbits(P[off + 4]), 0x07060302u); \
      uint32_t dw11 = __builtin_amdgcn_perm(fbits(P[off + 7]), fbits(P[off + 6]), 0x07060302u); \
      v2u sA = __builtin_amdgcn_permlane32_swap(dw00, dw10, false, false); \
      v2u sB = __builtin_amdgcn_permlane32_swap(dw01, dw11, false, false); \
      union { uint32_t u[4]; v8s v; } pa; \
      pa.u[0] = sA[0]; pa.u[1] = sB[0]; pa.u[2] = sA[1]; pa.u[3] = sB[1]; \
      const int c = 8 * ((2 * (t) + hi) ^ (l & 7)); \
      v8s vb0 = *(const v8s*)(Vt + l31 * 64 + c); \
      v8s vb1 = *(const v8s*)(Vt + (32 + l31) * 64 + c); \
      o0 = __builtin_amdgcn_mfma_f32_32x32x16_bf16(pa.v, vb0, o0, 0, 0, 0); \
      o1 = __builtin_amdgcn_mfma_f32_32x32x16_bf16(pa.v, vb1, o1, 0, 0, 0); }
    PVSTEP(0, p0)
    PVSTEP(1, p0)
    PVSTEP(2, p1)
    PVSTEP(3, p1)
#undef PVSTEP
    cur ^= 1;
  }

  ls += __shfl_xor(ls, 32, 64);   // den[q] at lanes with l31 == q

  const int hiq = hi * 4;
#pragma unroll
  for (int r = 0; r < 16; r++) {
    const int qo = (r & 3) + 8 * (r >> 2) + hiq;
    float den = __shfl(ls, qo, 64);
    float rden = 1.f / den;
    O[(rowQ + qo) * 1024 + h * 64 + l31] = f2bf(o0[r] * rden);
    O[(rowQ + qo) * 1024 + h * 64 + 32 + l31] = f2bf(o1[r] * rden);
  }
}

// ---------------------------------------------------------------------------
// out = LayerNorm(Y [+ Y2 + Y3 + Y4] + Xr) * g + b; row length 1024; dtype
// flags (1 = fp32, 0 = bf16). Y2/Y3/Y4 nullable (Y3/Y4 always bf16).
// R18: vectorized -- each thread owns 4 consecutive elements (float4/ushort4
// loads/stores, 8-16 B/lane vs the old 2-4 B scalar). In-place safe.
// ---------------------------------------------------------------------------
__global__ __launch_bounds__(256) void ln_residual(
    const void* __restrict__ Y, const void* __restrict__ Y2,
    const void* __restrict__ Y3, const void* __restrict__ Y4,
    const void* __restrict__ Xr,
    const float* __restrict__ g, const float* __restrict__ bb,
    void* __restrict__ out, int yf, int y2f, int xf, int of) {
  const int row = blockIdx.x, tid = threadIdx.x;
  const size_t base = (size_t)row * 1024;
  const int c0 = tid * 4;
  float v[4];
  if (yf) {
    float4 t = *(const float4*)((const float*)Y + base + c0);
    v[0] = t.x; v[1] = t.y; v[2] = t.z; v[3] = t.w;
  } else {
    ushort4 t = *(const ushort4*)((const u16*)Y + base + c0);
    v[0] = bf2f(t.x); v[1] = bf2f(t.y); v[2] = bf2f(t.z); v[3] = bf2f(t.w);
  }
  if (xf) {
    float4 t = *(const float4*)((const float*)Xr + base + c0);
    v[0] += t.x; v[1] += t.y; v[2] += t.z; v[3] += t.w;
  } else {
    ushort4 t = *(const ushort4*)((const u16*)Xr + base + c0);
    v[0] += bf2f(t.x); v[1] += bf2f(t.y); v[2] += bf2f(t.z); v[3] += bf2f(t.w);
  }
  if (Y2) {
    if (y2f) {
      float4 t = *(const float4*)((const float*)Y2 + base + c0);
      v[0] += t.x; v[1] += t.y; v[2] += t.z; v[3] += t.w;
    } else {
      ushort4 t = *(const ushort4*)((const u16*)Y2 + base + c0);
      v[0] += bf2f(t.x); v[1] += bf2f(t.y); v[2] += bf2f(t.z); v[3] += bf2f(t.w);
    }
  }
  if (Y3) {
    ushort4 t = *(const ushort4*)((const u16*)Y3 + base + c0);
    v[0] += bf2f(t.x); v[1] += bf2f(t.y); v[2] += bf2f(t.z); v[3] += bf2f(t.w);
  }
  if (Y4) {
    ushort4 t = *(const ushort4*)((const u16*)Y4 + base + c0);
    v[0] += bf2f(t.x); v[1] += bf2f(t.y); v[2] += bf2f(t.z); v[3] += bf2f(t.w);
  }
  float s = (v[0] + v[1]) + (v[2] + v[3]);
  float sq = (v[0] * v[0] + v[1] * v[1]) + (v[2] * v[2] + v[3] * v[3]);
#pragma unroll
  for (int off = 32; off >= 1; off >>= 1) {
    s += __shfl_down(s, off, 64);
    sq += __shfl_down(sq, off, 64);
  }
  __shared__ float rs[4], rq[4];
  const int w = tid >> 6, l = tid & 63;
  if (l == 0) { rs[w] = s; rq[w] = sq; }
  __syncthreads();
  s = rs[0] + rs[1] + rs[2] + rs[3];
  sq = rq[0] + rq[1] + rq[2] + rq[3];
  const float mu = s * (1.f / 1024.f);
  const float var = sq * (1.f / 1024.f) - mu * mu;
  const float rstd = rsqrtf(var + 1e-5f);
  float4 gg = *(const float4*)(g + c0);
  float4 bv = *(const float4*)(bb + c0);
  float r0 = (v[0] - mu) * rstd * gg.x + bv.x;
  float r1 = (v[1] - mu) * rstd * gg.y + bv.y;
  float r2 = (v[2] - mu) * rstd * gg.z + bv.z;
  float r3 = (v[3] - mu) * rstd * gg.w + bv.w;
  if (of) {
    float4 o = {r0, r1, r2, r3};
    *(float4*)((float*)out + base + c0) = o;
  } else {
    ushort4 o;
    o.x = f2bf(r0); o.y = f2bf(r1); o.z = f2bf(r2); o.w = f2bf(r3);
    *(ushort4*)((u16*)out + base + c0) = o;
  }
}

// ---------------------------------------------------------------------------
extern "C" void kernel_launch(void* const* d_in, const int* in_sizes, int n_in,
                              void* d_out, int out_size, void* d_ws, size_t ws_size,
                              hipStream_t stream) {
  const float* x   = (const float*)d_in[0];
  const float* Wq  = (const float*)d_in[1];
  const float* bq  = (const float*)d_in[2];
  const float* Wo  = (const float*)d_in[3];
  const float* bo  = (const float*)d_in[4];
  const float* g1  = (const float*)d_in[5];
  const float* be1 = (const float*)d_in[6];
  const float* W1  = (const float*)d_in[7];
  const float* b1  = (const float*)d_in[8];
  const float* W2  = (const float*)d_in[9];
  const float* b2  = (const float*)d_in[10];
  const float* g2  = (const float*)d_in[11];
  const float* be2 = (const float*)d_in[12];
  float* out = (float*)d_out;
  u16* ws  = (u16*)d_ws;

  const size_t M1 = 1048576;
  dim3 blk(256);
  dim3 blk8(512);
  const bool big = ws_size >= (size_t)37 * M1 * 2;  // 74 MiB

  if (big) {
    // Layout (u16 offsets):
    //  [0..4M)   xb  -> attn out -> P2_ffn2
    //  [4..8M)   Qb  -> x1
    //  [8..12M)  Qt  -> Yb (Wo P0) -> P1_ffn2
    //  [12..13M) WqT
    //  [13..17M) W1T -> P3_ffn2 (after FFN1)
    //  [17..21M) W2T
    //  [21..37M) Hh; transient before FFN1: Wo partials P1/P2/P3 @21/25/29M,
    //            WoT @33M (all dead before FFN1 overwrites Hh)
    u16* xb   = ws + 0;
    u16* Qb   = ws + 4 * M1;
    u16* Qt   = ws + 8 * M1;
    u16* WqT  = ws + 12 * M1;
    u16* W1T  = ws + 13 * M1;
    u16* W2T  = ws + 17 * M1;
    u16* Hh   = ws + 21 * M1;
    u16* P1wo = ws + 21 * M1;
    u16* P2wo = ws + 25 * M1;
    u16* P3wo = ws + 29 * M1;
    u16* WoT  = ws + 33 * M1;
    u16* attn = xb;  u16* Yb = Qt;  u16* x1 = Qb;
    u16* P1f2 = Qt;              // Yb dead after LN1
    u16* P2f2 = xb;              // attn dead after Wo-proj
    u16* P3f2 = W1T;             // W1T dead after FFN1

    // 1: fused input convert + all four weight transposes
    prep_all<<<dim3(14336), blk, 0, stream>>>(x, Wq, Wo, W1, W2,
                                              xb, WqT, WoT, W1T, W2T);
    // 2: Q projection
    gemm_g2<<<dim3(16, 32), blk, 0, stream>>>(xb, WqT, bq, Qb, 4096, 1024, 1024, 0, 0, 0);
    // 3: Q transpose (for attn V-side access)
    transpose_b2b<<<dim3(32, 128), blk, 0, stream>>>(Qb, Qt, 4096, 1024, 1024, 4096);
    // 4: attention
    attn_kernel<<<dim3(8, 32), blk8, 0, stream>>>(Qb, Qt, attn);
    // 5: Wo projection: split-K=4, P0 -> Yb (bf16, +bias)
    gemm_8p<<<dim3(4, 16, 4), blk8, 0, stream>>>(attn, WoT, bo, Yb, P1wo, P2wo, P3wo,
                                                 4096, 1024, 1024, 256, 0, 0);
    // 6: LN1 (folds Wo split-K partials + residual)
    ln_residual<<<dim3(4096), blk, 0, stream>>>(Yb, P1wo, P2wo, P3wo, x, g1, be1, x1,
                                                0, 0, 1, 0);
    // 7: FFN1 (full-K, 256 blocks)
    gemm_8p<<<dim3(16, 16, 1), blk8, 0, stream>>>(x1, W1T, b1, Hh,
                                                  nullptr, nullptr, nullptr,
                                                  4096, 4096, 1024, 1024, 1, 0);
    // 8: FFN2: split-K=4, P0 -> out (fp32, +bias)
    gemm_8p<<<dim3(4, 16, 4), blk8, 0, stream>>>(Hh, W2T, b2, out, P1f2, P2f2, P3f2,
                                                 4096, 1024, 4096, 1024, 0, 1);
    // 9: LN2 (folds FFN2 split-K partials + residual)
    ln_residual<<<dim3(4096), blk, 0, stream>>>(out, P1f2, P2f2, P3f2, x1, g2, be2, out,
                                                1, 0, 0, 1);
  } else {
    u16* xb   = ws + 0;
    u16* Qb   = ws + 4 * M1;
    u16* Qt   = ws + 8 * M1;
    u16* attn = xb;  u16* Yb = Qt;  u16* x1 = Qb;  u16* Hc = xb;
    u16* Wt1  = ws + 12 * M1;
    u16* Wt2  = ws + 13 * M1;

    cvt_f2b<<<dim3(4096), blk, 0, stream>>>(x, xb, 1048576);
    transpose_f2b<<<dim3(32, 32), blk, 0, stream>>>(Wq, Wt1, 1024, 1024, 1024, 1024);
    gemm_g2<<<dim3(16, 32), blk, 0, stream>>>(xb, Wt1, bq, Qb, 4096, 1024, 1024, 0, 0, 0);

    transpose_b2b<<<dim3(32, 128), blk, 0, stream>>>(Qb, Qt, 4096, 1024, 1024, 4096);
    attn_kernel<<<dim3(8, 32), blk8, 0, stream>>>(Qb, Qt, attn);

    transpose_f2b<<<dim3(32, 32), blk, 0, stream>>>(Wo, Wt2, 1024, 1024, 1024, 1024);
    gemm_g2<<<dim3(16, 32), blk, 0, stream>>>(attn, Wt2, bo, Yb, 4096, 1024, 1024, 0, 0, 0);
    ln_residual<<<dim3(4096), blk, 0, stream>>>(Yb, nullptr, nullptr, nullptr, x, g1, be1,
                                                x1, 0, 0, 1, 0);

    for (int c = 0; c < 4; c++) {
      transpose_f2b<<<dim3(32, 32), blk, 0, stream>>>(W1 + (size_t)c * 1024, Wt1,
                                                      1024, 1024, 4096, 1024);
      gemm_g2<<<dim3(16, 32), blk, 0, stream>>>(x1, Wt1, b1 + (size_t)c * 1024, Hc,
                                                4096, 1024, 1024, 1, 0, 0);
      transpose_f2b<<<dim3(32, 32), blk, 0, stream>>>(W2 + (size_t)c * M1, Wt2,
                                                      1024, 1024, 1024, 1024);
      gemm_g2<<<dim3(16, 32), blk, 0, stream>>>(Hc, Wt2, (c == 0) ? b2 : (const float*)nullptr,
                                                out, 4096, 1024, 1024, 0, (c > 0) ? 1 : 0, 1);
    }
    ln_residual<<<dim3(4096), blk, 0, stream>>>(out, nullptr, nullptr, nullptr, x1, g2, be2,
                                                out, 1, 0, 0, 1);
  }
}

// Round 13
// 316.133 us; speedup vs baseline: 1.0812x; 1.0151x over previous
//
#include <hip/hip_runtime.h>
#include <stdint.h>

// B=2, S=2048, D=1024, H=16, DK=64, DH=4096. I/O fp32; internals bf16 MFMA.
// R20: R19 (32x32x16 gemm_8p) with the LDS fragment-address bug fixed:
// LDA half-stride 4096 (64 rows) / tile-stride 2048 (32 rows) [was 2048/1024],
// LDB n-tile stride 2048 (32 cols) [was 1024]. Schedule = R14 (wait-at-
// consumption counted vmcnt, 2 barriers/tile). LN vectorized. Attention:
// R12+XCD swizzle. prep_all fused input stage.

typedef unsigned short u16;
typedef __attribute__((ext_vector_type(8))) short v8s;   // 8 x bf16
typedef __attribute__((ext_vector_type(4))) float v4f;
typedef __attribute__((ext_vector_type(16))) float v16f;
typedef __attribute__((ext_vector_type(2))) unsigned int v2u;

#define AS1 __attribute__((address_space(1)))
#define AS3 __attribute__((address_space(3)))

__device__ __forceinline__ void gl_lds16(const u16* g, u16* l) {
  __builtin_amdgcn_global_load_lds((const AS1 void*)g, (AS3 void*)l, 16, 0, 0);
}

__device__ __forceinline__ float bf2f(u16 u) {
  union { uint32_t i; float f; } v; v.i = ((uint32_t)u) << 16; return v.f;
}
__device__ __forceinline__ u16 f2bf(float f) {
  union { float f; uint32_t i; } v; v.f = f;
  uint32_t x = v.i;
  return (u16)((x + 0x7FFFu + ((x >> 16) & 1u)) >> 16);  // RNE
}
__device__ __forceinline__ uint32_t fbits(float f) {
  union { float f; uint32_t u; } v; v.f = f; return v.u;
}

// ---------------------------------------------------------------------------
__global__ __launch_bounds__(256) void cvt_f2b(
    const float* __restrict__ src, u16* __restrict__ dst, int n4) {
  int i = (blockIdx.x * 256 + threadIdx.x);
  if (i < n4) {
    float4 v = *(const float4*)(src + (size_t)i * 4);
    ushort4 o;
    o.x = f2bf(v.x); o.y = f2bf(v.y); o.z = f2bf(v.z); o.w = f2bf(v.w);
    *(ushort4*)(dst + (size_t)i * 4) = o;
  }
}

// ---------------------------------------------------------------------------
// prep_all: fused input-stage kernel (big path).
// ---------------------------------------------------------------------------
__global__ __launch_bounds__(256) void prep_all(
    const float* __restrict__ x, const float* __restrict__ Wq,
    const float* __restrict__ Wo, const float* __restrict__ W1,
    const float* __restrict__ W2, u16* __restrict__ xb,
    u16* __restrict__ WqT, u16* __restrict__ WoT,
    u16* __restrict__ W1T, u16* __restrict__ W2T) {
  const int r = blockIdx.x;
  const int tid = threadIdx.x;
  if (r >= 10240) {
    int i = (r - 10240) * 256 + tid;
    float4 v = *(const float4*)(x + (size_t)i * 4);
    ushort4 o;
    o.x = f2bf(v.x); o.y = f2bf(v.y); o.z = f2bf(v.z); o.w = f2bf(v.w);
    *(ushort4*)(xb + (size_t)i * 4) = o;
    return;
  }
  __shared__ float tile[32][33];
  const float* src; u16* dst; int ld_s, ld_d, bx, by;
  if (r < 1024)      { src = Wq; dst = WqT; ld_s = 1024; ld_d = 1024; bx = r & 31; by = r >> 5; }
  else if (r < 2048) { int r2 = r - 1024; src = Wo; dst = WoT; ld_s = 1024; ld_d = 1024; bx = r2 & 31; by = r2 >> 5; }
  else if (r < 6144) { int r2 = r - 2048; src = W1; dst = W1T; ld_s = 4096; ld_d = 1024; bx = r2 & 127; by = r2 >> 7; }
  else               { int r2 = r - 6144; src = W2; dst = W2T; ld_s = 1024; ld_d = 4096; bx = r2 & 31; by = r2 >> 5; }
  const int tx = tid & 31, ty = tid >> 5;
  const int c0 = bx * 32, r0 = by * 32;
#pragma unroll
  for (int j = 0; j < 32; j += 8)
    tile[ty + j][tx] = src[(size_t)(r0 + ty + j) * ld_s + c0 + tx];
  __syncthreads();
#pragma unroll
  for (int j = 0; j < 32; j += 8)
    dst[(size_t)(c0 + ty + j) * ld_d + r0 + tx] = f2bf(tile[tx][ty + j]);
}

// ---------------------------------------------------------------------------
__global__ __launch_bounds__(256) void transpose_f2b(
    const float* __restrict__ src, u16* __restrict__ dst,
    int R, int C, int ld_s, int ld_d) {
  __shared__ float tile[32][33];
  const int tx = threadIdx.x & 31, ty = threadIdx.x >> 5;
  const int c0 = blockIdx.x * 32, r0 = blockIdx.y * 32;
#pragma unroll
  for (int j = 0; j < 32; j += 8)
    tile[ty + j][tx] = src[(size_t)(r0 + ty + j) * ld_s + c0 + tx];
  __syncthreads();
#pragma unroll
  for (int j = 0; j < 32; j += 8)
    dst[(size_t)(c0 + ty + j) * ld_d + r0 + tx] = f2bf(tile[tx][ty + j]);
}

__global__ __launch_bounds__(256) void transpose_b2b(
    const u16* __restrict__ src, u16* __restrict__ dst,
    int R, int C, int ld_s, int ld_d) {
  __shared__ u16 tile[32][33];
  const int tx = threadIdx.x & 31, ty = threadIdx.x >> 5;
  const int c0 = blockIdx.x * 32, r0 = blockIdx.y * 32;
#pragma unroll
  for (int j = 0; j < 32; j += 8)
    tile[ty + j][tx] = src[(size_t)(r0 + ty + j) * ld_s + c0 + tx];
  __syncthreads();
#pragma unroll
  for (int j = 0; j < 32; j += 8)
    dst[(size_t)(c0 + ty + j) * ld_d + r0 + tx] = tile[tx][ty + j];
}

// ---------------------------------------------------------------------------
// gemm_8p: 256x256 tile, BK=64, 512 threads (8 waves: 2M x 4N), 128 KiB LDS,
// 32x32x16 MFMA. R14 wait-at-consumption schedule (2 barriers/K-tile):
//   Ph1: VMC(2)+bar -> LDA0/LDB0 ; stage A02(t+1) ; MFQ(0,0)
//   Ph2:              LDB1       ; stage B01+B23(t+1) ; MFQ(0,1)
//   Ph3: VMC(6)+bar -> LDA1      ; stage A13(t+1) ; MFQ(1,1)
//   Ph4:              MFQ(1,0)
// Per wave: output 128x64 = 4 m-tiles x 2 n-tiles of 32x32; 32 MFMA/K-tile.
// A-frag (m-tile mh*2+i): rows (wm*128 + mh*64 + i*32 + l31) -> byte offsets
// abase + mh*4096 + i*2048. B-frag (n-tile nh): cols (wn*64 + nh*32 + l31)
// -> bbase + nh*2048. Chunk: 8*((2t+hi)^(l31&7)) (row offsets all %8==0).
// C/D: col=l31, row=(r&3)+8*(r>>2)+4*hi. XCD-aware bijective block swizzle.
// z==0 -> C0 (+bias, relu, fp32 or bf16); z=1..3 -> C1/C2/C3 bf16 partials.
// ---------------------------------------------------------------------------
__global__ __launch_bounds__(512, 1) void gemm_8p(
    const u16* __restrict__ A, const u16* __restrict__ Bt,
    const float* __restrict__ bias, void* __restrict__ C0,
    u16* __restrict__ C1, u16* __restrict__ C2, u16* __restrict__ C3,
    int M, int N, int ldk, int klen, int relu, int c0_f32) {
  __shared__ u16 As[2][16384];   // [buf][row*64 + elem], 256 rows x 64 k
  __shared__ u16 Bs[2][16384];
  const int tid = threadIdx.x;
  const int w = tid >> 6, l = tid & 63;
  const int l31 = l & 31, hi = l >> 5;
  const int wm = w >> 2, wn = w & 3;

  // XCD-aware bijective swizzle over full linear id (all launches nwg%8==0)
  const int gx = gridDim.x, gyd = gridDim.y;
  const int nxy = gx * gyd;
  const int nwg = nxy * gridDim.z;
  int lin = blockIdx.x + gx * (blockIdx.y + gyd * blockIdx.z);
  if ((nwg & 7) == 0) lin = (lin & 7) * (nwg >> 3) + (lin >> 3);
  const int z = lin / nxy;
  const int rem = lin - z * nxy;
  const int by = rem / gx;
  const int bx = rem - by * gx;
  const int m0 = by * 256, n0 = bx * 256;
  const int NT = klen >> 6;

  const int rl = tid >> 3;
  const int sw = 8 * ((tid & 7) ^ (rl & 7));
  const u16* gA[4]; const u16* gB[4];
#pragma unroll
  for (int j = 0; j < 4; j++) {
    gA[j] = A + (size_t)(m0 + j * 64 + rl) * ldk + (size_t)z * klen + sw;
    gB[j] = Bt + (size_t)(n0 + j * 64 + rl) * ldk + (size_t)z * klen + sw;
  }
  const int sdst = w * 512;   // wave-uniform LDS base (+ j*4096)

  // fragment chunk offsets per k-step t: 8*((2t+hi) ^ (l31&7))
  int chs[4];
#pragma unroll
  for (int t = 0; t < 4; t++) chs[t] = 8 * ((2 * t + hi) ^ (l31 & 7));
  const int abase = (wm * 128 + l31) * 64;
  const int bbase = (wn * 64 + l31) * 64;

  v16f acc[4][2];
#pragma unroll
  for (int i = 0; i < 4; i++)
#pragma unroll
    for (int j = 0; j < 2; j++)
#pragma unroll
      for (int r = 0; r < 16; r++) acc[i][j][r] = 0.f;

  v8s a[2][4], b[2][4];

#define FENCE() asm volatile("" ::: "memory")
#define VMC(n) asm volatile("s_waitcnt vmcnt(" #n ")" ::: "memory")
#define BARX() { __builtin_amdgcn_s_barrier(); \
                 __builtin_amdgcn_sched_barrier(0); FENCE(); }
#define STGA(q, j, kt) gl_lds16(gA[j] + (size_t)(kt) * 64, &As[q][(j) * 4096 + sdst])
#define STGB(q, j, kt) gl_lds16(gB[j] + (size_t)(kt) * 64, &Bs[q][(j) * 4096 + sdst])
#define LDA(p, mh) { \
  const u16* Ap = &As[p][abase + (mh) * 4096]; \
  _Pragma("unroll") for (int i = 0; i < 2; i++) \
  _Pragma("unroll") for (int t = 0; t < 4; t++) \
    a[i][t] = *(const v8s*)(Ap + i * 2048 + chs[t]); }
#define LDB(p, nh) { \
  const u16* Bp = &Bs[p][bbase + (nh) * 2048]; \
  _Pragma("unroll") for (int t = 0; t < 4; t++) \
    b[nh][t] = *(const v8s*)(Bp + chs[t]); }
#define MFQ(mh, nh) { \
  __builtin_amdgcn_s_setprio(1); \
  _Pragma("unroll") for (int t = 0; t < 4; t++) \
  _Pragma("unroll") for (int i = 0; i < 2; i++) \
    acc[(mh) * 2 + i][nh] = __builtin_amdgcn_mfma_f32_32x32x16_bf16( \
        a[i][t], b[nh][t], acc[(mh) * 2 + i][nh], 0, 0, 0); \
  __builtin_amdgcn_s_setprio(0); }

  // prologue: stage tile 0 into buf0, need-first order: A02, B01, B23, A13.
  STGA(0, 0, 0); STGA(0, 2, 0);
  FENCE();
  STGB(0, 0, 0); STGB(0, 1, 0);
  FENCE();
  STGB(0, 2, 0); STGB(0, 3, 0);
  FENCE();
  STGA(0, 1, 0); STGA(0, 3, 0);

  int p = 0;
  for (int kt = 0; kt < NT - 1; ++kt, p ^= 1) {
    const int q = p ^ 1;
    const int kn = kt + 1;
    // Ph1: A02/B01/B23(kt) landed; A13(kt) still in flight
    VMC(2); BARX();
    LDA(p, 0);
    LDB(p, 0);
    FENCE();
    STGA(q, 0, kn); STGA(q, 2, kn);
    MFQ(0, 0);
    // Ph2: issue all B stages of kt+1 (B23 gets 3 phases of flight)
    LDB(p, 1);
    FENCE();
    STGB(q, 0, kn); STGB(q, 1, kn);
    STGB(q, 2, kn); STGB(q, 3, kn);
    MFQ(0, 1);
    // Ph3: retire A13(kt) (oldest 2 of 8 in flight)
    VMC(6); BARX();
    LDA(p, 1);
    FENCE();
    STGA(q, 1, kn); STGA(q, 3, kn);
    MFQ(1, 1);
    // Ph4: pure MFMA; next tile-boundary drain overlaps this cluster
    MFQ(1, 0);
  }
  // peeled last tile: drain everything; no staging.
  VMC(0); BARX();
  LDA(p, 0);
  LDB(p, 0);
  MFQ(0, 0);
  LDB(p, 1);
  MFQ(0, 1);
  LDA(p, 1);
  MFQ(1, 1);
  MFQ(1, 0);

#undef FENCE
#undef VMC
#undef BARX
#undef STGA
#undef STGB
#undef LDA
#undef LDB
#undef MFQ

#pragma unroll
  for (int mi = 0; mi < 4; mi++) {
#pragma unroll
    for (int ni = 0; ni < 2; ni++) {
      const int col = n0 + wn * 64 + ni * 32 + l31;
      float bv = (bias && z == 0) ? bias[col] : 0.f;
#pragma unroll
      for (int r = 0; r < 16; r++) {
        const int row = m0 + wm * 128 + mi * 32 + (r & 3) + 8 * (r >> 2) + 4 * hi;
        float v = acc[mi][ni][r] + bv;
        if (z == 0 && relu) v = fmaxf(v, 0.f);
        size_t idx = (size_t)row * N + col;
        if (z == 0) {
          if (c0_f32) ((float*)C0)[idx] = v;
          else ((u16*)C0)[idx] = f2bf(v);
        } else if (z == 1) {
          C1[idx] = f2bf(v);
        } else if (z == 2) {
          C2[idx] = f2bf(v);
        } else {
          C3[idx] = f2bf(v);
        }
      }
    }
  }
}

// ---------------------------------------------------------------------------
// G2: 128x64 tile, BK=64, double-buffered (Qproj + small path).
// ---------------------------------------------------------------------------
__global__ __launch_bounds__(256) void gemm_g2(
    const u16* __restrict__ A, const u16* __restrict__ Bt,
    const float* __restrict__ bias, void* __restrict__ C,
    int M, int N, int K, int relu, int accum, int out_f32) {
  __shared__ u16 As[2][8192];
  __shared__ u16 Bs[2][4096];
  const int tid = threadIdx.x;
  const int w = tid >> 6, l = tid & 63;
  const int l16 = l & 15, kgrp = l >> 4;
  const int m0 = blockIdx.y * 128, n0 = blockIdx.x * 64;
  const int wr = (w >> 1) * 64, wc = (w & 1) * 32;

  const int srow = w * 8 + (l >> 3);
  const u16* gA[4];
#pragma unroll
  for (int i = 0; i < 4; i++) {
    int r = i * 32 + srow;
    gA[i] = A + (size_t)(m0 + r) * K + 8 * ((l & 7) ^ (r & 7));
  }
  const u16* gB[2];
#pragma unroll
  for (int i = 0; i < 2; i++) {
    int r = i * 32 + srow;
    gB[i] = Bt + (size_t)(n0 + r) * K + 8 * ((l & 7) ^ (r & 7));
  }

  v4f acc[4][2];
#pragma unroll
  for (int i = 0; i < 4; i++)
#pragma unroll
    for (int j = 0; j < 2; j++)
#pragma unroll
      for (int r = 0; r < 4; r++) acc[i][j][r] = 0.f;

#pragma unroll
  for (int i = 0; i < 4; i++) gl_lds16(gA[i], &As[0][(i * 256 + w * 64) * 8]);
#pragma unroll
  for (int i = 0; i < 2; i++) gl_lds16(gB[i], &Bs[0][(i * 256 + w * 64) * 8]);

  int cur = 0;
  for (int k0 = 0; k0 < K; k0 += 64) {
    __syncthreads();
    if (k0 + 64 < K) {
      int nxt = cur ^ 1;
#pragma unroll
      for (int i = 0; i < 4; i++)
        gl_lds16(gA[i] + k0 + 64, &As[nxt][(i * 256 + w * 64) * 8]);
#pragma unroll
      for (int i = 0; i < 2; i++)
        gl_lds16(gB[i] + k0 + 64, &Bs[nxt][(i * 256 + w * 64) * 8]);
    }
    v8s a[4][2], b[2][2];
#pragma unroll
    for (int ks = 0; ks < 2; ks++) {
      int ch = 8 * ((ks * 4 + kgrp) ^ (l16 & 7));
#pragma unroll
      for (int mi = 0; mi < 4; mi++)
        a[mi][ks] = *(const v8s*)(&As[cur][(wr + mi * 16 + l16) * 64 + ch]);
#pragma unroll
      for (int ni = 0; ni < 2; ni++)
        b[ni][ks] = *(const v8s*)(&Bs[cur][(wc + ni * 16 + l16) * 64 + ch]);
    }
#pragma unroll
    for (int ks = 0; ks < 2; ks++)
#pragma unroll
      for (int mi = 0; mi < 4; mi++)
#pragma unroll
        for (int ni = 0; ni < 2; ni++)
          acc[mi][ni] = __builtin_amdgcn_mfma_f32_16x16x32_bf16(a[mi][ks], b[ni][ks], acc[mi][ni], 0, 0, 0);
    cur ^= 1;
  }

#pragma unroll
  for (int ni = 0; ni < 2; ni++) {
    int col = n0 + wc + ni * 16 + l16;
    float bv = bias ? bias[col] : 0.f;
#pragma unroll
    for (int mi = 0; mi < 4; mi++) {
      int row = m0 + wr + mi * 16 + kgrp * 4;
#pragma unroll
      for (int r = 0; r < 4; r++) {
        float v = acc[mi][ni][r] + bv;
        if (relu) v = fmaxf(v, 0.f);
        size_t idx = (size_t)(row + r) * N + col;
        if (out_f32) {
          float* Cf = (float*)C;
          if (accum) v += Cf[idx];
          Cf[idx] = v;
        } else {
          ((u16*)C)[idx] = f2bf(v);
        }
      }
    }
  }
}

// ---------------------------------------------------------------------------
// Attention (R12 structure + XCD swizzle): O = softmax(Q Q^T / sqrt(S)) Q.
// 512 threads, 8 waves x 32 q-rows (256-row blocks), 32x32x16 MFMA,
// P fully in-register (perm-pack + permlane32_swap). Grid (8, 32) = 256.
// ---------------------------------------------------------------------------
__global__ __launch_bounds__(512) void attn_kernel(
    const u16* __restrict__ Q, const u16* __restrict__ Qt,
    u16* __restrict__ O) {
  __shared__ u16 KV[2][8192];
  const int tid = threadIdx.x;
  const int w = tid >> 6, l = tid & 63;
  const int l31 = l & 31, hi = l >> 5;

  // XCD-aware bijective swizzle (nwg % 8 == 0)
  const int gx = gridDim.x;
  const int nwg = gx * gridDim.y;
  int lin = blockIdx.x + gx * blockIdx.y;
  if ((nwg & 7) == 0) lin = (lin & 7) * (nwg >> 3) + (lin >> 3);
  const int bxi = lin % gx;
  const int bh = lin / gx;
  const int b = bh >> 4, h = bh & 15;
  const int q0 = bxi * 256;
  const size_t rowQ = (size_t)(b * 2048 + q0 + w * 32);
  const float cexp = 1.4426950408889634f / 45.254833995939045f;

  const int isV = w >> 2, wl = w & 3;
  const int r0 = wl * 16 + (l >> 3);
  const int sch8 = 8 * ((l & 7) ^ (l >> 3));
  const u16* gS0;
  size_t kstep;
  if (!isV) {
    gS0 = Q + (size_t)(b * 2048 + r0) * 1024 + h * 64 + sch8;
    kstep = 1024;
  } else {
    gS0 = Qt + (size_t)(h * 64 + r0) * 4096 + b * 2048 + sch8;
    kstep = 1;
  }
  const u16* gS1 = gS0 + (size_t)8 * (isV ? 4096 : 1024);
  const int ldst = isV * 4096 + wl * 1024;

  v8s qb[4];
#pragma unroll
  for (int t = 0; t < 4; t++) {
    v8s v = *(const v8s*)(Q + (rowQ + l31) * 1024 + h * 64 + t * 16 + hi * 8);
#pragma unroll
    for (int j = 0; j < 8; j++) v[j] = (short)f2bf(bf2f((u16)v[j]) * cexp);
    qb[t] = v;
  }

  v16f o0, o1;
#pragma unroll
  for (int r = 0; r < 16; r++) { o0[r] = 0.f; o1[r] = 0.f; }
  float ls = 0.f;

  gl_lds16(gS0, &KV[0][ldst]);
  gl_lds16(gS1, &KV[0][ldst + 512]);

  int cur = 0;
  for (int kb = 0; kb < 2048; kb += 64) {
    __syncthreads();
    if (kb + 64 < 2048) {
      int nxt = cur ^ 1;
      gl_lds16(gS0 + (size_t)(kb + 64) * kstep, &KV[nxt][ldst]);
      gl_lds16(gS1 + (size_t)(kb + 64) * kstep, &KV[nxt][ldst + 512]);
    }
    const u16* Ks = &KV[cur][0];
    const u16* Vt = &KV[cur][4096];

    v16f s0, s1;
#pragma unroll
    for (int r = 0; r < 16; r++) { s0[r] = 0.f; s1[r] = 0.f; }
#pragma unroll
    for (int t = 0; t < 4; t++) {
      const int c = 8 * ((2 * t + hi) ^ (l & 7));
      v8s ka0 = *(const v8s*)(Ks + l31 * 64 + c);
      v8s ka1 = *(const v8s*)(Ks + (32 + l31) * 64 + c);
      s0 = __builtin_amdgcn_mfma_f32_32x32x16_bf16(ka0, qb[t], s0, 0, 0, 0);
      s1 = __builtin_amdgcn_mfma_f32_32x32x16_bf16(ka1, qb[t], s1, 0, 0, 0);
    }

    float p0[16], p1[16];
#pragma unroll
    for (int r = 0; r < 16; r++) {
      p0[r] = __builtin_amdgcn_exp2f(s0[r]);
      p1[r] = __builtin_amdgcn_exp2f(s1[r]);
      ls += p0[r] + p1[r];
    }

#define PVSTEP(t, P) { \
      const int off = 8 * ((t) & 1); \
      uint32_t dw00 = __builtin_amdgcn_perm(fbits(P[off + 1]), fbits(P[off + 0]), 0x07060302u); \
      uint32_t dw01 = __builtin_amdgcn_perm(fbits(P[off + 3]), fbits(P[off + 2]), 0x07060302u); \
      uint32_t dw10 = __builtin_amdgcn_perm(fbits(P[off + 5]), fbits(P[off + 4]), 0x07060302u); \
      uint32_t dw11 = __builtin_amdgcn_perm(fbits(P[off + 7]), fbits(P[off + 6]), 0x07060302u); \
      v2u sA = __builtin_amdgcn_permlane32_swap(dw00, dw10, false, false); \
      v2u sB = __builtin_amdgcn_permlane32_swap(dw01, dw11, false, false); \
      union { uint32_t u[4]; v8s v; } pa; \
      pa.u[0] = sA[0]; pa.u[1] = sB[0]; pa.u[2] = sA[1]; pa.u[3] = sB[1]; \
      const int c = 8 * ((2 * (t) + hi) ^ (l & 7)); \
      v8s vb0 = *(const v8s*)(Vt + l31 * 64 + c); \
      v8s vb1 = *(const v8s*)(Vt + (32 + l31) * 64 + c); \
      o0 = __builtin_amdgcn_mfma_f32_32x32x16_bf16(pa.v, vb0, o0, 0, 0, 0); \
      o1 = __builtin_amdgcn_mfma_f32_32x32x16_bf16(pa.v, vb1, o1, 0, 0, 0); }
    PVSTEP(0, p0)
    PVSTEP(1, p0)
    PVSTEP(2, p1)
    PVSTEP(3, p1)
#undef PVSTEP
    cur ^= 1;
  }

  ls += __shfl_xor(ls, 32, 64);   // den[q] at lanes with l31 == q

  const int hiq = hi * 4;
#pragma unroll
  for (int r = 0; r < 16; r++) {
    const int qo = (r & 3) + 8 * (r >> 2) + hiq;
    float den = __shfl(ls, qo, 64);
    float rden = 1.f / den;
    O[(rowQ + qo) * 1024 + h * 64 + l31] = f2bf(o0[r] * rden);
    O[(rowQ + qo) * 1024 + h * 64 + 32 + l31] = f2bf(o1[r] * rden);
  }
}

// ---------------------------------------------------------------------------
// out = LayerNorm(Y [+ Y2 + Y3 + Y4] + Xr) * g + b; row length 1024; dtype
// flags (1 = fp32, 0 = bf16). Vectorized: 4 consecutive elems per thread.
// In-place safe.
// ---------------------------------------------------------------------------
__global__ __launch_bounds__(256) void ln_residual(
    const void* __restrict__ Y, const void* __restrict__ Y2,
    const void* __restrict__ Y3, const void* __restrict__ Y4,
    const void* __restrict__ Xr,
    const float* __restrict__ g, const float* __restrict__ bb,
    void* __restrict__ out, int yf, int y2f, int xf, int of) {
  const int row = blockIdx.x, tid = threadIdx.x;
  const size_t base = (size_t)row * 1024;
  const int c0 = tid * 4;
  float v[4];
  if (yf) {
    float4 t = *(const float4*)((const float*)Y + base + c0);
    v[0] = t.x; v[1] = t.y; v[2] = t.z; v[3] = t.w;
  } else {
    ushort4 t = *(const ushort4*)((const u16*)Y + base + c0);
    v[0] = bf2f(t.x); v[1] = bf2f(t.y); v[2] = bf2f(t.z); v[3] = bf2f(t.w);
  }
  if (xf) {
    float4 t = *(const float4*)((const float*)Xr + base + c0);
    v[0] += t.x; v[1] += t.y; v[2] += t.z; v[3] += t.w;
  } else {
    ushort4 t = *(const ushort4*)((const u16*)Xr + base + c0);
    v[0] += bf2f(t.x); v[1] += bf2f(t.y); v[2] += bf2f(t.z); v[3] += bf2f(t.w);
  }
  if (Y2) {
    if (y2f) {
      float4 t = *(const float4*)((const float*)Y2 + base + c0);
      v[0] += t.x; v[1] += t.y; v[2] += t.z; v[3] += t.w;
    } else {
      ushort4 t = *(const ushort4*)((const u16*)Y2 + base + c0);
      v[0] += bf2f(t.x); v[1] += bf2f(t.y); v[2] += bf2f(t.z); v[3] += bf2f(t.w);
    }
  }
  if (Y3) {
    ushort4 t = *(const ushort4*)((const u16*)Y3 + base + c0);
    v[0] += bf2f(t.x); v[1] += bf2f(t.y); v[2] += bf2f(t.z); v[3] += bf2f(t.w);
  }
  if (Y4) {
    ushort4 t = *(const ushort4*)((const u16*)Y4 + base + c0);
    v[0] += bf2f(t.x); v[1] += bf2f(t.y); v[2] += bf2f(t.z); v[3] += bf2f(t.w);
  }
  float s = (v[0] + v[1]) + (v[2] + v[3]);
  float sq = (v[0] * v[0] + v[1] * v[1]) + (v[2] * v[2] + v[3] * v[3]);
#pragma unroll
  for (int off = 32; off >= 1; off >>= 1) {
    s += __shfl_down(s, off, 64);
    sq += __shfl_down(sq, off, 64);
  }
  __shared__ float rs[4], rq[4];
  const int w = tid >> 6, l = tid & 63;
  if (l == 0) { rs[w] = s; rq[w] = sq; }
  __syncthreads();
  s = rs[0] + rs[1] + rs[2] + rs[3];
  sq = rq[0] + rq[1] + rq[2] + rq[3];
  const float mu = s * (1.f / 1024.f);
  const float var = sq * (1.f / 1024.f) - mu * mu;
  const float rstd = rsqrtf(var + 1e-5f);
  float4 gg = *(const float4*)(g + c0);
  float4 bv = *(const float4*)(bb + c0);
  float r0 = (v[0] - mu) * rstd * gg.x + bv.x;
  float r1 = (v[1] - mu) * rstd * gg.y + bv.y;
  float r2 = (v[2] - mu) * rstd * gg.z + bv.z;
  float r3 = (v[3] - mu) * rstd * gg.w + bv.w;
  if (of) {
    float4 o = {r0, r1, r2, r3};
    *(float4*)((float*)out + base + c0) = o;
  } else {
    ushort4 o;
    o.x = f2bf(r0); o.y = f2bf(r1); o.z = f2bf(r2); o.w = f2bf(r3);
    *(ushort4*)((u16*)out + base + c0) = o;
  }
}

// ---------------------------------------------------------------------------
extern "C" void kernel_launch(void* const* d_in, const int* in_sizes, int n_in,
                              void* d_out, int out_size, void* d_ws, size_t ws_size,
                              hipStream_t stream) {
  const float* x   = (const float*)d_in[0];
  const float* Wq  = (const float*)d_in[1];
  const float* bq  = (const float*)d_in[2];
  const float* Wo  = (const float*)d_in[3];
  const float* bo  = (const float*)d_in[4];
  const float* g1  = (const float*)d_in[5];
  const float* be1 = (const float*)d_in[6];
  const float* W1  = (const float*)d_in[7];
  const float* b1  = (const float*)d_in[8];
  const float* W2  = (const float*)d_in[9];
  const float* b2  = (const float*)d_in[10];
  const float* g2  = (const float*)d_in[11];
  const float* be2 = (const float*)d_in[12];
  float* out = (float*)d_out;
  u16* ws  = (u16*)d_ws;

  const size_t M1 = 1048576;
  dim3 blk(256);
  dim3 blk8(512);
  const bool big = ws_size >= (size_t)37 * M1 * 2;  // 74 MiB

  if (big) {
    // Layout (u16 offsets):
    //  [0..4M)   xb  -> attn out -> P2_ffn2
    //  [4..8M)   Qb  -> x1
    //  [8..12M)  Qt  -> Yb (Wo P0) -> P1_ffn2
    //  [12..13M) WqT
    //  [13..17M) W1T -> P3_ffn2 (after FFN1)
    //  [17..21M) W2T
    //  [21..37M) Hh; transient before FFN1: Wo partials P1/P2/P3 @21/25/29M,
    //            WoT @33M (all dead before FFN1 overwrites Hh)
    u16* xb   = ws + 0;
    u16* Qb   = ws + 4 * M1;
    u16* Qt   = ws + 8 * M1;
    u16* WqT  = ws + 12 * M1;
    u16* W1T  = ws + 13 * M1;
    u16* W2T  = ws + 17 * M1;
    u16* Hh   = ws + 21 * M1;
    u16* P1wo = ws + 21 * M1;
    u16* P2wo = ws + 25 * M1;
    u16* P3wo = ws + 29 * M1;
    u16* WoT  = ws + 33 * M1;
    u16* attn = xb;  u16* Yb = Qt;  u16* x1 = Qb;
    u16* P1f2 = Qt;              // Yb dead after LN1
    u16* P2f2 = xb;              // attn dead after Wo-proj
    u16* P3f2 = W1T;             // W1T dead after FFN1

    // 1: fused input convert + all four weight transposes
    prep_all<<<dim3(14336), blk, 0, stream>>>(x, Wq, Wo, W1, W2,
                                              xb, WqT, WoT, W1T, W2T);
    // 2: Q projection
    gemm_g2<<<dim3(16, 32), blk, 0, stream>>>(xb, WqT, bq, Qb, 4096, 1024, 1024, 0, 0, 0);
    // 3: Q transpose (for attn V-side access)
    transpose_b2b<<<dim3(32, 128), blk, 0, stream>>>(Qb, Qt, 4096, 1024, 1024, 4096);
    // 4: attention
    attn_kernel<<<dim3(8, 32), blk8, 0, stream>>>(Qb, Qt, attn);
    // 5: Wo projection: split-K=4, P0 -> Yb (bf16, +bias)
    gemm_8p<<<dim3(4, 16, 4), blk8, 0, stream>>>(attn, WoT, bo, Yb, P1wo, P2wo, P3wo,
                                                 4096, 1024, 1024, 256, 0, 0);
    // 6: LN1 (folds Wo split-K partials + residual)
    ln_residual<<<dim3(4096), blk, 0, stream>>>(Yb, P1wo, P2wo, P3wo, x, g1, be1, x1,
                                                0, 0, 1, 0);
    // 7: FFN1 (full-K, 256 blocks)
    gemm_8p<<<dim3(16, 16, 1), blk8, 0, stream>>>(x1, W1T, b1, Hh,
                                                  nullptr, nullptr, nullptr,
                                                  4096, 4096, 1024, 1024, 1, 0);
    // 8: FFN2: split-K=4, P0 -> out (fp32, +bias)
    gemm_8p<<<dim3(4, 16, 4), blk8, 0, stream>>>(Hh, W2T, b2, out, P1f2, P2f2, P3f2,
                                                 4096, 1024, 4096, 1024, 0, 1);
    // 9: LN2 (folds FFN2 split-K partials + residual)
    ln_residual<<<dim3(4096), blk, 0, stream>>>(out, P1f2, P2f2, P3f2, x1, g2, be2, out,
                                                1, 0, 0, 1);
  } else {
    u16* xb   = ws + 0;
    u16* Qb   = ws + 4 * M1;
    u16* Qt   = ws + 8 * M1;
    u16* attn = xb;  u16* Yb = Qt;  u16* x1 = Qb;  u16* Hc = xb;
    u16* Wt1  = ws + 12 * M1;
    u16* Wt2  = ws + 13 * M1;

    cvt_f2b<<<dim3(4096), blk, 0, stream>>>(x, xb, 1048576);
    transpose_f2b<<<dim3(32, 32), blk, 0, stream>>>(Wq, Wt1, 1024, 1024, 1024, 1024);
    gemm_g2<<<dim3(16, 32), blk, 0, stream>>>(xb, Wt1, bq, Qb, 4096, 1024, 1024, 0, 0, 0);

    transpose_b2b<<<dim3(32, 128), blk, 0, stream>>>(Qb, Qt, 4096, 1024, 1024, 4096);
    attn_kernel<<<dim3(8, 32), blk8, 0, stream>>>(Qb, Qt, attn);

    transpose_f2b<<<dim3(32, 32), blk, 0, stream>>>(Wo, Wt2, 1024, 1024, 1024, 1024);
    gemm_g2<<<dim3(16, 32), blk, 0, stream>>>(attn, Wt2, bo, Yb, 4096, 1024, 1024, 0, 0, 0);
    ln_residual<<<dim3(4096), blk, 0, stream>>>(Yb, nullptr, nullptr, nullptr, x, g1, be1,
                                                x1, 0, 0, 1, 0);

    for (int c = 0; c < 4; c++) {
      transpose_f2b<<<dim3(32, 32), blk, 0, stream>>>(W1 + (size_t)c * 1024, Wt1,
                                                      1024, 1024, 4096, 1024);
      gemm_g2<<<dim3(16, 32), blk, 0, stream>>>(x1, Wt1, b1 + (size_t)c * 1024, Hc,
                                                4096, 1024, 1024, 1, 0, 0);
      transpose_f2b<<<dim3(32, 32), blk, 0, stream>>>(W2 + (size_t)c * M1, Wt2,
                                                      1024, 1024, 1024, 1024);
      gemm_g2<<<dim3(16, 32), blk, 0, stream>>>(Hc, Wt2, (c == 0) ? b2 : (const float*)nullptr,
                                                out, 4096, 1024, 1024, 0, (c > 0) ? 1 : 0, 1);
    }
    ln_residual<<<dim3(4096), blk, 0, stream>>>(out, nullptr, nullptr, nullptr, x1, g2, be2,
                                                out, 1, 0, 0, 1);
  }
}

// Round 14
// 315.253 us; speedup vs baseline: 1.0842x; 1.0028x over previous
//
#include <hip/hip_runtime.h>
#include <stdint.h>

// B=2, S=2048, D=1024, H=16, DK=64, DH=4096. I/O fp32; internals bf16 MFMA.
// R21: best-of composition. gemm_8p reverted to the 16x16x32 R14 kernel
// (46.2 us measured, 0 bank conflicts; the 32x32 variant measured 51.5 --
// shape refuted for this schedule). Kept: vectorized LN (R18), prep_all
// fusion (R17), attn R12 + XCD swizzle (R17), wait-at-consumption counted
// vmcnt schedule (R14), split-K=4 + LN-fold (R9), XCD swizzle (R13).

typedef unsigned short u16;
typedef __attribute__((ext_vector_type(8))) short v8s;   // 8 x bf16
typedef __attribute__((ext_vector_type(4))) float v4f;
typedef __attribute__((ext_vector_type(16))) float v16f;
typedef __attribute__((ext_vector_type(2))) unsigned int v2u;

#define AS1 __attribute__((address_space(1)))
#define AS3 __attribute__((address_space(3)))

__device__ __forceinline__ void gl_lds16(const u16* g, u16* l) {
  __builtin_amdgcn_global_load_lds((const AS1 void*)g, (AS3 void*)l, 16, 0, 0);
}

__device__ __forceinline__ float bf2f(u16 u) {
  union { uint32_t i; float f; } v; v.i = ((uint32_t)u) << 16; return v.f;
}
__device__ __forceinline__ u16 f2bf(float f) {
  union { float f; uint32_t i; } v; v.f = f;
  uint32_t x = v.i;
  return (u16)((x + 0x7FFFu + ((x >> 16) & 1u)) >> 16);  // RNE
}
__device__ __forceinline__ uint32_t fbits(float f) {
  union { float f; uint32_t u; } v; v.f = f; return v.u;
}

// ---------------------------------------------------------------------------
__global__ __launch_bounds__(256) void cvt_f2b(
    const float* __restrict__ src, u16* __restrict__ dst, int n4) {
  int i = (blockIdx.x * 256 + threadIdx.x);
  if (i < n4) {
    float4 v = *(const float4*)(src + (size_t)i * 4);
    ushort4 o;
    o.x = f2bf(v.x); o.y = f2bf(v.y); o.z = f2bf(v.z); o.w = f2bf(v.w);
    *(ushort4*)(dst + (size_t)i * 4) = o;
  }
}

// ---------------------------------------------------------------------------
// prep_all: fused input-stage kernel (big path).
// ---------------------------------------------------------------------------
__global__ __launch_bounds__(256) void prep_all(
    const float* __restrict__ x, const float* __restrict__ Wq,
    const float* __restrict__ Wo, const float* __restrict__ W1,
    const float* __restrict__ W2, u16* __restrict__ xb,
    u16* __restrict__ WqT, u16* __restrict__ WoT,
    u16* __restrict__ W1T, u16* __restrict__ W2T) {
  const int r = blockIdx.x;
  const int tid = threadIdx.x;
  if (r >= 10240) {
    int i = (r - 10240) * 256 + tid;
    float4 v = *(const float4*)(x + (size_t)i * 4);
    ushort4 o;
    o.x = f2bf(v.x); o.y = f2bf(v.y); o.z = f2bf(v.z); o.w = f2bf(v.w);
    *(ushort4*)(xb + (size_t)i * 4) = o;
    return;
  }
  __shared__ float tile[32][33];
  const float* src; u16* dst; int ld_s, ld_d, bx, by;
  if (r < 1024)      { src = Wq; dst = WqT; ld_s = 1024; ld_d = 1024; bx = r & 31; by = r >> 5; }
  else if (r < 2048) { int r2 = r - 1024; src = Wo; dst = WoT; ld_s = 1024; ld_d = 1024; bx = r2 & 31; by = r2 >> 5; }
  else if (r < 6144) { int r2 = r - 2048; src = W1; dst = W1T; ld_s = 4096; ld_d = 1024; bx = r2 & 127; by = r2 >> 7; }
  else               { int r2 = r - 6144; src = W2; dst = W2T; ld_s = 1024; ld_d = 4096; bx = r2 & 31; by = r2 >> 5; }
  const int tx = tid & 31, ty = tid >> 5;
  const int c0 = bx * 32, r0 = by * 32;
#pragma unroll
  for (int j = 0; j < 32; j += 8)
    tile[ty + j][tx] = src[(size_t)(r0 + ty + j) * ld_s + c0 + tx];
  __syncthreads();
#pragma unroll
  for (int j = 0; j < 32; j += 8)
    dst[(size_t)(c0 + ty + j) * ld_d + r0 + tx] = f2bf(tile[tx][ty + j]);
}

// ---------------------------------------------------------------------------
__global__ __launch_bounds__(256) void transpose_f2b(
    const float* __restrict__ src, u16* __restrict__ dst,
    int R, int C, int ld_s, int ld_d) {
  __shared__ float tile[32][33];
  const int tx = threadIdx.x & 31, ty = threadIdx.x >> 5;
  const int c0 = blockIdx.x * 32, r0 = blockIdx.y * 32;
#pragma unroll
  for (int j = 0; j < 32; j += 8)
    tile[ty + j][tx] = src[(size_t)(r0 + ty + j) * ld_s + c0 + tx];
  __syncthreads();
#pragma unroll
  for (int j = 0; j < 32; j += 8)
    dst[(size_t)(c0 + ty + j) * ld_d + r0 + tx] = f2bf(tile[tx][ty + j]);
}

__global__ __launch_bounds__(256) void transpose_b2b(
    const u16* __restrict__ src, u16* __restrict__ dst,
    int R, int C, int ld_s, int ld_d) {
  __shared__ u16 tile[32][33];
  const int tx = threadIdx.x & 31, ty = threadIdx.x >> 5;
  const int c0 = blockIdx.x * 32, r0 = blockIdx.y * 32;
#pragma unroll
  for (int j = 0; j < 32; j += 8)
    tile[ty + j][tx] = src[(size_t)(r0 + ty + j) * ld_s + c0 + tx];
  __syncthreads();
#pragma unroll
  for (int j = 0; j < 32; j += 8)
    dst[(size_t)(c0 + ty + j) * ld_d + r0 + tx] = tile[tx][ty + j];
}

// ---------------------------------------------------------------------------
// gemm_8p: 256x256 tile, BK=64, 512 threads (8 waves: 2M x 4N), 128 KiB LDS,
// 16x16x32 MFMA. R14 wait-at-consumption schedule (2 barriers/K-tile):
//   Ph1: VMC(2)+bar -> LDA0/LDB0 ; stage A02(t+1) ; MFQ(0,0)
//   Ph2:              LDB1       ; stage B01+B23(t+1) ; MFQ(0,1)
//   Ph3: VMC(6)+bar -> LDA1      ; stage A13(t+1) ; MFQ(1,1)
//   Ph4:              MFQ(1,0)
// Ledger: in-flight peaks at 8 loads; all loads >=3 phases of flight.
// XCD-aware bijective block swizzle (nwg%8==0 for all launches).
// z==0 -> C0 (+bias, relu, fp32 or bf16); z=1..3 -> C1/C2/C3 bf16 partials.
// ---------------------------------------------------------------------------
__global__ __launch_bounds__(512, 1) void gemm_8p(
    const u16* __restrict__ A, const u16* __restrict__ Bt,
    const float* __restrict__ bias, void* __restrict__ C0,
    u16* __restrict__ C1, u16* __restrict__ C2, u16* __restrict__ C3,
    int M, int N, int ldk, int klen, int relu, int c0_f32) {
  __shared__ u16 As[2][16384];   // [buf][row*64 + elem], 256 rows x 64 k
  __shared__ u16 Bs[2][16384];
  const int tid = threadIdx.x;
  const int w = tid >> 6, l = tid & 63;
  const int l16 = l & 15, kgrp = (l >> 4) & 3;
  const int wm = w >> 2, wn = w & 3;

  // XCD-aware bijective swizzle over full linear id (all launches nwg%8==0)
  const int gx = gridDim.x, gyd = gridDim.y;
  const int nxy = gx * gyd;
  const int nwg = nxy * gridDim.z;
  int lin = blockIdx.x + gx * (blockIdx.y + gyd * blockIdx.z);
  if ((nwg & 7) == 0) lin = (lin & 7) * (nwg >> 3) + (lin >> 3);
  const int z = lin / nxy;
  const int rem = lin - z * nxy;
  const int by = rem / gx;
  const int bx = rem - by * gx;
  const int m0 = by * 256, n0 = bx * 256;
  const int NT = klen >> 6;

  const int rl = tid >> 3;
  const int sw = 8 * ((tid & 7) ^ (rl & 7));
  const u16* gA[4]; const u16* gB[4];
#pragma unroll
  for (int j = 0; j < 4; j++) {
    gA[j] = A + (size_t)(m0 + j * 64 + rl) * ldk + (size_t)z * klen + sw;
    gB[j] = Bt + (size_t)(n0 + j * 64 + rl) * ldk + (size_t)z * klen + sw;
  }
  const int sdst = w * 512;   // wave-uniform LDS base (+ j*4096)

  const int ch0 = 8 * ((kgrp) ^ (l16 & 7));
  const int ch1 = 8 * ((4 + kgrp) ^ (l16 & 7));
  const int abase = (wm * 128 + l16) * 64;
  const int bbase = (wn * 64 + l16) * 64;

  v4f acc[8][4];
#pragma unroll
  for (int i = 0; i < 8; i++)
#pragma unroll
    for (int j = 0; j < 4; j++)
#pragma unroll
      for (int r = 0; r < 4; r++) acc[i][j][r] = 0.f;

  v8s a[4][2], b[4][2];

#define FENCE() asm volatile("" ::: "memory")
#define VMC(n) asm volatile("s_waitcnt vmcnt(" #n ")" ::: "memory")
#define BARX() { __builtin_amdgcn_s_barrier(); \
                 __builtin_amdgcn_sched_barrier(0); FENCE(); }
#define STGA(q, j, kt) gl_lds16(gA[j] + (size_t)(kt) * 64, &As[q][(j) * 4096 + sdst])
#define STGB(q, j, kt) gl_lds16(gB[j] + (size_t)(kt) * 64, &Bs[q][(j) * 4096 + sdst])
#define LDA(p, mh) { \
  const u16* Ap = &As[p][abase + (mh) * 4096]; \
  _Pragma("unroll") for (int mi = 0; mi < 4; mi++) { \
    a[mi][0] = *(const v8s*)(Ap + mi * 1024 + ch0); \
    a[mi][1] = *(const v8s*)(Ap + mi * 1024 + ch1); } }
#define LDB(p, nh) { \
  const u16* Bp = &Bs[p][bbase + (nh) * 2048]; \
  _Pragma("unroll") for (int ni = 0; ni < 2; ni++) { \
    b[(nh) * 2 + ni][0] = *(const v8s*)(Bp + ni * 1024 + ch0); \
    b[(nh) * 2 + ni][1] = *(const v8s*)(Bp + ni * 1024 + ch1); } }
#define MFQ(mh, nh) { \
  __builtin_amdgcn_s_setprio(1); \
  _Pragma("unroll") for (int ks = 0; ks < 2; ks++) \
  _Pragma("unroll") for (int mi = 0; mi < 4; mi++) \
  _Pragma("unroll") for (int ni = 0; ni < 2; ni++) \
    acc[(mh) * 4 + mi][(nh) * 2 + ni] = __builtin_amdgcn_mfma_f32_16x16x32_bf16( \
        a[mi][ks], b[(nh) * 2 + ni][ks], acc[(mh) * 4 + mi][(nh) * 2 + ni], 0, 0, 0); \
  __builtin_amdgcn_s_setprio(0); }

  // prologue: stage tile 0 into buf0, need-first order: A02, B01, B23, A13.
  STGA(0, 0, 0); STGA(0, 2, 0);
  FENCE();
  STGB(0, 0, 0); STGB(0, 1, 0);
  FENCE();
  STGB(0, 2, 0); STGB(0, 3, 0);
  FENCE();
  STGA(0, 1, 0); STGA(0, 3, 0);

  int p = 0;
  for (int kt = 0; kt < NT - 1; ++kt, p ^= 1) {
    const int q = p ^ 1;
    const int kn = kt + 1;
    // Ph1: A02/B01/B23(kt) landed; A13(kt) still in flight
    VMC(2); BARX();
    LDA(p, 0);
    LDB(p, 0);
    FENCE();
    STGA(q, 0, kn); STGA(q, 2, kn);
    MFQ(0, 0);
    // Ph2: issue all B stages of kt+1 (B23 gets 3 phases of flight)
    LDB(p, 1);
    FENCE();
    STGB(q, 0, kn); STGB(q, 1, kn);
    STGB(q, 2, kn); STGB(q, 3, kn);
    MFQ(0, 1);
    // Ph3: retire A13(kt) (oldest 2 of 8 in flight)
    VMC(6); BARX();
    LDA(p, 1);
    FENCE();
    STGA(q, 1, kn); STGA(q, 3, kn);
    MFQ(1, 1);
    // Ph4: pure MFMA; next tile-boundary drain overlaps this cluster
    MFQ(1, 0);
  }
  // peeled last tile: drain everything; no staging.
  VMC(0); BARX();
  LDA(p, 0);
  LDB(p, 0);
  MFQ(0, 0);
  LDB(p, 1);
  MFQ(0, 1);
  LDA(p, 1);
  MFQ(1, 1);
  MFQ(1, 0);

#undef FENCE
#undef VMC
#undef BARX
#undef STGA
#undef STGB
#undef LDA
#undef LDB
#undef MFQ

#pragma unroll
  for (int mi = 0; mi < 8; mi++) {
    const int row = m0 + wm * 128 + mi * 16 + kgrp * 4;
#pragma unroll
    for (int ni = 0; ni < 4; ni++) {
      const int col = n0 + wn * 64 + ni * 16 + l16;
      float bv = (bias && z == 0) ? bias[col] : 0.f;
#pragma unroll
      for (int r = 0; r < 4; r++) {
        float v = acc[mi][ni][r] + bv;
        if (z == 0 && relu) v = fmaxf(v, 0.f);
        size_t idx = (size_t)(row + r) * N + col;
        if (z == 0) {
          if (c0_f32) ((float*)C0)[idx] = v;
          else ((u16*)C0)[idx] = f2bf(v);
        } else if (z == 1) {
          C1[idx] = f2bf(v);
        } else if (z == 2) {
          C2[idx] = f2bf(v);
        } else {
          C3[idx] = f2bf(v);
        }
      }
    }
  }
}

// ---------------------------------------------------------------------------
// G2: 128x64 tile, BK=64, double-buffered (Qproj + small path).
// ---------------------------------------------------------------------------
__global__ __launch_bounds__(256) void gemm_g2(
    const u16* __restrict__ A, const u16* __restrict__ Bt,
    const float* __restrict__ bias, void* __restrict__ C,
    int M, int N, int K, int relu, int accum, int out_f32) {
  __shared__ u16 As[2][8192];
  __shared__ u16 Bs[2][4096];
  const int tid = threadIdx.x;
  const int w = tid >> 6, l = tid & 63;
  const int l16 = l & 15, kgrp = l >> 4;
  const int m0 = blockIdx.y * 128, n0 = blockIdx.x * 64;
  const int wr = (w >> 1) * 64, wc = (w & 1) * 32;

  const int srow = w * 8 + (l >> 3);
  const u16* gA[4];
#pragma unroll
  for (int i = 0; i < 4; i++) {
    int r = i * 32 + srow;
    gA[i] = A + (size_t)(m0 + r) * K + 8 * ((l & 7) ^ (r & 7));
  }
  const u16* gB[2];
#pragma unroll
  for (int i = 0; i < 2; i++) {
    int r = i * 32 + srow;
    gB[i] = Bt + (size_t)(n0 + r) * K + 8 * ((l & 7) ^ (r & 7));
  }

  v4f acc[4][2];
#pragma unroll
  for (int i = 0; i < 4; i++)
#pragma unroll
    for (int j = 0; j < 2; j++)
#pragma unroll
      for (int r = 0; r < 4; r++) acc[i][j][r] = 0.f;

#pragma unroll
  for (int i = 0; i < 4; i++) gl_lds16(gA[i], &As[0][(i * 256 + w * 64) * 8]);
#pragma unroll
  for (int i = 0; i < 2; i++) gl_lds16(gB[i], &Bs[0][(i * 256 + w * 64) * 8]);

  int cur = 0;
  for (int k0 = 0; k0 < K; k0 += 64) {
    __syncthreads();
    if (k0 + 64 < K) {
      int nxt = cur ^ 1;
#pragma unroll
      for (int i = 0; i < 4; i++)
        gl_lds16(gA[i] + k0 + 64, &As[nxt][(i * 256 + w * 64) * 8]);
#pragma unroll
      for (int i = 0; i < 2; i++)
        gl_lds16(gB[i] + k0 + 64, &Bs[nxt][(i * 256 + w * 64) * 8]);
    }
    v8s a[4][2], b[2][2];
#pragma unroll
    for (int ks = 0; ks < 2; ks++) {
      int ch = 8 * ((ks * 4 + kgrp) ^ (l16 & 7));
#pragma unroll
      for (int mi = 0; mi < 4; mi++)
        a[mi][ks] = *(const v8s*)(&As[cur][(wr + mi * 16 + l16) * 64 + ch]);
#pragma unroll
      for (int ni = 0; ni < 2; ni++)
        b[ni][ks] = *(const v8s*)(&Bs[cur][(wc + ni * 16 + l16) * 64 + ch]);
    }
#pragma unroll
    for (int ks = 0; ks < 2; ks++)
#pragma unroll
      for (int mi = 0; mi < 4; mi++)
#pragma unroll
        for (int ni = 0; ni < 2; ni++)
          acc[mi][ni] = __builtin_amdgcn_mfma_f32_16x16x32_bf16(a[mi][ks], b[ni][ks], acc[mi][ni], 0, 0, 0);
    cur ^= 1;
  }

#pragma unroll
  for (int ni = 0; ni < 2; ni++) {
    int col = n0 + wc + ni * 16 + l16;
    float bv = bias ? bias[col] : 0.f;
#pragma unroll
    for (int mi = 0; mi < 4; mi++) {
      int row = m0 + wr + mi * 16 + kgrp * 4;
#pragma unroll
      for (int r = 0; r < 4; r++) {
        float v = acc[mi][ni][r] + bv;
        if (relu) v = fmaxf(v, 0.f);
        size_t idx = (size_t)(row + r) * N + col;
        if (out_f32) {
          float* Cf = (float*)C;
          if (accum) v += Cf[idx];
          Cf[idx] = v;
        } else {
          ((u16*)C)[idx] = f2bf(v);
        }
      }
    }
  }
}

// ---------------------------------------------------------------------------
// Attention (R12 structure + XCD swizzle): O = softmax(Q Q^T / sqrt(S)) Q.
// 512 threads, 8 waves x 32 q-rows (256-row blocks), 32x32x16 MFMA,
// P fully in-register (perm-pack + permlane32_swap). Grid (8, 32) = 256.
// ---------------------------------------------------------------------------
__global__ __launch_bounds__(512) void attn_kernel(
    const u16* __restrict__ Q, const u16* __restrict__ Qt,
    u16* __restrict__ O) {
  __shared__ u16 KV[2][8192];
  const int tid = threadIdx.x;
  const int w = tid >> 6, l = tid & 63;
  const int l31 = l & 31, hi = l >> 5;

  // XCD-aware bijective swizzle (nwg % 8 == 0)
  const int gx = gridDim.x;
  const int nwg = gx * gridDim.y;
  int lin = blockIdx.x + gx * blockIdx.y;
  if ((nwg & 7) == 0) lin = (lin & 7) * (nwg >> 3) + (lin >> 3);
  const int bxi = lin % gx;
  const int bh = lin / gx;
  const int b = bh >> 4, h = bh & 15;
  const int q0 = bxi * 256;
  const size_t rowQ = (size_t)(b * 2048 + q0 + w * 32);
  const float cexp = 1.4426950408889634f / 45.254833995939045f;

  const int isV = w >> 2, wl = w & 3;
  const int r0 = wl * 16 + (l >> 3);
  const int sch8 = 8 * ((l & 7) ^ (l >> 3));
  const u16* gS0;
  size_t kstep;
  if (!isV) {
    gS0 = Q + (size_t)(b * 2048 + r0) * 1024 + h * 64 + sch8;
    kstep = 1024;
  } else {
    gS0 = Qt + (size_t)(h * 64 + r0) * 4096 + b * 2048 + sch8;
    kstep = 1;
  }
  const u16* gS1 = gS0 + (size_t)8 * (isV ? 4096 : 1024);
  const int ldst = isV * 4096 + wl * 1024;

  v8s qb[4];
#pragma unroll
  for (int t = 0; t < 4; t++) {
    v8s v = *(const v8s*)(Q + (rowQ + l31) * 1024 + h * 64 + t * 16 + hi * 8);
#pragma unroll
    for (int j = 0; j < 8; j++) v[j] = (short)f2bf(bf2f((u16)v[j]) * cexp);
    qb[t] = v;
  }

  v16f o0, o1;
#pragma unroll
  for (int r = 0; r < 16; r++) { o0[r] = 0.f; o1[r] = 0.f; }
  float ls = 0.f;

  gl_lds16(gS0, &KV[0][ldst]);
  gl_lds16(gS1, &KV[0][ldst + 512]);

  int cur = 0;
  for (int kb = 0; kb < 2048; kb += 64) {
    __syncthreads();
    if (kb + 64 < 2048) {
      int nxt = cur ^ 1;
      gl_lds16(gS0 + (size_t)(kb + 64) * kstep, &KV[nxt][ldst]);
      gl_lds16(gS1 + (size_t)(kb + 64) * kstep, &KV[nxt][ldst + 512]);
    }
    const u16* Ks = &KV[cur][0];
    const u16* Vt = &KV[cur][4096];

    v16f s0, s1;
#pragma unroll
    for (int r = 0; r < 16; r++) { s0[r] = 0.f; s1[r] = 0.f; }
#pragma unroll
    for (int t = 0; t < 4; t++) {
      const int c = 8 * ((2 * t + hi) ^ (l & 7));
      v8s ka0 = *(const v8s*)(Ks + l31 * 64 + c);
      v8s ka1 = *(const v8s*)(Ks + (32 + l31) * 64 + c);
      s0 = __builtin_amdgcn_mfma_f32_32x32x16_bf16(ka0, qb[t], s0, 0, 0, 0);
      s1 = __builtin_amdgcn_mfma_f32_32x32x16_bf16(ka1, qb[t], s1, 0, 0, 0);
    }

    float p0[16], p1[16];
#pragma unroll
    for (int r = 0; r < 16; r++) {
      p0[r] = __builtin_amdgcn_exp2f(s0[r]);
      p1[r] = __builtin_amdgcn_exp2f(s1[r]);
      ls += p0[r] + p1[r];
    }

#define PVSTEP(t, P) { \
      const int off = 8 * ((t) & 1); \
      uint32_t dw00 = __builtin_amdgcn_perm(fbits(P[off + 1]), fbits(P[off + 0]), 0x07060302u); \
      uint32_t dw01 = __builtin_amdgcn_perm(fbits(P[off + 3]), fbits(P[off + 2]), 0x07060302u); \
      uint32_t dw10 = __builtin_amdgcn_perm(fbits(P[off + 5]), fbits(P[off + 4]), 0x07060302u); \
      uint32_t dw11 = __builtin_amdgcn_perm(fbits(P[off + 7]), fbits(P[off + 6]), 0x07060302u); \
      v2u sA = __builtin_amdgcn_permlane32_swap(dw00, dw10, false, false); \
      v2u sB = __builtin_amdgcn_permlane32_swap(dw01, dw11, false, false); \
      union { uint32_t u[4]; v8s v; } pa; \
      pa.u[0] = sA[0]; pa.u[1] = sB[0]; pa.u[2] = sA[1]; pa.u[3] = sB[1]; \
      const int c = 8 * ((2 * (t) + hi) ^ (l & 7)); \
      v8s vb0 = *(const v8s*)(Vt + l31 * 64 + c); \
      v8s vb1 = *(const v8s*)(Vt + (32 + l31) * 64 + c); \
      o0 = __builtin_amdgcn_mfma_f32_32x32x16_bf16(pa.v, vb0, o0, 0, 0, 0); \
      o1 = __builtin_amdgcn_mfma_f32_32x32x16_bf16(pa.v, vb1, o1, 0, 0, 0); }
    PVSTEP(0, p0)
    PVSTEP(1, p0)
    PVSTEP(2, p1)
    PVSTEP(3, p1)
#undef PVSTEP
    cur ^= 1;
  }

  ls += __shfl_xor(ls, 32, 64);   // den[q] at lanes with l31 == q

  const int hiq = hi * 4;
#pragma unroll
  for (int r = 0; r < 16; r++) {
    const int qo = (r & 3) + 8 * (r >> 2) + hiq;
    float den = __shfl(ls, qo, 64);
    float rden = 1.f / den;
    O[(rowQ + qo) * 1024 + h * 64 + l31] = f2bf(o0[r] * rden);
    O[(rowQ + qo) * 1024 + h * 64 + 32 + l31] = f2bf(o1[r] * rden);
  }
}

// ---------------------------------------------------------------------------
// out = LayerNorm(Y [+ Y2 + Y3 + Y4] + Xr) * g + b; row length 1024; dtype
// flags (1 = fp32, 0 = bf16). Vectorized: 4 consecutive elems per thread.
// In-place safe.
// ---------------------------------------------------------------------------
__global__ __launch_bounds__(256) void ln_residual(
    const void* __restrict__ Y, const void* __restrict__ Y2,
    const void* __restrict__ Y3, const void* __restrict__ Y4,
    const void* __restrict__ Xr,
    const float* __restrict__ g, const float* __restrict__ bb,
    void* __restrict__ out, int yf, int y2f, int xf, int of) {
  const int row = blockIdx.x, tid = threadIdx.x;
  const size_t base = (size_t)row * 1024;
  const int c0 = tid * 4;
  float v[4];
  if (yf) {
    float4 t = *(const float4*)((const float*)Y + base + c0);
    v[0] = t.x; v[1] = t.y; v[2] = t.z; v[3] = t.w;
  } else {
    ushort4 t = *(const ushort4*)((const u16*)Y + base + c0);
    v[0] = bf2f(t.x); v[1] = bf2f(t.y); v[2] = bf2f(t.z); v[3] = bf2f(t.w);
  }
  if (xf) {
    float4 t = *(const float4*)((const float*)Xr + base + c0);
    v[0] += t.x; v[1] += t.y; v[2] += t.z; v[3] += t.w;
  } else {
    ushort4 t = *(const ushort4*)((const u16*)Xr + base + c0);
    v[0] += bf2f(t.x); v[1] += bf2f(t.y); v[2] += bf2f(t.z); v[3] += bf2f(t.w);
  }
  if (Y2) {
    if (y2f) {
      float4 t = *(const float4*)((const float*)Y2 + base + c0);
      v[0] += t.x; v[1] += t.y; v[2] += t.z; v[3] += t.w;
    } else {
      ushort4 t = *(const ushort4*)((const u16*)Y2 + base + c0);
      v[0] += bf2f(t.x); v[1] += bf2f(t.y); v[2] += bf2f(t.z); v[3] += bf2f(t.w);
    }
  }
  if (Y3) {
    ushort4 t = *(const ushort4*)((const u16*)Y3 + base + c0);
    v[0] += bf2f(t.x); v[1] += bf2f(t.y); v[2] += bf2f(t.z); v[3] += bf2f(t.w);
  }
  if (Y4) {
    ushort4 t = *(const ushort4*)((const u16*)Y4 + base + c0);
    v[0] += bf2f(t.x); v[1] += bf2f(t.y); v[2] += bf2f(t.z); v[3] += bf2f(t.w);
  }
  float s = (v[0] + v[1]) + (v[2] + v[3]);
  float sq = (v[0] * v[0] + v[1] * v[1]) + (v[2] * v[2] + v[3] * v[3]);
#pragma unroll
  for (int off = 32; off >= 1; off >>= 1) {
    s += __shfl_down(s, off, 64);
    sq += __shfl_down(sq, off, 64);
  }
  __shared__ float rs[4], rq[4];
  const int w = tid >> 6, l = tid & 63;
  if (l == 0) { rs[w] = s; rq[w] = sq; }
  __syncthreads();
  s = rs[0] + rs[1] + rs[2] + rs[3];
  sq = rq[0] + rq[1] + rq[2] + rq[3];
  const float mu = s * (1.f / 1024.f);
  const float var = sq * (1.f / 1024.f) - mu * mu;
  const float rstd = rsqrtf(var + 1e-5f);
  float4 gg = *(const float4*)(g + c0);
  float4 bv = *(const float4*)(bb + c0);
  float r0 = (v[0] - mu) * rstd * gg.x + bv.x;
  float r1 = (v[1] - mu) * rstd * gg.y + bv.y;
  float r2 = (v[2] - mu) * rstd * gg.z + bv.z;
  float r3 = (v[3] - mu) * rstd * gg.w + bv.w;
  if (of) {
    float4 o = {r0, r1, r2, r3};
    *(float4*)((float*)out + base + c0) = o;
  } else {
    ushort4 o;
    o.x = f2bf(r0); o.y = f2bf(r1); o.z = f2bf(r2); o.w = f2bf(r3);
    *(ushort4*)((u16*)out + base + c0) = o;
  }
}

// ---------------------------------------------------------------------------
extern "C" void kernel_launch(void* const* d_in, const int* in_sizes, int n_in,
                              void* d_out, int out_size, void* d_ws, size_t ws_size,
                              hipStream_t stream) {
  const float* x   = (const float*)d_in[0];
  const float* Wq  = (const float*)d_in[1];
  const float* bq  = (const float*)d_in[2];
  const float* Wo  = (const float*)d_in[3];
  const float* bo  = (const float*)d_in[4];
  const float* g1  = (const float*)d_in[5];
  const float* be1 = (const float*)d_in[6];
  const float* W1  = (const float*)d_in[7];
  const float* b1  = (const float*)d_in[8];
  const float* W2  = (const float*)d_in[9];
  const float* b2  = (const float*)d_in[10];
  const float* g2  = (const float*)d_in[11];
  const float* be2 = (const float*)d_in[12];
  float* out = (float*)d_out;
  u16* ws  = (u16*)d_ws;

  const size_t M1 = 1048576;
  dim3 blk(256);
  dim3 blk8(512);
  const bool big = ws_size >= (size_t)37 * M1 * 2;  // 74 MiB

  if (big) {
    // Layout (u16 offsets):
    //  [0..4M)   xb  -> attn out -> P2_ffn2
    //  [4..8M)   Qb  -> x1
    //  [8..12M)  Qt  -> Yb (Wo P0) -> P1_ffn2
    //  [12..13M) WqT
    //  [13..17M) W1T -> P3_ffn2 (after FFN1)
    //  [17..21M) W2T
    //  [21..37M) Hh; transient before FFN1: Wo partials P1/P2/P3 @21/25/29M,
    //            WoT @33M (all dead before FFN1 overwrites Hh)
    u16* xb   = ws + 0;
    u16* Qb   = ws + 4 * M1;
    u16* Qt   = ws + 8 * M1;
    u16* WqT  = ws + 12 * M1;
    u16* W1T  = ws + 13 * M1;
    u16* W2T  = ws + 17 * M1;
    u16* Hh   = ws + 21 * M1;
    u16* P1wo = ws + 21 * M1;
    u16* P2wo = ws + 25 * M1;
    u16* P3wo = ws + 29 * M1;
    u16* WoT  = ws + 33 * M1;
    u16* attn = xb;  u16* Yb = Qt;  u16* x1 = Qb;
    u16* P1f2 = Qt;              // Yb dead after LN1
    u16* P2f2 = xb;              // attn dead after Wo-proj
    u16* P3f2 = W1T;             // W1T dead after FFN1

    // 1: fused input convert + all four weight transposes
    prep_all<<<dim3(14336), blk, 0, stream>>>(x, Wq, Wo, W1, W2,
                                              xb, WqT, WoT, W1T, W2T);
    // 2: Q projection
    gemm_g2<<<dim3(16, 32), blk, 0, stream>>>(xb, WqT, bq, Qb, 4096, 1024, 1024, 0, 0, 0);
    // 3: Q transpose (for attn V-side access)
    transpose_b2b<<<dim3(32, 128), blk, 0, stream>>>(Qb, Qt, 4096, 1024, 1024, 4096);
    // 4: attention
    attn_kernel<<<dim3(8, 32), blk8, 0, stream>>>(Qb, Qt, attn);
    // 5: Wo projection: split-K=4, P0 -> Yb (bf16, +bias)
    gemm_8p<<<dim3(4, 16, 4), blk8, 0, stream>>>(attn, WoT, bo, Yb, P1wo, P2wo, P3wo,
                                                 4096, 1024, 1024, 256, 0, 0);
    // 6: LN1 (folds Wo split-K partials + residual)
    ln_residual<<<dim3(4096), blk, 0, stream>>>(Yb, P1wo, P2wo, P3wo, x, g1, be1, x1,
                                                0, 0, 1, 0);
    // 7: FFN1 (full-K, 256 blocks)
    gemm_8p<<<dim3(16, 16, 1), blk8, 0, stream>>>(x1, W1T, b1, Hh,
                                                  nullptr, nullptr, nullptr,
                                                  4096, 4096, 1024, 1024, 1, 0);
    // 8: FFN2: split-K=4, P0 -> out (fp32, +bias)
    gemm_8p<<<dim3(4, 16, 4), blk8, 0, stream>>>(Hh, W2T, b2, out, P1f2, P2f2, P3f2,
                                                 4096, 1024, 4096, 1024, 0, 1);
    // 9: LN2 (folds FFN2 split-K partials + residual)
    ln_residual<<<dim3(4096), blk, 0, stream>>>(out, P1f2, P2f2, P3f2, x1, g2, be2, out,
                                                1, 0, 0, 1);
  } else {
    u16* xb   = ws + 0;
    u16* Qb   = ws + 4 * M1;
    u16* Qt   = ws + 8 * M1;
    u16* attn = xb;  u16* Yb = Qt;  u16* x1 = Qb;  u16* Hc = xb;
    u16* Wt1  = ws + 12 * M1;
    u16* Wt2  = ws + 13 * M1;

    cvt_f2b<<<dim3(4096), blk, 0, stream>>>(x, xb, 1048576);
    transpose_f2b<<<dim3(32, 32), blk, 0, stream>>>(Wq, Wt1, 1024, 1024, 1024, 1024);
    gemm_g2<<<dim3(16, 32), blk, 0, stream>>>(xb, Wt1, bq, Qb, 4096, 1024, 1024, 0, 0, 0);

    transpose_b2b<<<dim3(32, 128), blk, 0, stream>>>(Qb, Qt, 4096, 1024, 1024, 4096);
    attn_kernel<<<dim3(8, 32), blk8, 0, stream>>>(Qb, Qt, attn);

    transpose_f2b<<<dim3(32, 32), blk, 0, stream>>>(Wo, Wt2, 1024, 1024, 1024, 1024);
    gemm_g2<<<dim3(16, 32), blk, 0, stream>>>(attn, Wt2, bo, Yb, 4096, 1024, 1024, 0, 0, 0);
    ln_residual<<<dim3(4096), blk, 0, stream>>>(Yb, nullptr, nullptr, nullptr, x, g1, be1,
                                                x1, 0, 0, 1, 0);

    for (int c = 0; c < 4; c++) {
      transpose_f2b<<<dim3(32, 32), blk, 0, stream>>>(W1 + (size_t)c * 1024, Wt1,
                                                      1024, 1024, 4096, 1024);
      gemm_g2<<<dim3(16, 32), blk, 0, stream>>>(x1, Wt1, b1 + (size_t)c * 1024, Hc,
                                                4096, 1024, 1024, 1, 0, 0);
      transpose_f2b<<<dim3(32, 32), blk, 0, stream>>>(W2 + (size_t)c * M1, Wt2,
                                                      1024, 1024, 1024, 1024);
      gemm_g2<<<dim3(16, 32), blk, 0, stream>>>(Hc, Wt2, (c == 0) ? b2 : (const float*)nullptr,
                                                out, 4096, 1024, 1024, 0, (c > 0) ? 1 : 0, 1);
    }
    ln_residual<<<dim3(4096), blk, 0, stream>>>(out, nullptr, nullptr, nullptr, x1, g2, be2,
                                                out, 1, 0, 0, 1);
  }
}